// Round 2
// baseline (8880.381 us; speedup 1.0000x reference)
//
#include <hip/hip_runtime.h>
#include <hip/hip_bf16.h>

// FAVOR+ attention, MI355X. Round 2: low-workspace (225 MB) fused design.
//   - proj GEMMs write q,k bf16 head-layout, v f32 head-layout
//   - phi computed on the fly in LDS tiles (omega bf16 in LDS)
//   - superchunk (256-token) KV states + exclusive scan (16 per bh)
//   - outchunk (64-token) recomputes prior in-superchunk chunks as
//     unmasked S@V blocks; own chunk masked (s<=t)
//   - attn bf16 -> final GEMM (bf16 A, f32 W) -> f32 out
//
// Workspace layout (bytes), total 235,929,600 (225 MB):
//   v     [64bh,4096,64]  f32  @ 0          (64 MB)
//   q     [64bh,4096,64]  bf16 @ 64 MB      (32 MB)
//   k     [64bh,4096,64]  bf16 @ 96 MB      (32 MB)
//   attn  [4,4096,1024]   bf16 @ 128 MB     (32 MB)
//   state [64bh,16,16640] f32  @ 160 MB     (65 MB)

#define B_ 4
#define H_ 16
#define L_ 4096
#define D_ 64
#define M_ 256
#define DM_ 1024
#define BH_ 64
#define NSC 16            // superchunks per bh
#define SC_ 256           // tokens per superchunk
#define C_ 64             // output chunk
#define ST_STRIDE (M_*D_ + M_)   // 16640 floats per state

typedef unsigned int u32;
typedef unsigned short u16;

static __device__ __forceinline__ float bf2f(u16 u) {
  return __uint_as_float(((u32)u) << 16);
}
static __device__ __forceinline__ u16 f2bf(float f) {
  u32 x = __float_as_uint(f);
  return (u16)((x + 0x7fffu + ((x >> 16) & 1u)) >> 16);   // RNE
}

// ---------------- projection GEMM: out = x[16384x1024] @ W + b -------------
// MODE 0: head f32 [BH,L,64];  MODE 1: head bf16 [BH,L,64]
template<int MODE>
__global__ __launch_bounds__(256) void proj_gemm_k(
    const float* __restrict__ A, const float* __restrict__ W,
    const float* __restrict__ bias, void* __restrict__ outp) {
  __shared__ float As[16][68];
  __shared__ float Bs[16][68];
  const int tid = threadIdx.x;
  const int m0 = blockIdx.y * 64;
  const int n0 = blockIdx.x * 64;
  const int tm = tid & 15;
  const int tn = tid >> 4;
  const int la_r = tid >> 2;
  const int la_c = (tid & 3) << 2;
  const int lb_r = tid >> 4;
  const int lb_c = (tid & 15) << 2;
  float acc[4][4] = {};
  for (int k0 = 0; k0 < DM_; k0 += 16) {
    float4 a4 = *(const float4*)(A + (size_t)(m0 + la_r) * DM_ + k0 + la_c);
    float4 b4 = *(const float4*)(W + (size_t)(k0 + lb_r) * DM_ + n0 + lb_c);
    __syncthreads();
    As[la_c + 0][la_r] = a4.x;
    As[la_c + 1][la_r] = a4.y;
    As[la_c + 2][la_r] = a4.z;
    As[la_c + 3][la_r] = a4.w;
    *(float4*)&Bs[lb_r][lb_c] = b4;
    __syncthreads();
#pragma unroll
    for (int k = 0; k < 16; ++k) {
      float a[4], b[4];
      *(float4*)a = *(const float4*)&As[k][tn << 2];
      *(float4*)b = *(const float4*)&Bs[k][tm << 2];
#pragma unroll
      for (int i = 0; i < 4; ++i)
#pragma unroll
        for (int j = 0; j < 4; ++j)
          acc[i][j] += a[i] * b[j];
    }
  }
  const int n = n0 + (tm << 2);
  const float4 bi = *(const float4*)(bias + n);
  const int h = n >> 6, dd = n & 63;
#pragma unroll
  for (int i = 0; i < 4; ++i) {
    const int m = m0 + (tn << 2) + i;
    const int b = m >> 12, l = m & 4095;
    float r0 = acc[i][0] + bi.x;
    float r1 = acc[i][1] + bi.y;
    float r2 = acc[i][2] + bi.z;
    float r3 = acc[i][3] + bi.w;
    const size_t off = ((size_t)(b * H_ + h) * L_ + l) * D_ + dd;
    if (MODE == 0) {
      float4 r; r.x = r0; r.y = r1; r.z = r2; r.w = r3;
      *(float4*)((float*)outp + off) = r;
    } else {
      ushort4 s;
      s.x = f2bf(r0); s.y = f2bf(r1); s.z = f2bf(r2); s.w = f2bf(r3);
      *(ushort4*)((u16*)outp + off) = s;
    }
  }
}

// ---------------- shared phi helpers --------------------------------------
// omega staged to LDS bf16 as om[d][m]
static __device__ __forceinline__ void stage_omega(
    const float* __restrict__ omega, u16 (*om)[258], int tid) {
  for (int i = tid; i < 64 * M_; i += 256) {
    const int d = i & 63, m = i >> 6;
    om[d][m] = f2bf(omega[m * 64 + d]);
  }
}

// phi for a 64-token tile: dst[t][m] = bf16(exp(om_m . xs_t - |xs_t|^2/2)/16)
// xg points at 64 tokens x 64 dims (bf16, contiguous)
static __device__ __forceinline__ void phi_tile(
    const u16* __restrict__ xg, const u16 (*om)[258], u16 (*dst)[258], int tid) {
  const int lane = tid & 63, wv = tid >> 6;
  for (int tk = wv; tk < 64; tk += 4) {
    const float xv = bf2f(xg[tk * 64 + lane]) * 0.35355339059327373f; // 64^-0.25
    float a0 = 0.f, a1 = 0.f, a2 = 0.f, a3 = 0.f, nrm = 0.f;
#pragma unroll
    for (int d = 0; d < 64; ++d) {
      const float xd = __shfl(xv, d, 64);
      nrm += xd * xd;
      a0 += bf2f(om[d][lane      ]) * xd;
      a1 += bf2f(om[d][lane + 64 ]) * xd;
      a2 += bf2f(om[d][lane + 128]) * xd;
      a3 += bf2f(om[d][lane + 192]) * xd;
    }
    const float nh = 0.5f * nrm;
    dst[tk][lane      ] = f2bf(__expf(a0 - nh) * 0.0625f);
    dst[tk][lane + 64 ] = f2bf(__expf(a1 - nh) * 0.0625f);
    dst[tk][lane + 128] = f2bf(__expf(a2 - nh) * 0.0625f);
    dst[tk][lane + 192] = f2bf(__expf(a3 - nh) * 0.0625f);
  }
}

// ---------------- per-superchunk KV state: KV = phi(K)^T V, ksum ----------
__global__ __launch_bounds__(256) void kvstate_k(
    const u16* __restrict__ k, const float* __restrict__ v,
    const float* __restrict__ omega, float* __restrict__ state) {
  __shared__ u16 om[64][258];
  __shared__ u16 kps[64][258];
  __shared__ float vs[64][64];
  const int tid = threadIdx.x;
  stage_omega(omega, om, tid);
  const int sc = blockIdx.x, bh = blockIdx.y;
  const size_t base_l = (size_t)bh * L_ + (size_t)sc * SC_;
  const int mi = tid >> 2, di = tid & 3;
  float acc[4][16] = {};
  float ksum[4] = {0.f, 0.f, 0.f, 0.f};
  for (int sub = 0; sub < 4; ++sub) {
    const size_t tl = base_l + sub * 64;
    __syncthreads();                       // omega visible / prior reads done
    const float4* vg = (const float4*)(v + tl * D_);
    for (int i = tid; i < 64 * D_ / 4; i += 256) ((float4*)vs)[i] = vg[i];
    phi_tile(k + tl * D_, om, kps, tid);
    __syncthreads();
    for (int t = 0; t < 64; ++t) {
      const u32 k0 = *(const u32*)&kps[t][(mi << 2)];
      const u32 k1 = *(const u32*)&kps[t][(mi << 2) + 2];
      float kf[4] = { bf2f((u16)k0), bf2f((u16)(k0 >> 16)),
                      bf2f((u16)k1), bf2f((u16)(k1 >> 16)) };
      float vv[16];
#pragma unroll
      for (int j4 = 0; j4 < 4; ++j4)
        *(float4*)&vv[j4 << 2] = *(const float4*)&vs[t][(di << 4) + (j4 << 2)];
#pragma unroll
      for (int i2 = 0; i2 < 4; ++i2) {
        ksum[i2] += kf[i2];
#pragma unroll
        for (int j = 0; j < 16; ++j) acc[i2][j] += kf[i2] * vv[j];
      }
    }
  }
  float* st = state + ((size_t)bh * NSC + sc) * ST_STRIDE;
#pragma unroll
  for (int i2 = 0; i2 < 4; ++i2)
#pragma unroll
    for (int j4 = 0; j4 < 4; ++j4)
      *(float4*)&st[((mi << 2) + i2) * D_ + (di << 4) + (j4 << 2)] =
          *(float4*)&acc[i2][j4 << 2];
  if (di == 0) {
#pragma unroll
    for (int i2 = 0; i2 < 4; ++i2) st[M_ * D_ + (mi << 2) + i2] = ksum[i2];
  }
}

// ---------------- exclusive prefix over superchunks (per bh) --------------
__global__ __launch_bounds__(256) void scan_k(float* __restrict__ state) {
  const int tid = threadIdx.x;
  float* sb = state + (size_t)blockIdx.x * NSC * ST_STRIDE;
  float run[64];
#pragma unroll
  for (int i = 0; i < 64; ++i) run[i] = 0.f;
  float runk = 0.f;
  for (int c = 0; c < NSC; ++c) {
    float* st = sb + (size_t)c * ST_STRIDE;
#pragma unroll
    for (int i = 0; i < 64; ++i) {
      const int idx = (i << 8) + tid;
      const float t = st[idx];
      st[idx] = run[i];
      run[i] += t;
    }
    const float tk = st[M_ * D_ + tid];
    st[M_ * D_ + tid] = runk;
    runk += tk;
  }
}

// ---------------- per-64-chunk output -------------------------------------
__global__ __launch_bounds__(256) void outchunk_k(
    const u16* __restrict__ q, const u16* __restrict__ kk,
    const float* __restrict__ v, const float* __restrict__ omega,
    const float* __restrict__ state, u16* __restrict__ attn) {
  __shared__ u16 om[64][258];     // 33,024 B
  __shared__ u16 qps[64][258];    // 33,024 B
  __shared__ u16 kps[64][258];    // 33,024 B
  __shared__ float S[64][65];     // 16,640 B
  __shared__ float vs[64][64];    // 16,384 B
  __shared__ float kvs[64][64];   // 16,384 B
  __shared__ float ksums[256];    //  1,024 B   total 149,504 B
  const int tid = threadIdx.x;
  const int bh = blockIdx.x >> 6, c = blockIdx.x & 63;
  const int sc = c >> 2;
  const size_t base_l = (size_t)bh * L_ + (size_t)c * C_;
  stage_omega(omega, om, tid);
  const float* stg = state + ((size_t)bh * NSC + sc) * ST_STRIDE;
  ksums[tid] = stg[M_ * D_ + tid];
  __syncthreads();
  phi_tile(q + base_l * D_, om, qps, tid);
  __syncthreads();
  const int g = tid >> 6, t = tid & 63;
  float o[16] = {};
  float den = 0.f;
  // cross term with exclusive superchunk state (4 quadrants of 64 features)
  for (int mc = 0; mc < 4; ++mc) {
    __syncthreads();
    const float4* sg4 = (const float4*)(stg + (size_t)(mc << 6) * D_);
    for (int i = tid; i < 64 * D_ / 4; i += 256) ((float4*)kvs)[i] = sg4[i];
    __syncthreads();
    for (int mm = 0; mm < 64; ++mm) {
      const int m = (mc << 6) + mm;
      const float qv = bf2f(qps[t][m]);
      den += qv * ksums[m];
#pragma unroll
      for (int j4 = 0; j4 < 4; ++j4) {
        const float4 kv4 = *(const float4*)&kvs[mm][(g << 4) + (j4 << 2)];
        o[(j4 << 2) + 0] += qv * kv4.x;
        o[(j4 << 2) + 1] += qv * kv4.y;
        o[(j4 << 2) + 2] += qv * kv4.z;
        o[(j4 << 2) + 3] += qv * kv4.w;
      }
    }
  }
  // source chunks within superchunk: unmasked for prior, masked for own
  for (int s_c = (sc << 2); s_c <= c; ++s_c) {
    const size_t sl = (size_t)bh * L_ + (size_t)s_c * C_;
    __syncthreads();
    const float4* vg = (const float4*)(v + sl * D_);
    for (int i = tid; i < 64 * D_ / 4; i += 256) ((float4*)vs)[i] = vg[i];
    phi_tile(kk + sl * D_, om, kps, tid);
    __syncthreads();
    {  // phase A: S = qp @ kp^T over 256 features
      const int tg = tid >> 4, sg = tid & 15;
      float pacc[4][4] = {};
      for (int m2 = 0; m2 < 128; ++m2) {
        u32 qa[4], kb[4];
#pragma unroll
        for (int i = 0; i < 4; ++i) qa[i] = *(const u32*)&qps[(tg << 2) + i][m2 << 1];
#pragma unroll
        for (int j = 0; j < 4; ++j) kb[j] = *(const u32*)&kps[(sg << 2) + j][m2 << 1];
#pragma unroll
        for (int i = 0; i < 4; ++i) {
          const float qlo = __uint_as_float(qa[i] << 16);
          const float qhi = __uint_as_float(qa[i] & 0xffff0000u);
#pragma unroll
          for (int j = 0; j < 4; ++j) {
            const float klo = __uint_as_float(kb[j] << 16);
            const float khi = __uint_as_float(kb[j] & 0xffff0000u);
            pacc[i][j] += qlo * klo + qhi * khi;
          }
        }
      }
#pragma unroll
      for (int i = 0; i < 4; ++i)
#pragma unroll
        for (int j = 0; j < 4; ++j)
          S[(tg << 2) + i][(sg << 2) + j] = pacc[i][j];
    }
    __syncthreads();
    const bool diag = (s_c == c);
#pragma unroll 4
    for (int s = 0; s < 64; ++s) {
      const float sv = (!diag || s <= t) ? S[t][s] : 0.f;
      den += sv;
#pragma unroll
      for (int j4 = 0; j4 < 4; ++j4) {
        const float4 vv = *(const float4*)&vs[s][(g << 4) + (j4 << 2)];
        o[(j4 << 2) + 0] += sv * vv.x;
        o[(j4 << 2) + 1] += sv * vv.y;
        o[(j4 << 2) + 2] += sv * vv.z;
        o[(j4 << 2) + 3] += sv * vv.w;
      }
    }
  }
  const float r = 1.f / (den + 1e-6f);
  const int b = bh >> 4, h = bh & 15;
  const int l = (c << 6) + t;
  u16* op = attn + ((size_t)b * L_ + l) * DM_ + (h << 6) + (g << 4);
  u32 __attribute__((aligned(16))) pk[8];
#pragma unroll
  for (int i = 0; i < 8; ++i)
    pk[i] = (u32)f2bf(o[2 * i] * r) | ((u32)f2bf(o[2 * i + 1] * r) << 16);
  *(uint4*)(op)     = *(const uint4*)&pk[0];
  *(uint4*)(op + 8) = *(const uint4*)&pk[4];
}

// ---------------- final GEMM: out = attn(bf16)[16384x1024] @ Wo + bo ------
__global__ __launch_bounds__(256) void out_gemm_k(
    const u16* __restrict__ A, const float* __restrict__ W,
    const float* __restrict__ bias, float* __restrict__ out) {
  __shared__ float As[16][68];
  __shared__ float Bs[16][68];
  const int tid = threadIdx.x;
  const int m0 = blockIdx.y * 64;
  const int n0 = blockIdx.x * 64;
  const int tm = tid & 15;
  const int tn = tid >> 4;
  const int la_r = tid >> 2;
  const int la_c = (tid & 3) << 2;
  const int lb_r = tid >> 4;
  const int lb_c = (tid & 15) << 2;
  float acc[4][4] = {};
  for (int k0 = 0; k0 < DM_; k0 += 16) {
    ushort4 a4 = *(const ushort4*)(A + (size_t)(m0 + la_r) * DM_ + k0 + la_c);
    float4 b4 = *(const float4*)(W + (size_t)(k0 + lb_r) * DM_ + n0 + lb_c);
    __syncthreads();
    As[la_c + 0][la_r] = bf2f(a4.x);
    As[la_c + 1][la_r] = bf2f(a4.y);
    As[la_c + 2][la_r] = bf2f(a4.z);
    As[la_c + 3][la_r] = bf2f(a4.w);
    *(float4*)&Bs[lb_r][lb_c] = b4;
    __syncthreads();
#pragma unroll
    for (int k = 0; k < 16; ++k) {
      float a[4], b[4];
      *(float4*)a = *(const float4*)&As[k][tn << 2];
      *(float4*)b = *(const float4*)&Bs[k][tm << 2];
#pragma unroll
      for (int i = 0; i < 4; ++i)
#pragma unroll
        for (int j = 0; j < 4; ++j)
          acc[i][j] += a[i] * b[j];
    }
  }
  const int n = n0 + (tm << 2);
  const float4 bi = *(const float4*)(bias + n);
#pragma unroll
  for (int i = 0; i < 4; ++i) {
    const int m = m0 + (tn << 2) + i;
    float4 r;
    r.x = acc[i][0] + bi.x;
    r.y = acc[i][1] + bi.y;
    r.z = acc[i][2] + bi.z;
    r.w = acc[i][3] + bi.w;
    *(float4*)(out + (size_t)m * DM_ + n) = r;
  }
}

extern "C" void kernel_launch(void* const* d_in, const int* in_sizes, int n_in,
                              void* d_out, int out_size, void* d_ws, size_t ws_size,
                              hipStream_t stream) {
  const float* x     = (const float*)d_in[0];
  const float* Wq    = (const float*)d_in[1];
  const float* bq    = (const float*)d_in[2];
  const float* Wk    = (const float*)d_in[3];
  const float* bk    = (const float*)d_in[4];
  const float* Wv    = (const float*)d_in[5];
  const float* bv    = (const float*)d_in[6];
  const float* Wo    = (const float*)d_in[7];
  const float* bo    = (const float*)d_in[8];
  const float* omega = (const float*)d_in[9];
  float* out = (float*)d_out;

  char* ws = (char*)d_ws;
  float* v     = (float*)(ws);                          // 64 MB
  u16*   qb    = (u16*)(ws + 67108864ull);              // 32 MB
  u16*   kb    = (u16*)(ws + 100663296ull);             // 32 MB
  u16*   attn  = (u16*)(ws + 134217728ull);             // 32 MB
  float* state = (float*)(ws + 167772160ull);           // 65 MB -> end 225 MB

  const dim3 gg(16, 256);
  proj_gemm_k<1><<<gg, 256, 0, stream>>>(x, Wq, bq, qb);
  proj_gemm_k<1><<<gg, 256, 0, stream>>>(x, Wk, bk, kb);
  proj_gemm_k<0><<<gg, 256, 0, stream>>>(x, Wv, bv, v);
  kvstate_k<<<dim3(NSC, BH_), 256, 0, stream>>>(kb, v, omega, state);
  scan_k<<<BH_, 256, 0, stream>>>(state);
  outchunk_k<<<BH_ * 64, 256, 0, stream>>>(qb, kb, v, omega, state, attn);
  out_gemm_k<<<gg, 256, 0, stream>>>(attn, Wo, bo, out);
}

// Round 3
// 1921.256 us; speedup vs baseline: 4.6222x; 4.6222x over previous
//
#include <hip/hip_runtime.h>
#include <hip/hip_bf16.h>

// FAVOR+ attention, MI355X. Round 3: MFMA everywhere.
//  - conv kernels: x->bf16, W->bf16 transposed [n][k], omega->bf16*64^-0.25
//  - mm_k: bf16 MFMA GEMM, fragments direct from global, 128x128/block
//  - kvstate: VALU (small), writes state TRANSPOSED [d=64][m=256] (+ksum)
//  - scan: 512-block parallel exclusive prefix over superchunks
//  - outchunk: full-MFMA (phi via x@om^T, S=Qp Kp^T, S@V, cross Qp@KV hi/lo)
//
// Workspace (bytes):
//   v    bf16 [64bh][4096][64] @ 0        (32 MB)
//   q    bf16                  @ 32 MB    (32 MB)
//   k    bf16                  @ 64 MB    (32 MB)
//   xb   bf16 [16384][1024]    @ 96 MB    (32 MB)  -- ALIASED with attn
//   state f32 [64bh][16][16640]@ 128 MB   (65 MB)
//   Wt   bf16 4x[1024][1024]   @ 202,375,168  (8 MB)
//   omb  bf16 [256][64]        @ 210,763,776  (32 KB)   total ~201 MB

#define B_ 4
#define H_ 16
#define L_ 4096
#define D_ 64
#define M_ 256
#define DM_ 1024
#define BH_ 64
#define NSC 16
#define ST_STRIDE (M_*D_ + M_)   // 16640 floats

typedef unsigned int u32;
typedef unsigned short u16;
typedef __attribute__((ext_vector_type(8))) short bf16x8;
typedef __attribute__((ext_vector_type(4))) float f32x4;

static __device__ __forceinline__ float bf2f(u16 u) {
  return __uint_as_float(((u32)u) << 16);
}
static __device__ __forceinline__ u16 f2bf(float f) {
  u32 x = __float_as_uint(f);
  return (u16)((x + 0x7fffu + ((x >> 16) & 1u)) >> 16);   // RNE
}
#define MFMA16(a, b, c) __builtin_amdgcn_mfma_f32_16x16x32_bf16((a), (b), (c), 0, 0, 0)

// ---------------- converters ----------------------------------------------
__global__ __launch_bounds__(256) void convx_k(const float* __restrict__ x,
                                               u16* __restrict__ xb) {
  const int i = blockIdx.x * 256 + threadIdx.x;      // n4 = 4,194,304
  float4 f = ((const float4*)x)[i];
  ushort4 u;
  u.x = f2bf(f.x); u.y = f2bf(f.y); u.z = f2bf(f.z); u.w = f2bf(f.w);
  ((ushort4*)xb)[i] = u;
}

__global__ __launch_bounds__(256) void convw_k(
    const float* __restrict__ W0, const float* __restrict__ W1,
    const float* __restrict__ W2, const float* __restrict__ W3,
    u16* __restrict__ out) {
  __shared__ u16 tt[64][66];
  const int z = blockIdx.z;
  const float* W = (z == 0) ? W0 : (z == 1) ? W1 : (z == 2) ? W2 : W3;
  u16* o = out + (size_t)z * 1048576ull;
  const int k0 = blockIdx.y * 64, n0 = blockIdx.x * 64;
  const int r = threadIdx.x >> 4, c4 = (threadIdx.x & 15) << 2;
  for (int rr = r; rr < 64; rr += 16) {
    float4 w4 = *(const float4*)(W + (size_t)(k0 + rr) * DM_ + n0 + c4);
    tt[c4 + 0][rr] = f2bf(w4.x);
    tt[c4 + 1][rr] = f2bf(w4.y);
    tt[c4 + 2][rr] = f2bf(w4.z);
    tt[c4 + 3][rr] = f2bf(w4.w);
  }
  __syncthreads();
  for (int rr = r; rr < 64; rr += 16) {
    ushort4 u4;
    u4.x = tt[rr][c4 + 0];
    u4.y = tt[rr][c4 + 1];
    u4.z = tt[rr][c4 + 2];
    u4.w = tt[rr][c4 + 3];
    *(ushort4*)(o + (size_t)(n0 + rr) * DM_ + k0 + c4) = u4;
  }
}

__global__ __launch_bounds__(256) void convom_k(const float* __restrict__ om,
                                                u16* __restrict__ omb) {
  const int i = blockIdx.x * 256 + threadIdx.x;      // 16384
  omb[i] = f2bf(om[i] * 0.35355339059327373f);       // fold 64^-0.25
}

// ---------------- bf16 MFMA GEMM ------------------------------------------
// out = A[16384x1024] @ W + bias, W given transposed Bt[n][k].
// MODE 0: bf16 head layout [bh][l][64]; MODE 1: f32 row-major [m][1024].
template<int MODE>
__global__ __launch_bounds__(256) void mm_k(
    const u16* __restrict__ A, const u16* __restrict__ Bt,
    const float* __restrict__ bias, void* __restrict__ outp) {
  const int tid = threadIdx.x, lane = tid & 63, w = tid >> 6;
  const int fr = lane & 15, fg = lane >> 4;
  const int m_blk = blockIdx.y * 128 + (w >> 1) * 64;
  const int n_blk = blockIdx.x * 128 + (w & 1) * 64;
  f32x4 acc[4][4] = {};
  for (int k0 = 0; k0 < DM_; k0 += 32) {
    bf16x8 a[4], b[4];
#pragma unroll
    for (int i = 0; i < 4; ++i)
      a[i] = *(const bf16x8*)(A + (size_t)(m_blk + i * 16 + fr) * DM_ + k0 + fg * 8);
#pragma unroll
    for (int j = 0; j < 4; ++j)
      b[j] = *(const bf16x8*)(Bt + (size_t)(n_blk + j * 16 + fr) * DM_ + k0 + fg * 8);
#pragma unroll
    for (int i = 0; i < 4; ++i)
#pragma unroll
      for (int j = 0; j < 4; ++j)
        acc[i][j] = MFMA16(a[i], b[j], acc[i][j]);
  }
#pragma unroll
  for (int j = 0; j < 4; ++j) {
    const int n = n_blk + j * 16 + fr;
    const float bi = bias[n];
    const int h = n >> 6, d = n & 63;
#pragma unroll
    for (int i = 0; i < 4; ++i) {
#pragma unroll
      for (int r = 0; r < 4; ++r) {
        const int m = m_blk + i * 16 + fg * 4 + r;
        const float val = acc[i][j][r] + bi;
        if (MODE == 0) {
          const int b = m >> 12, l = m & 4095;
          ((u16*)outp)[((size_t)(b * H_ + h) * L_ + l) * D_ + d] = f2bf(val);
        } else {
          ((float*)outp)[(size_t)m * DM_ + n] = val;
        }
      }
    }
  }
}

// ---------------- kvstate (VALU): KV = phi(K)^T V transposed [d][m] -------
static __device__ __forceinline__ void stage_omega(
    const float* __restrict__ omega, u16 (*om)[258], int tid) {
  for (int i = tid; i < 64 * M_; i += 256) {
    const int d = i & 63, m = i >> 6;
    om[d][m] = f2bf(omega[m * 64 + d]);
  }
}

static __device__ __forceinline__ void phi_tile_valu(
    const u16* __restrict__ xg, const u16 (*om)[258], u16 (*dst)[258], int tid) {
  const int lane = tid & 63, wv = tid >> 6;
  for (int tk = wv; tk < 64; tk += 4) {
    const float xv = bf2f(xg[tk * 64 + lane]) * 0.35355339059327373f;
    float a0 = 0.f, a1 = 0.f, a2 = 0.f, a3 = 0.f, nrm = 0.f;
#pragma unroll
    for (int d = 0; d < 64; ++d) {
      const float xd = __shfl(xv, d, 64);
      nrm += xd * xd;
      a0 += bf2f(om[d][lane      ]) * xd;
      a1 += bf2f(om[d][lane + 64 ]) * xd;
      a2 += bf2f(om[d][lane + 128]) * xd;
      a3 += bf2f(om[d][lane + 192]) * xd;
    }
    const float nh = 0.5f * nrm;
    dst[tk][lane      ] = f2bf(__expf(a0 - nh) * 0.0625f);
    dst[tk][lane + 64 ] = f2bf(__expf(a1 - nh) * 0.0625f);
    dst[tk][lane + 128] = f2bf(__expf(a2 - nh) * 0.0625f);
    dst[tk][lane + 192] = f2bf(__expf(a3 - nh) * 0.0625f);
  }
}

__global__ __launch_bounds__(256) void kvstate_k(
    const u16* __restrict__ k, const u16* __restrict__ v,
    const float* __restrict__ omega, float* __restrict__ state) {
  __shared__ u16 om[64][258];
  __shared__ u16 kps[64][258];
  __shared__ float vs[64][64];
  const int tid = threadIdx.x;
  stage_omega(omega, om, tid);
  const int sc = blockIdx.x, bh = blockIdx.y;
  const size_t base_l = (size_t)bh * L_ + (size_t)sc * 256;
  const int mi = tid >> 2, di = tid & 3;
  float acc[4][16] = {};
  float ksum[4] = {0.f, 0.f, 0.f, 0.f};
  for (int sub = 0; sub < 4; ++sub) {
    const size_t tl = base_l + sub * 64;
    __syncthreads();
    const ushort4* vg = (const ushort4*)(v + tl * D_);
    for (int i = tid; i < 64 * D_ / 4; i += 256) {
      ushort4 t4 = vg[i];
      float4 f4;
      f4.x = bf2f(t4.x); f4.y = bf2f(t4.y); f4.z = bf2f(t4.z); f4.w = bf2f(t4.w);
      ((float4*)vs)[i] = f4;
    }
    phi_tile_valu(k + tl * D_, om, kps, tid);
    __syncthreads();
    for (int t = 0; t < 64; ++t) {
      const u32 k0 = *(const u32*)&kps[t][(mi << 2)];
      const u32 k1 = *(const u32*)&kps[t][(mi << 2) + 2];
      float kf[4] = { bf2f((u16)k0), bf2f((u16)(k0 >> 16)),
                      bf2f((u16)k1), bf2f((u16)(k1 >> 16)) };
      float vv[16];
#pragma unroll
      for (int j4 = 0; j4 < 4; ++j4)
        *(float4*)&vv[j4 << 2] = *(const float4*)&vs[t][(di << 4) + (j4 << 2)];
#pragma unroll
      for (int i2 = 0; i2 < 4; ++i2) {
        ksum[i2] += kf[i2];
#pragma unroll
        for (int j = 0; j < 16; ++j) acc[i2][j] += kf[i2] * vv[j];
      }
    }
  }
  float* st = state + ((size_t)bh * NSC + sc) * ST_STRIDE;
#pragma unroll
  for (int j = 0; j < 16; ++j) {   // transposed: st[d*256 + m]
    float4 r;
    r.x = acc[0][j]; r.y = acc[1][j]; r.z = acc[2][j]; r.w = acc[3][j];
    *(float4*)&st[(size_t)(di * 16 + j) * M_ + mi * 4] = r;
  }
  if (di == 0) {
#pragma unroll
    for (int i2 = 0; i2 < 4; ++i2) st[M_ * D_ + mi * 4 + i2] = ksum[i2];
  }
}

// ---------------- parallel exclusive prefix over superchunks --------------
__global__ __launch_bounds__(256) void scan_k(float* __restrict__ state) {
  const int bh = blockIdx.y;
  float* sb = state + (size_t)bh * NSC * ST_STRIDE;
  const int base = blockIdx.x * 2048 + threadIdx.x * 8;
  float run[8] = {};
  for (int cc = 0; cc < NSC; ++cc) {
    float* st = sb + (size_t)cc * ST_STRIDE + base;
    float4 t0 = *(float4*)st;
    float4 t1 = *(float4*)(st + 4);
    *(float4*)st       = make_float4(run[0], run[1], run[2], run[3]);
    *(float4*)(st + 4) = make_float4(run[4], run[5], run[6], run[7]);
    run[0] += t0.x; run[1] += t0.y; run[2] += t0.z; run[3] += t0.w;
    run[4] += t1.x; run[5] += t1.y; run[6] += t1.z; run[7] += t1.w;
  }
  if (blockIdx.x == 0) {           // ksum tail
    float rk = 0.f;
    for (int cc = 0; cc < NSC; ++cc) {
      float* p = sb + (size_t)cc * ST_STRIDE + M_ * D_ + threadIdx.x;
      const float t = *p;
      *p = rk;
      rk += t;
    }
  }
}

// ---------------- outchunk: full MFMA -------------------------------------
static __device__ __forceinline__ void sumsq_tile(
    const u16* __restrict__ xg, float (*ssq)[4], float* __restrict__ nh, int tid) {
  const int t = tid >> 2, qt = tid & 3;
  const u16* xp = xg + t * 64 + qt * 16;
  float s = 0.f;
#pragma unroll
  for (int jj = 0; jj < 2; ++jj) {
    bf16x8 xv = *(const bf16x8*)(xp + jj * 8);
#pragma unroll
    for (int e = 0; e < 8; ++e) { const float f = bf2f((u16)xv[e]); s += f * f; }
  }
  ssq[t][qt] = s;
  __syncthreads();
  if (tid < 64)
    nh[tid] = 0.0625f * (ssq[tid][0] + ssq[tid][1] + ssq[tid][2] + ssq[tid][3]);
  __syncthreads();
}

// phi quadrant: dst[t][j*16+fr] = exp(omb_q[m].x_t - nh[t])/16  (64t x 64m)
static __device__ __forceinline__ void phi_quad(
    const u16* __restrict__ xg, const u16* __restrict__ ombq,
    u16* __restrict__ dst, int dstride, const float* __restrict__ nh,
    int w, int lane) {
  const int fr = lane & 15, fg = lane >> 4;
  const int tband = w * 16;
  const bf16x8 a0 = *(const bf16x8*)(xg + (tband + fr) * 64 + fg * 8);
  const bf16x8 a1 = *(const bf16x8*)(xg + (tband + fr) * 64 + 32 + fg * 8);
  float nhv[4];
#pragma unroll
  for (int r = 0; r < 4; ++r) nhv[r] = nh[tband + fg * 4 + r];
#pragma unroll
  for (int j = 0; j < 4; ++j) {
    const bf16x8 b0 = *(const bf16x8*)(ombq + (j * 16 + fr) * 64 + fg * 8);
    const bf16x8 b1 = *(const bf16x8*)(ombq + (j * 16 + fr) * 64 + 32 + fg * 8);
    f32x4 acc = {0.f, 0.f, 0.f, 0.f};
    acc = MFMA16(a0, b0, acc);
    acc = MFMA16(a1, b1, acc);
#pragma unroll
    for (int r = 0; r < 4; ++r) {
      const int t = tband + fg * 4 + r;
      dst[t * dstride + j * 16 + fr] = f2bf(__expf(acc[r] - nhv[r]) * 0.0625f);
    }
  }
}

__global__ __launch_bounds__(256) void outchunk_k(
    const u16* __restrict__ q, const u16* __restrict__ kk,
    const u16* __restrict__ v, const u16* __restrict__ omb,
    const float* __restrict__ state, u16* __restrict__ attn) {
  __shared__ u16 sA[64][264];     // Qp full        33,792 B
  __shared__ u16 sK[64][72];      // Kp quadrant     9,216 B
  __shared__ u16 sB1[64][72];     // kvT hi / vT     9,216 B
  __shared__ u16 sB2[64][72];     // kvT lo          9,216 B
  __shared__ u16 sS[64][72];      // S bf16          9,216 B
  __shared__ float ksum_l[256];
  __shared__ float nh_q[64], nh_k[64];
  __shared__ float ssq[64][4];
  __shared__ float dq[64][4];
  __shared__ float sden[64];
  const int tid = threadIdx.x, lane = tid & 63, w = tid >> 6;
  const int fr = lane & 15, fg = lane >> 4;
  const int bh = blockIdx.x >> 6, c = blockIdx.x & 63;
  const int sc = c >> 2;
  const size_t tok0 = (size_t)bh * L_ + (size_t)c * 64;
  const u16* qg = q + tok0 * 64;
  const float* stg = state + ((size_t)bh * NSC + sc) * ST_STRIDE;

  ksum_l[tid] = stg[M_ * D_ + tid];
  sumsq_tile(qg, ssq, nh_q, tid);
#pragma unroll 1
  for (int mq = 0; mq < 4; ++mq)
    phi_quad(qg, omb + mq * 4096, &sA[0][mq * 64], 264, nh_q, w, lane);
  __syncthreads();

  // den: ksum part. thread = (t=lane, quadrant=w)
  {
    float s = 0.f;
#pragma unroll
    for (int g8 = 0; g8 < 8; ++g8) {
      bf16x8 qv = *(const bf16x8*)&sA[lane][w * 64 + g8 * 8];
#pragma unroll
      for (int e = 0; e < 8; ++e)
        s += bf2f((u16)qv[e]) * ksum_l[w * 64 + g8 * 8 + e];
    }
    dq[lane][w] = s;
  }

  f32x4 oacc[4] = {};
  // ---- cross term: Qp @ KVex (hi/lo), 4 feature quadrants
#pragma unroll 1
  for (int mq = 0; mq < 4; ++mq) {
    {
      const int d = tid >> 2, seg = tid & 3;
      const float* sp = stg + (size_t)d * M_ + mq * 64 + seg * 16;
      u16* ph = &sB1[d][seg * 16];
      u16* pl = &sB2[d][seg * 16];
#pragma unroll
      for (int e = 0; e < 16; ++e) {
        const float f = sp[e];
        const u16 hi = f2bf(f);
        ph[e] = hi;
        pl[e] = f2bf(f - bf2f(hi));
      }
    }
    __syncthreads();
    const bf16x8 a0 = *(const bf16x8*)&sA[w * 16 + fr][mq * 64 + fg * 8];
    const bf16x8 a1 = *(const bf16x8*)&sA[w * 16 + fr][mq * 64 + 32 + fg * 8];
#pragma unroll
    for (int j = 0; j < 4; ++j) {
      const bf16x8 bh0 = *(const bf16x8*)&sB1[j * 16 + fr][fg * 8];
      const bf16x8 bh1 = *(const bf16x8*)&sB1[j * 16 + fr][32 + fg * 8];
      const bf16x8 bl0 = *(const bf16x8*)&sB2[j * 16 + fr][fg * 8];
      const bf16x8 bl1 = *(const bf16x8*)&sB2[j * 16 + fr][32 + fg * 8];
      oacc[j] = MFMA16(a0, bh0, oacc[j]);
      oacc[j] = MFMA16(a1, bh1, oacc[j]);
      oacc[j] = MFMA16(a0, bl0, oacc[j]);
      oacc[j] = MFMA16(a1, bl1, oacc[j]);
    }
    __syncthreads();
  }

  // ---- source chunks in superchunk
#pragma unroll 1
  for (int s_c = sc * 4; s_c <= c; ++s_c) {
    const size_t ktok = (size_t)bh * L_ + (size_t)s_c * 64;
    const u16* kg = kk + ktok * 64;
    sumsq_tile(kg, ssq, nh_k, tid);
    f32x4 sacc[4] = {};
#pragma unroll 1
    for (int mq = 0; mq < 4; ++mq) {
      phi_quad(kg, omb + mq * 4096, &sK[0][0], 72, nh_k, w, lane);
      __syncthreads();
      const bf16x8 a0 = *(const bf16x8*)&sA[w * 16 + fr][mq * 64 + fg * 8];
      const bf16x8 a1 = *(const bf16x8*)&sA[w * 16 + fr][mq * 64 + 32 + fg * 8];
#pragma unroll
      for (int j = 0; j < 4; ++j) {
        const bf16x8 b0 = *(const bf16x8*)&sK[j * 16 + fr][fg * 8];
        const bf16x8 b1 = *(const bf16x8*)&sK[j * 16 + fr][32 + fg * 8];
        sacc[j] = MFMA16(a0, b0, sacc[j]);
        sacc[j] = MFMA16(a1, b1, sacc[j]);
      }
      __syncthreads();
    }
    const bool diag = (s_c == c);
#pragma unroll
    for (int j = 0; j < 4; ++j)
#pragma unroll
      for (int r = 0; r < 4; ++r) {
        const int s = j * 16 + fr, t = w * 16 + fg * 4 + r;
        float val = sacc[j][r];
        if (diag && s > t) val = 0.f;
        sS[t][s] = f2bf(val);
      }
    __syncthreads();
    // den contribution + vT staging
    {
      float s = 0.f;
      bf16x8 s0 = *(const bf16x8*)&sS[lane][w * 16];
      bf16x8 s1 = *(const bf16x8*)&sS[lane][w * 16 + 8];
#pragma unroll
      for (int e = 0; e < 8; ++e) s += bf2f((u16)s0[e]) + bf2f((u16)s1[e]);
      dq[lane][w] += s;
      const u16* vp = v + (ktok + lane) * 64 + w * 16;
      bf16x8 v0 = *(const bf16x8*)(vp);
      bf16x8 v1 = *(const bf16x8*)(vp + 8);
#pragma unroll
      for (int e = 0; e < 8; ++e) sB1[w * 16 + e][lane] = (u16)v0[e];
#pragma unroll
      for (int e = 0; e < 8; ++e) sB1[w * 16 + 8 + e][lane] = (u16)v1[e];
    }
    __syncthreads();
    // S @ V
    {
      const bf16x8 a0 = *(const bf16x8*)&sS[w * 16 + fr][fg * 8];
      const bf16x8 a1 = *(const bf16x8*)&sS[w * 16 + fr][32 + fg * 8];
#pragma unroll
      for (int j = 0; j < 4; ++j) {
        const bf16x8 b0 = *(const bf16x8*)&sB1[j * 16 + fr][fg * 8];
        const bf16x8 b1 = *(const bf16x8*)&sB1[j * 16 + fr][32 + fg * 8];
        oacc[j] = MFMA16(a0, b0, oacc[j]);
        oacc[j] = MFMA16(a1, b1, oacc[j]);
      }
    }
    __syncthreads();
  }

  if (tid < 64)
    sden[tid] = 1.0f / (dq[tid][0] + dq[tid][1] + dq[tid][2] + dq[tid][3] + 1e-6f);
  __syncthreads();
  const int b = bh >> 4, hh = bh & 15;
#pragma unroll
  for (int j = 0; j < 4; ++j)
#pragma unroll
    for (int r = 0; r < 4; ++r) {
      const int t = w * 16 + fg * 4 + r;
      const int d = j * 16 + fr;
      const int l = c * 64 + t;
      attn[((size_t)b * L_ + l) * DM_ + hh * 64 + d] = f2bf(oacc[j][r] * sden[t]);
    }
}

extern "C" void kernel_launch(void* const* d_in, const int* in_sizes, int n_in,
                              void* d_out, int out_size, void* d_ws, size_t ws_size,
                              hipStream_t stream) {
  const float* x     = (const float*)d_in[0];
  const float* Wq    = (const float*)d_in[1];
  const float* bq    = (const float*)d_in[2];
  const float* Wk    = (const float*)d_in[3];
  const float* bk    = (const float*)d_in[4];
  const float* Wv    = (const float*)d_in[5];
  const float* bv    = (const float*)d_in[6];
  const float* Wo    = (const float*)d_in[7];
  const float* bo    = (const float*)d_in[8];
  const float* omega = (const float*)d_in[9];
  float* out = (float*)d_out;

  char* ws = (char*)d_ws;
  u16*   v     = (u16*)(ws);                            // 32 MB
  u16*   qb    = (u16*)(ws + 33554432ull);              // 32 MB
  u16*   kb    = (u16*)(ws + 67108864ull);              // 32 MB
  u16*   xb    = (u16*)(ws + 100663296ull);             // 32 MB (alias attn)
  u16*   attn  = xb;
  float* state = (float*)(ws + 134217728ull);           // 68.16 MB
  u16*   Wt    = (u16*)(ws + 202375168ull);             // 8 MB
  u16*   omb   = (u16*)(ws + 210763776ull);             // 32 KB

  convx_k<<<16384, 256, 0, stream>>>(x, xb);
  convw_k<<<dim3(16, 16, 4), 256, 0, stream>>>(Wq, Wk, Wv, Wo, Wt);
  convom_k<<<64, 256, 0, stream>>>(omega, omb);

  const dim3 gg(8, 128);
  mm_k<0><<<gg, 256, 0, stream>>>(xb, Wt,                 bq, qb);
  mm_k<0><<<gg, 256, 0, stream>>>(xb, Wt + 1048576ull,    bk, kb);
  mm_k<0><<<gg, 256, 0, stream>>>(xb, Wt + 2097152ull,    bv, v);
  kvstate_k<<<dim3(NSC, BH_), 256, 0, stream>>>(kb, v, omega, state);
  scan_k<<<dim3(8, BH_), 256, 0, stream>>>(state);
  outchunk_k<<<BH_ * 64, 256, 0, stream>>>(qb, kb, v, omb, state, attn);
  mm_k<1><<<gg, 256, 0, stream>>>(attn, Wt + 3145728ull,  bo, out);
}

// Round 4
// 1056.407 us; speedup vs baseline: 8.4062x; 1.8187x over previous
//
#include <hip/hip_runtime.h>
#include <hip/hip_bf16.h>

// FAVOR+ attention, MI355X. Round 4: kvstate -> full MFMA.
//  - conv kernels: x->bf16, W->bf16 transposed [n][k], omega->bf16*64^-0.25
//  - mm_k: bf16 MFMA GEMM, fragments direct from global, 128x128/block
//  - kvstate: MFMA (phi^T via om@x^T MFMA, KV = v^T @ phi^T, ksum via ones-MFMA)
//  - scan: 512-block parallel exclusive prefix over superchunks
//  - outchunk: full-MFMA (phi via x@om^T, S=Qp Kp^T, S@V, cross Qp@KV hi/lo)
//
// Workspace (bytes):
//   v    bf16 [64bh][4096][64] @ 0        (32 MB)
//   q    bf16                  @ 32 MB    (32 MB)
//   k    bf16                  @ 64 MB    (32 MB)
//   xb   bf16 [16384][1024]    @ 96 MB    (32 MB)  -- ALIASED with attn
//   state f32 [64bh][16][16640]@ 128 MB   (65 MB)
//   Wt   bf16 4x[1024][1024]   @ 202,375,168  (8 MB)
//   omb  bf16 [256][64]        @ 210,763,776  (32 KB)   total ~201 MB

#define B_ 4
#define H_ 16
#define L_ 4096
#define D_ 64
#define M_ 256
#define DM_ 1024
#define BH_ 64
#define NSC 16
#define ST_STRIDE (M_*D_ + M_)   // 16640 floats

typedef unsigned int u32;
typedef unsigned short u16;
typedef __attribute__((ext_vector_type(8))) short bf16x8;
typedef __attribute__((ext_vector_type(4))) float f32x4;

static __device__ __forceinline__ float bf2f(u16 u) {
  return __uint_as_float(((u32)u) << 16);
}
static __device__ __forceinline__ u16 f2bf(float f) {
  u32 x = __float_as_uint(f);
  return (u16)((x + 0x7fffu + ((x >> 16) & 1u)) >> 16);   // RNE
}
#define MFMA16(a, b, c) __builtin_amdgcn_mfma_f32_16x16x32_bf16((a), (b), (c), 0, 0, 0)

// ---------------- converters ----------------------------------------------
__global__ __launch_bounds__(256) void convx_k(const float* __restrict__ x,
                                               u16* __restrict__ xb) {
  const int i = blockIdx.x * 256 + threadIdx.x;      // n4 = 4,194,304
  float4 f = ((const float4*)x)[i];
  ushort4 u;
  u.x = f2bf(f.x); u.y = f2bf(f.y); u.z = f2bf(f.z); u.w = f2bf(f.w);
  ((ushort4*)xb)[i] = u;
}

__global__ __launch_bounds__(256) void convw_k(
    const float* __restrict__ W0, const float* __restrict__ W1,
    const float* __restrict__ W2, const float* __restrict__ W3,
    u16* __restrict__ out) {
  __shared__ u16 tt[64][66];
  const int z = blockIdx.z;
  const float* W = (z == 0) ? W0 : (z == 1) ? W1 : (z == 2) ? W2 : W3;
  u16* o = out + (size_t)z * 1048576ull;
  const int k0 = blockIdx.y * 64, n0 = blockIdx.x * 64;
  const int r = threadIdx.x >> 4, c4 = (threadIdx.x & 15) << 2;
  for (int rr = r; rr < 64; rr += 16) {
    float4 w4 = *(const float4*)(W + (size_t)(k0 + rr) * DM_ + n0 + c4);
    tt[c4 + 0][rr] = f2bf(w4.x);
    tt[c4 + 1][rr] = f2bf(w4.y);
    tt[c4 + 2][rr] = f2bf(w4.z);
    tt[c4 + 3][rr] = f2bf(w4.w);
  }
  __syncthreads();
  for (int rr = r; rr < 64; rr += 16) {
    ushort4 u4;
    u4.x = tt[rr][c4 + 0];
    u4.y = tt[rr][c4 + 1];
    u4.z = tt[rr][c4 + 2];
    u4.w = tt[rr][c4 + 3];
    *(ushort4*)(o + (size_t)(n0 + rr) * DM_ + k0 + c4) = u4;
  }
}

__global__ __launch_bounds__(256) void convom_k(const float* __restrict__ om,
                                                u16* __restrict__ omb) {
  const int i = blockIdx.x * 256 + threadIdx.x;      // 16384
  omb[i] = f2bf(om[i] * 0.35355339059327373f);       // fold 64^-0.25
}

// ---------------- bf16 MFMA GEMM ------------------------------------------
// out = A[16384x1024] @ W + bias, W given transposed Bt[n][k].
// MODE 0: bf16 head layout [bh][l][64]; MODE 1: f32 row-major [m][1024].
template<int MODE>
__global__ __launch_bounds__(256) void mm_k(
    const u16* __restrict__ A, const u16* __restrict__ Bt,
    const float* __restrict__ bias, void* __restrict__ outp) {
  const int tid = threadIdx.x, lane = tid & 63, w = tid >> 6;
  const int fr = lane & 15, fg = lane >> 4;
  const int m_blk = blockIdx.y * 128 + (w >> 1) * 64;
  const int n_blk = blockIdx.x * 128 + (w & 1) * 64;
  f32x4 acc[4][4] = {};
  for (int k0 = 0; k0 < DM_; k0 += 32) {
    bf16x8 a[4], b[4];
#pragma unroll
    for (int i = 0; i < 4; ++i)
      a[i] = *(const bf16x8*)(A + (size_t)(m_blk + i * 16 + fr) * DM_ + k0 + fg * 8);
#pragma unroll
    for (int j = 0; j < 4; ++j)
      b[j] = *(const bf16x8*)(Bt + (size_t)(n_blk + j * 16 + fr) * DM_ + k0 + fg * 8);
#pragma unroll
    for (int i = 0; i < 4; ++i)
#pragma unroll
      for (int j = 0; j < 4; ++j)
        acc[i][j] = MFMA16(a[i], b[j], acc[i][j]);
  }
#pragma unroll
  for (int j = 0; j < 4; ++j) {
    const int n = n_blk + j * 16 + fr;
    const float bi = bias[n];
    const int h = n >> 6, d = n & 63;
#pragma unroll
    for (int i = 0; i < 4; ++i) {
#pragma unroll
      for (int r = 0; r < 4; ++r) {
        const int m = m_blk + i * 16 + fg * 4 + r;
        const float val = acc[i][j][r] + bi;
        if (MODE == 0) {
          const int b = m >> 12, l = m & 4095;
          ((u16*)outp)[((size_t)(b * H_ + h) * L_ + l) * D_ + d] = f2bf(val);
        } else {
          ((float*)outp)[(size_t)m * DM_ + n] = val;
        }
      }
    }
  }
}

// ---------------- shared: per-64-token sumsq -> nh[t] = ||x_t||^2/16 ------
static __device__ __forceinline__ void sumsq_tile(
    const u16* __restrict__ xg, float (*ssq)[4], float* __restrict__ nh, int tid) {
  const int t = tid >> 2, qt = tid & 3;
  const u16* xp = xg + t * 64 + qt * 16;
  float s = 0.f;
#pragma unroll
  for (int jj = 0; jj < 2; ++jj) {
    bf16x8 xv = *(const bf16x8*)(xp + jj * 8);
#pragma unroll
    for (int e = 0; e < 8; ++e) { const float f = bf2f((u16)xv[e]); s += f * f; }
  }
  ssq[t][qt] = s;
  __syncthreads();
  if (tid < 64)
    nh[tid] = 0.0625f * (ssq[tid][0] + ssq[tid][1] + ssq[tid][2] + ssq[tid][3]);
  __syncthreads();
}

// ---------------- kvstate (MFMA): state[d][m] = sum_t v[t][d] phi_k[t][m] --
__global__ __launch_bounds__(256) void kvstate_k(
    const u16* __restrict__ k, const u16* __restrict__ v,
    const u16* __restrict__ omb, float* __restrict__ state) {
  __shared__ u16 sPhi[256][72];   // phi^T [m][t], 36,864 B
  __shared__ u16 sVt[64][72];     // v^T  [d][t],  9,216 B
  __shared__ float ssq[64][4];
  __shared__ float nh[64];
  const int tid = threadIdx.x, lane = tid & 63, w = tid >> 6;
  const int fr = lane & 15, fg = lane >> 4;
  const int sc = blockIdx.x, bh = blockIdx.y;
  const size_t base_l = (size_t)bh * L_ + (size_t)sc * 256;

  bf16x8 ones;
#pragma unroll
  for (int e = 0; e < 8; ++e) ones[e] = (short)0x3F80;   // bf16 1.0

  f32x4 kvacc[4][4] = {};   // [m-tile within wave band][d-tile]
  f32x4 ksacc[4] = {};      // [m-tile]

  for (int sub = 0; sub < 4; ++sub) {
    const size_t tl = base_l + sub * 64;
    const u16* kg = k + tl * 64;
    __syncthreads();   // prior iteration's MFMA reads of sPhi/sVt done
    // stage v^T: thread (w,lane): rows d = w*16+e, col t = lane
    {
      const u16* vp = v + (tl + lane) * 64 + w * 16;
      bf16x8 v0 = *(const bf16x8*)(vp);
      bf16x8 v1 = *(const bf16x8*)(vp + 8);
#pragma unroll
      for (int e = 0; e < 8; ++e) sVt[w * 16 + e][lane] = (u16)v0[e];
#pragma unroll
      for (int e = 0; e < 8; ++e) sVt[w * 16 + 8 + e][lane] = (u16)v1[e];
    }
    sumsq_tile(kg, ssq, nh, tid);   // internal syncs; nh[t] ready after
    // phi^T: wave w computes m-band w*64 (4 m-tiles x 4 t-tiles)
#pragma unroll
    for (int mi = 0; mi < 4; ++mi) {
      const int m0 = (w << 6) + mi * 16;
      const bf16x8 a0 = *(const bf16x8*)(omb + (m0 + fr) * 64 + fg * 8);
      const bf16x8 a1 = *(const bf16x8*)(omb + (m0 + fr) * 64 + 32 + fg * 8);
#pragma unroll
      for (int tt = 0; tt < 4; ++tt) {
        const bf16x8 b0 = *(const bf16x8*)(kg + (tt * 16 + fr) * 64 + fg * 8);
        const bf16x8 b1 = *(const bf16x8*)(kg + (tt * 16 + fr) * 64 + 32 + fg * 8);
        f32x4 acc = {0.f, 0.f, 0.f, 0.f};
        acc = MFMA16(a0, b0, acc);
        acc = MFMA16(a1, b1, acc);
        const float nhv = nh[tt * 16 + fr];   // col t = tt*16+fr (lane-fixed)
#pragma unroll
        for (int r = 0; r < 4; ++r)
          sPhi[m0 + fg * 4 + r][tt * 16 + fr] = f2bf(__expf(acc[r] - nhv) * 0.0625f);
      }
    }
    __syncthreads();
    // KV += v^T @ phi^T over t (K=64 -> 2 MFMAs); ksum += phi^T @ ones
#pragma unroll
    for (int mi = 0; mi < 4; ++mi) {
      const int m0 = (w << 6) + mi * 16;
      const bf16x8 pb0 = *(const bf16x8*)&sPhi[m0 + fr][fg * 8];
      const bf16x8 pb1 = *(const bf16x8*)&sPhi[m0 + fr][32 + fg * 8];
      ksacc[mi] = MFMA16(pb0, ones, ksacc[mi]);
      ksacc[mi] = MFMA16(pb1, ones, ksacc[mi]);
#pragma unroll
      for (int dj = 0; dj < 4; ++dj) {
        const bf16x8 va0 = *(const bf16x8*)&sVt[dj * 16 + fr][fg * 8];
        const bf16x8 va1 = *(const bf16x8*)&sVt[dj * 16 + fr][32 + fg * 8];
        kvacc[mi][dj] = MFMA16(va0, pb0, kvacc[mi][dj]);
        kvacc[mi][dj] = MFMA16(va1, pb1, kvacc[mi][dj]);
      }
    }
  }
  // write state: st[d*256 + m], d = dj*16+fg*4+r, m = w*64+mi*16+fr
  float* st = state + ((size_t)bh * NSC + sc) * ST_STRIDE;
#pragma unroll
  for (int mi = 0; mi < 4; ++mi) {
    const int m = (w << 6) + mi * 16 + fr;
#pragma unroll
    for (int dj = 0; dj < 4; ++dj)
#pragma unroll
      for (int r = 0; r < 4; ++r)
        st[(size_t)(dj * 16 + fg * 4 + r) * M_ + m] = kvacc[mi][dj][r];
    if (fr == 0) {   // ksum: D cols identical; take col 0
#pragma unroll
      for (int r = 0; r < 4; ++r)
        st[M_ * D_ + (w << 6) + mi * 16 + fg * 4 + r] = ksacc[mi][r];
    }
  }
}

// ---------------- parallel exclusive prefix over superchunks --------------
__global__ __launch_bounds__(256) void scan_k(float* __restrict__ state) {
  const int bh = blockIdx.y;
  float* sb = state + (size_t)bh * NSC * ST_STRIDE;
  const int base = blockIdx.x * 2048 + threadIdx.x * 8;
  float run[8] = {};
  for (int cc = 0; cc < NSC; ++cc) {
    float* st = sb + (size_t)cc * ST_STRIDE + base;
    float4 t0 = *(float4*)st;
    float4 t1 = *(float4*)(st + 4);
    *(float4*)st       = make_float4(run[0], run[1], run[2], run[3]);
    *(float4*)(st + 4) = make_float4(run[4], run[5], run[6], run[7]);
    run[0] += t0.x; run[1] += t0.y; run[2] += t0.z; run[3] += t0.w;
    run[4] += t1.x; run[5] += t1.y; run[6] += t1.z; run[7] += t1.w;
  }
  if (blockIdx.x == 0) {           // ksum tail
    float rk = 0.f;
    for (int cc = 0; cc < NSC; ++cc) {
      float* p = sb + (size_t)cc * ST_STRIDE + M_ * D_ + threadIdx.x;
      const float t = *p;
      *p = rk;
      rk += t;
    }
  }
}

// ---------------- outchunk: full MFMA -------------------------------------
// phi quadrant: dst[t][j*16+fr] = exp(omb_q[m].x_t - nh[t])/16  (64t x 64m)
static __device__ __forceinline__ void phi_quad(
    const u16* __restrict__ xg, const u16* __restrict__ ombq,
    u16* __restrict__ dst, int dstride, const float* __restrict__ nh,
    int w, int lane) {
  const int fr = lane & 15, fg = lane >> 4;
  const int tband = w * 16;
  const bf16x8 a0 = *(const bf16x8*)(xg + (tband + fr) * 64 + fg * 8);
  const bf16x8 a1 = *(const bf16x8*)(xg + (tband + fr) * 64 + 32 + fg * 8);
  float nhv[4];
#pragma unroll
  for (int r = 0; r < 4; ++r) nhv[r] = nh[tband + fg * 4 + r];
#pragma unroll
  for (int j = 0; j < 4; ++j) {
    const bf16x8 b0 = *(const bf16x8*)(ombq + (j * 16 + fr) * 64 + fg * 8);
    const bf16x8 b1 = *(const bf16x8*)(ombq + (j * 16 + fr) * 64 + 32 + fg * 8);
    f32x4 acc = {0.f, 0.f, 0.f, 0.f};
    acc = MFMA16(a0, b0, acc);
    acc = MFMA16(a1, b1, acc);
#pragma unroll
    for (int r = 0; r < 4; ++r) {
      const int t = tband + fg * 4 + r;
      dst[t * dstride + j * 16 + fr] = f2bf(__expf(acc[r] - nhv[r]) * 0.0625f);
    }
  }
}

__global__ __launch_bounds__(256) void outchunk_k(
    const u16* __restrict__ q, const u16* __restrict__ kk,
    const u16* __restrict__ v, const u16* __restrict__ omb,
    const float* __restrict__ state, u16* __restrict__ attn) {
  __shared__ u16 sA[64][264];     // Qp full        33,792 B
  __shared__ u16 sK[64][72];      // Kp quadrant     9,216 B
  __shared__ u16 sB1[64][72];     // kvT hi / vT     9,216 B
  __shared__ u16 sB2[64][72];     // kvT lo          9,216 B
  __shared__ u16 sS[64][72];      // S bf16          9,216 B
  __shared__ float ksum_l[256];
  __shared__ float nh_q[64], nh_k[64];
  __shared__ float ssq[64][4];
  __shared__ float dq[64][4];
  __shared__ float sden[64];
  const int tid = threadIdx.x, lane = tid & 63, w = tid >> 6;
  const int fr = lane & 15, fg = lane >> 4;
  const int bh = blockIdx.x >> 6, c = blockIdx.x & 63;
  const int sc = c >> 2;
  const size_t tok0 = (size_t)bh * L_ + (size_t)c * 64;
  const u16* qg = q + tok0 * 64;
  const float* stg = state + ((size_t)bh * NSC + sc) * ST_STRIDE;

  ksum_l[tid] = stg[M_ * D_ + tid];
  sumsq_tile(qg, ssq, nh_q, tid);
#pragma unroll 1
  for (int mq = 0; mq < 4; ++mq)
    phi_quad(qg, omb + mq * 4096, &sA[0][mq * 64], 264, nh_q, w, lane);
  __syncthreads();

  // den: ksum part. thread = (t=lane, quadrant=w)
  {
    float s = 0.f;
#pragma unroll
    for (int g8 = 0; g8 < 8; ++g8) {
      bf16x8 qv = *(const bf16x8*)&sA[lane][w * 64 + g8 * 8];
#pragma unroll
      for (int e = 0; e < 8; ++e)
        s += bf2f((u16)qv[e]) * ksum_l[w * 64 + g8 * 8 + e];
    }
    dq[lane][w] = s;
  }

  f32x4 oacc[4] = {};
  // ---- cross term: Qp @ KVex (hi/lo), 4 feature quadrants
#pragma unroll 1
  for (int mq = 0; mq < 4; ++mq) {
    {
      const int d = tid >> 2, seg = tid & 3;
      const float* sp = stg + (size_t)d * M_ + mq * 64 + seg * 16;
      u16* ph = &sB1[d][seg * 16];
      u16* pl = &sB2[d][seg * 16];
#pragma unroll
      for (int e = 0; e < 16; ++e) {
        const float f = sp[e];
        const u16 hi = f2bf(f);
        ph[e] = hi;
        pl[e] = f2bf(f - bf2f(hi));
      }
    }
    __syncthreads();
    const bf16x8 a0 = *(const bf16x8*)&sA[w * 16 + fr][mq * 64 + fg * 8];
    const bf16x8 a1 = *(const bf16x8*)&sA[w * 16 + fr][mq * 64 + 32 + fg * 8];
#pragma unroll
    for (int j = 0; j < 4; ++j) {
      const bf16x8 bh0 = *(const bf16x8*)&sB1[j * 16 + fr][fg * 8];
      const bf16x8 bh1 = *(const bf16x8*)&sB1[j * 16 + fr][32 + fg * 8];
      const bf16x8 bl0 = *(const bf16x8*)&sB2[j * 16 + fr][fg * 8];
      const bf16x8 bl1 = *(const bf16x8*)&sB2[j * 16 + fr][32 + fg * 8];
      oacc[j] = MFMA16(a0, bh0, oacc[j]);
      oacc[j] = MFMA16(a1, bh1, oacc[j]);
      oacc[j] = MFMA16(a0, bl0, oacc[j]);
      oacc[j] = MFMA16(a1, bl1, oacc[j]);
    }
    __syncthreads();
  }

  // ---- source chunks in superchunk
#pragma unroll 1
  for (int s_c = sc * 4; s_c <= c; ++s_c) {
    const size_t ktok = (size_t)bh * L_ + (size_t)s_c * 64;
    const u16* kg = kk + ktok * 64;
    sumsq_tile(kg, ssq, nh_k, tid);
    f32x4 sacc[4] = {};
#pragma unroll 1
    for (int mq = 0; mq < 4; ++mq) {
      phi_quad(kg, omb + mq * 4096, &sK[0][0], 72, nh_k, w, lane);
      __syncthreads();
      const bf16x8 a0 = *(const bf16x8*)&sA[w * 16 + fr][mq * 64 + fg * 8];
      const bf16x8 a1 = *(const bf16x8*)&sA[w * 16 + fr][mq * 64 + 32 + fg * 8];
#pragma unroll
      for (int j = 0; j < 4; ++j) {
        const bf16x8 b0 = *(const bf16x8*)&sK[j * 16 + fr][fg * 8];
        const bf16x8 b1 = *(const bf16x8*)&sK[j * 16 + fr][32 + fg * 8];
        sacc[j] = MFMA16(a0, b0, sacc[j]);
        sacc[j] = MFMA16(a1, b1, sacc[j]);
      }
      __syncthreads();
    }
    const bool diag = (s_c == c);
#pragma unroll
    for (int j = 0; j < 4; ++j)
#pragma unroll
      for (int r = 0; r < 4; ++r) {
        const int s = j * 16 + fr, t = w * 16 + fg * 4 + r;
        float val = sacc[j][r];
        if (diag && s > t) val = 0.f;
        sS[t][s] = f2bf(val);
      }
    __syncthreads();
    // den contribution + vT staging
    {
      float s = 0.f;
      bf16x8 s0 = *(const bf16x8*)&sS[lane][w * 16];
      bf16x8 s1 = *(const bf16x8*)&sS[lane][w * 16 + 8];
#pragma unroll
      for (int e = 0; e < 8; ++e) s += bf2f((u16)s0[e]) + bf2f((u16)s1[e]);
      dq[lane][w] += s;
      const u16* vp = v + (ktok + lane) * 64 + w * 16;
      bf16x8 v0 = *(const bf16x8*)(vp);
      bf16x8 v1 = *(const bf16x8*)(vp + 8);
#pragma unroll
      for (int e = 0; e < 8; ++e) sB1[w * 16 + e][lane] = (u16)v0[e];
#pragma unroll
      for (int e = 0; e < 8; ++e) sB1[w * 16 + 8 + e][lane] = (u16)v1[e];
    }
    __syncthreads();
    // S @ V
    {
      const bf16x8 a0 = *(const bf16x8*)&sS[w * 16 + fr][fg * 8];
      const bf16x8 a1 = *(const bf16x8*)&sS[w * 16 + fr][32 + fg * 8];
#pragma unroll
      for (int j = 0; j < 4; ++j) {
        const bf16x8 b0 = *(const bf16x8*)&sB1[j * 16 + fr][fg * 8];
        const bf16x8 b1 = *(const bf16x8*)&sB1[j * 16 + fr][32 + fg * 8];
        oacc[j] = MFMA16(a0, b0, oacc[j]);
        oacc[j] = MFMA16(a1, b1, oacc[j]);
      }
    }
    __syncthreads();
  }

  if (tid < 64)
    sden[tid] = 1.0f / (dq[tid][0] + dq[tid][1] + dq[tid][2] + dq[tid][3] + 1e-6f);
  __syncthreads();
  const int b = bh >> 4, hh = bh & 15;
#pragma unroll
  for (int j = 0; j < 4; ++j)
#pragma unroll
    for (int r = 0; r < 4; ++r) {
      const int t = w * 16 + fg * 4 + r;
      const int d = j * 16 + fr;
      const int l = c * 64 + t;
      attn[((size_t)b * L_ + l) * DM_ + hh * 64 + d] = f2bf(oacc[j][r] * sden[t]);
    }
}

extern "C" void kernel_launch(void* const* d_in, const int* in_sizes, int n_in,
                              void* d_out, int out_size, void* d_ws, size_t ws_size,
                              hipStream_t stream) {
  const float* x     = (const float*)d_in[0];
  const float* Wq    = (const float*)d_in[1];
  const float* bq    = (const float*)d_in[2];
  const float* Wk    = (const float*)d_in[3];
  const float* bk    = (const float*)d_in[4];
  const float* Wv    = (const float*)d_in[5];
  const float* bv    = (const float*)d_in[6];
  const float* Wo    = (const float*)d_in[7];
  const float* bo    = (const float*)d_in[8];
  const float* omega = (const float*)d_in[9];
  float* out = (float*)d_out;

  char* ws = (char*)d_ws;
  u16*   v     = (u16*)(ws);                            // 32 MB
  u16*   qb    = (u16*)(ws + 33554432ull);              // 32 MB
  u16*   kb    = (u16*)(ws + 67108864ull);              // 32 MB
  u16*   xb    = (u16*)(ws + 100663296ull);             // 32 MB (alias attn)
  u16*   attn  = xb;
  float* state = (float*)(ws + 134217728ull);           // 68.16 MB
  u16*   Wt    = (u16*)(ws + 202375168ull);             // 8 MB
  u16*   omb   = (u16*)(ws + 210763776ull);             // 32 KB

  convx_k<<<16384, 256, 0, stream>>>(x, xb);
  convw_k<<<dim3(16, 16, 4), 256, 0, stream>>>(Wq, Wk, Wv, Wo, Wt);
  convom_k<<<64, 256, 0, stream>>>(omega, omb);

  const dim3 gg(8, 128);
  mm_k<0><<<gg, 256, 0, stream>>>(xb, Wt,                 bq, qb);
  mm_k<0><<<gg, 256, 0, stream>>>(xb, Wt + 1048576ull,    bk, kb);
  mm_k<0><<<gg, 256, 0, stream>>>(xb, Wt + 2097152ull,    bv, v);
  kvstate_k<<<dim3(NSC, BH_), 256, 0, stream>>>(kb, v, omb, state);
  scan_k<<<dim3(8, BH_), 256, 0, stream>>>(state);
  outchunk_k<<<BH_ * 64, 256, 0, stream>>>(qb, kb, v, omb, state, attn);
  mm_k<1><<<gg, 256, 0, stream>>>(attn, Wt + 3145728ull,  bo, out);
}

// Round 6
// 741.383 us; speedup vs baseline: 11.9781x; 1.4249x over previous
//
#include <hip/hip_runtime.h>
#include <hip/hip_bf16.h>

// FAVOR+ attention, MI355X. Round 6: bisection round.
//  - mm_k: R5's LDS-staged XOR-swizzled GEMM (formally verified)
//  - outchunk: R4's validated version + XCD-swizzled block id ONLY
//  - kvstate/scan/conv unchanged (validated)
//
// Workspace (bytes):
//   v    bf16 [64bh][4096][64] @ 0        (32 MB)
//   q    bf16                  @ 32 MB    (32 MB)
//   k    bf16                  @ 64 MB    (32 MB)
//   xb   bf16 [16384][1024]    @ 96 MB    (32 MB)  -- ALIASED with attn
//   state f32 [64bh][16][16640]@ 128 MB   (65 MB)
//   Wt   bf16 4x[1024][1024]   @ 202,375,168  (8 MB)
//   omb  bf16 [256][64]        @ 210,763,776  (32 KB)   total ~201 MB

#define B_ 4
#define H_ 16
#define L_ 4096
#define D_ 64
#define M_ 256
#define DM_ 1024
#define BH_ 64
#define NSC 16
#define ST_STRIDE (M_*D_ + M_)   // 16640 floats

typedef unsigned int u32;
typedef unsigned short u16;
typedef __attribute__((ext_vector_type(8))) short bf16x8;
typedef __attribute__((ext_vector_type(4))) float f32x4;

static __device__ __forceinline__ float bf2f(u16 u) {
  return __uint_as_float(((u32)u) << 16);
}
static __device__ __forceinline__ u16 f2bf(float f) {
  u32 x = __float_as_uint(f);
  return (u16)((x + 0x7fffu + ((x >> 16) & 1u)) >> 16);   // RNE
}
#define MFMA16(a, b, c) __builtin_amdgcn_mfma_f32_16x16x32_bf16((a), (b), (c), 0, 0, 0)

// ---------------- converters ----------------------------------------------
__global__ __launch_bounds__(256) void convx_k(const float* __restrict__ x,
                                               u16* __restrict__ xb) {
  const int i = blockIdx.x * 256 + threadIdx.x;
  float4 f = ((const float4*)x)[i];
  ushort4 u;
  u.x = f2bf(f.x); u.y = f2bf(f.y); u.z = f2bf(f.z); u.w = f2bf(f.w);
  ((ushort4*)xb)[i] = u;
}

__global__ __launch_bounds__(256) void convw_k(
    const float* __restrict__ W0, const float* __restrict__ W1,
    const float* __restrict__ W2, const float* __restrict__ W3,
    u16* __restrict__ out) {
  __shared__ u16 tt[64][66];
  const int z = blockIdx.z;
  const float* W = (z == 0) ? W0 : (z == 1) ? W1 : (z == 2) ? W2 : W3;
  u16* o = out + (size_t)z * 1048576ull;
  const int k0 = blockIdx.y * 64, n0 = blockIdx.x * 64;
  const int r = threadIdx.x >> 4, c4 = (threadIdx.x & 15) << 2;
  for (int rr = r; rr < 64; rr += 16) {
    float4 w4 = *(const float4*)(W + (size_t)(k0 + rr) * DM_ + n0 + c4);
    tt[c4 + 0][rr] = f2bf(w4.x);
    tt[c4 + 1][rr] = f2bf(w4.y);
    tt[c4 + 2][rr] = f2bf(w4.z);
    tt[c4 + 3][rr] = f2bf(w4.w);
  }
  __syncthreads();
  for (int rr = r; rr < 64; rr += 16) {
    ushort4 u4;
    u4.x = tt[rr][c4 + 0];
    u4.y = tt[rr][c4 + 1];
    u4.z = tt[rr][c4 + 2];
    u4.w = tt[rr][c4 + 3];
    *(ushort4*)(o + (size_t)(n0 + rr) * DM_ + k0 + c4) = u4;
  }
}

__global__ __launch_bounds__(256) void convom_k(const float* __restrict__ om,
                                                u16* __restrict__ omb) {
  const int i = blockIdx.x * 256 + threadIdx.x;
  omb[i] = f2bf(om[i] * 0.35355339059327373f);       // fold 64^-0.25
}

// ---------------- bf16 MFMA GEMM, LDS-staged -------------------------------
// out = A[16384x1024] @ W + bias, W given transposed Bt[n][k].
// MODE 0: bf16 head layout [bh][l][64]; MODE 1: f32 row-major [m][1024].
template<int MODE>
__global__ __launch_bounds__(256) void mm_k(
    const u16* __restrict__ A, const u16* __restrict__ Bt,
    const float* __restrict__ bias, void* __restrict__ outp) {
  __shared__ u16 sA[128][64];   // 16 KB, XOR-swizzled 16B slots
  __shared__ u16 sB[128][64];   // 16 KB
  const int tid = threadIdx.x, lane = tid & 63, w = tid >> 6;
  const int fr = lane & 15, fg = lane >> 4;
  const int wr = w >> 1, wc = w & 1;
  const int m0 = blockIdx.y * 128, n0 = blockIdx.x * 128;
  const int srow = tid >> 3, sslot = tid & 7;   // +p*32 rows per pass
  f32x4 acc[4][4] = {};
  bf16x8 av[4], bv[4];
#pragma unroll
  for (int p = 0; p < 4; ++p) {
    av[p] = *(const bf16x8*)(A  + (size_t)(m0 + srow + p * 32) * DM_ + sslot * 8);
    bv[p] = *(const bf16x8*)(Bt + (size_t)(n0 + srow + p * 32) * DM_ + sslot * 8);
  }
  for (int k0 = 0; k0 < DM_; k0 += 64) {
    __syncthreads();
#pragma unroll
    for (int p = 0; p < 4; ++p) {
      const int r = srow + p * 32;
      *(bf16x8*)&sA[r][(sslot ^ (r & 7)) * 8] = av[p];
      *(bf16x8*)&sB[r][(sslot ^ (r & 7)) * 8] = bv[p];
    }
    if (k0 + 64 < DM_) {
#pragma unroll
      for (int p = 0; p < 4; ++p) {
        av[p] = *(const bf16x8*)(A  + (size_t)(m0 + srow + p * 32) * DM_ + k0 + 64 + sslot * 8);
        bv[p] = *(const bf16x8*)(Bt + (size_t)(n0 + srow + p * 32) * DM_ + k0 + 64 + sslot * 8);
      }
    }
    __syncthreads();
#pragma unroll
    for (int ks = 0; ks < 2; ++ks) {
      bf16x8 af[4], bf[4];
#pragma unroll
      for (int i = 0; i < 4; ++i) {
        const int r = wr * 64 + i * 16 + fr;
        af[i] = *(const bf16x8*)&sA[r][((ks * 4 + fg) ^ (r & 7)) * 8];
      }
#pragma unroll
      for (int j = 0; j < 4; ++j) {
        const int r = wc * 64 + j * 16 + fr;
        bf[j] = *(const bf16x8*)&sB[r][((ks * 4 + fg) ^ (r & 7)) * 8];
      }
#pragma unroll
      for (int i = 0; i < 4; ++i)
#pragma unroll
        for (int j = 0; j < 4; ++j)
          acc[i][j] = MFMA16(af[i], bf[j], acc[i][j]);
    }
  }
  const int m_blk = m0 + wr * 64, n_blk = n0 + wc * 64;
#pragma unroll
  for (int j = 0; j < 4; ++j) {
    const int n = n_blk + j * 16 + fr;
    const float bi = bias[n];
    const int h = n >> 6, d = n & 63;
#pragma unroll
    for (int i = 0; i < 4; ++i) {
#pragma unroll
      for (int r = 0; r < 4; ++r) {
        const int m = m_blk + i * 16 + fg * 4 + r;
        const float val = acc[i][j][r] + bi;
        if (MODE == 0) {
          const int b = m >> 12, l = m & 4095;
          ((u16*)outp)[((size_t)(b * H_ + h) * L_ + l) * D_ + d] = f2bf(val);
        } else {
          ((float*)outp)[(size_t)m * DM_ + n] = val;
        }
      }
    }
  }
}

// ---------------- shared: per-64-token sumsq -> nh[t] = ||x_t||^2/16 ------
static __device__ __forceinline__ void sumsq_tile(
    const u16* __restrict__ xg, float (*ssq)[4], float* __restrict__ nh, int tid) {
  const int t = tid >> 2, qt = tid & 3;
  const u16* xp = xg + t * 64 + qt * 16;
  float s = 0.f;
#pragma unroll
  for (int jj = 0; jj < 2; ++jj) {
    bf16x8 xv = *(const bf16x8*)(xp + jj * 8);
#pragma unroll
    for (int e = 0; e < 8; ++e) { const float f = bf2f((u16)xv[e]); s += f * f; }
  }
  ssq[t][qt] = s;
  __syncthreads();
  if (tid < 64)
    nh[tid] = 0.0625f * (ssq[tid][0] + ssq[tid][1] + ssq[tid][2] + ssq[tid][3]);
  __syncthreads();
}

// ---------------- kvstate (MFMA): state[d][m] = sum_t v[t][d] phi_k[t][m] --
__global__ __launch_bounds__(256) void kvstate_k(
    const u16* __restrict__ k, const u16* __restrict__ v,
    const u16* __restrict__ omb, float* __restrict__ state) {
  __shared__ u16 sPhi[256][72];
  __shared__ u16 sVt[64][72];
  __shared__ float ssq[64][4];
  __shared__ float nh[64];
  const int tid = threadIdx.x, lane = tid & 63, w = tid >> 6;
  const int fr = lane & 15, fg = lane >> 4;
  const int sc = blockIdx.x, bh = blockIdx.y;
  const size_t base_l = (size_t)bh * L_ + (size_t)sc * 256;

  bf16x8 ones;
#pragma unroll
  for (int e = 0; e < 8; ++e) ones[e] = (short)0x3F80;

  f32x4 kvacc[4][4] = {};
  f32x4 ksacc[4] = {};

  for (int sub = 0; sub < 4; ++sub) {
    const size_t tl = base_l + sub * 64;
    const u16* kg = k + tl * 64;
    __syncthreads();
    {
      const u16* vp = v + (tl + lane) * 64 + w * 16;
      bf16x8 v0 = *(const bf16x8*)(vp);
      bf16x8 v1 = *(const bf16x8*)(vp + 8);
#pragma unroll
      for (int e = 0; e < 8; ++e) sVt[w * 16 + e][lane] = (u16)v0[e];
#pragma unroll
      for (int e = 0; e < 8; ++e) sVt[w * 16 + 8 + e][lane] = (u16)v1[e];
    }
    sumsq_tile(kg, ssq, nh, tid);
#pragma unroll
    for (int mi = 0; mi < 4; ++mi) {
      const int m0 = (w << 6) + mi * 16;
      const bf16x8 a0 = *(const bf16x8*)(omb + (m0 + fr) * 64 + fg * 8);
      const bf16x8 a1 = *(const bf16x8*)(omb + (m0 + fr) * 64 + 32 + fg * 8);
#pragma unroll
      for (int tt = 0; tt < 4; ++tt) {
        const bf16x8 b0 = *(const bf16x8*)(kg + (tt * 16 + fr) * 64 + fg * 8);
        const bf16x8 b1 = *(const bf16x8*)(kg + (tt * 16 + fr) * 64 + 32 + fg * 8);
        f32x4 acc = {0.f, 0.f, 0.f, 0.f};
        acc = MFMA16(a0, b0, acc);
        acc = MFMA16(a1, b1, acc);
        const float nhv = nh[tt * 16 + fr];
#pragma unroll
        for (int r = 0; r < 4; ++r)
          sPhi[m0 + fg * 4 + r][tt * 16 + fr] = f2bf(__expf(acc[r] - nhv) * 0.0625f);
      }
    }
    __syncthreads();
#pragma unroll
    for (int mi = 0; mi < 4; ++mi) {
      const int m0 = (w << 6) + mi * 16;
      const bf16x8 pb0 = *(const bf16x8*)&sPhi[m0 + fr][fg * 8];
      const bf16x8 pb1 = *(const bf16x8*)&sPhi[m0 + fr][32 + fg * 8];
      ksacc[mi] = MFMA16(pb0, ones, ksacc[mi]);
      ksacc[mi] = MFMA16(pb1, ones, ksacc[mi]);
#pragma unroll
      for (int dj = 0; dj < 4; ++dj) {
        const bf16x8 va0 = *(const bf16x8*)&sVt[dj * 16 + fr][fg * 8];
        const bf16x8 va1 = *(const bf16x8*)&sVt[dj * 16 + fr][32 + fg * 8];
        kvacc[mi][dj] = MFMA16(va0, pb0, kvacc[mi][dj]);
        kvacc[mi][dj] = MFMA16(va1, pb1, kvacc[mi][dj]);
      }
    }
  }
  float* st = state + ((size_t)bh * NSC + sc) * ST_STRIDE;
#pragma unroll
  for (int mi = 0; mi < 4; ++mi) {
    const int m = (w << 6) + mi * 16 + fr;
#pragma unroll
    for (int dj = 0; dj < 4; ++dj)
#pragma unroll
      for (int r = 0; r < 4; ++r)
        st[(size_t)(dj * 16 + fg * 4 + r) * M_ + m] = kvacc[mi][dj][r];
    if (fr == 0) {
#pragma unroll
      for (int r = 0; r < 4; ++r)
        st[M_ * D_ + (w << 6) + mi * 16 + fg * 4 + r] = ksacc[mi][r];
    }
  }
}

// ---------------- parallel exclusive prefix over superchunks --------------
__global__ __launch_bounds__(256) void scan_k(float* __restrict__ state) {
  const int bh = blockIdx.y;
  float* sb = state + (size_t)bh * NSC * ST_STRIDE;
  const int base = blockIdx.x * 2048 + threadIdx.x * 8;
  float run[8] = {};
  for (int cc = 0; cc < NSC; ++cc) {
    float* st = sb + (size_t)cc * ST_STRIDE + base;
    float4 t0 = *(float4*)st;
    float4 t1 = *(float4*)(st + 4);
    *(float4*)st       = make_float4(run[0], run[1], run[2], run[3]);
    *(float4*)(st + 4) = make_float4(run[4], run[5], run[6], run[7]);
    run[0] += t0.x; run[1] += t0.y; run[2] += t0.z; run[3] += t0.w;
    run[4] += t1.x; run[5] += t1.y; run[6] += t1.z; run[7] += t1.w;
  }
  if (blockIdx.x == 0) {
    float rk = 0.f;
    for (int cc = 0; cc < NSC; ++cc) {
      float* p = sb + (size_t)cc * ST_STRIDE + M_ * D_ + threadIdx.x;
      const float t = *p;
      *p = rk;
      rk += t;
    }
  }
}

// ---------------- outchunk: full MFMA (R4-validated) + XCD swizzle ---------
// phi quadrant: dst[t][j*16+fr] = exp(omb_q[m].x_t - nh[t])/16  (64t x 64m)
static __device__ __forceinline__ void phi_quad(
    const u16* __restrict__ xg, const u16* __restrict__ ombq,
    u16* __restrict__ dst, int dstride, const float* __restrict__ nh,
    int w, int lane) {
  const int fr = lane & 15, fg = lane >> 4;
  const int tband = w * 16;
  const bf16x8 a0 = *(const bf16x8*)(xg + (tband + fr) * 64 + fg * 8);
  const bf16x8 a1 = *(const bf16x8*)(xg + (tband + fr) * 64 + 32 + fg * 8);
  float nhv[4];
#pragma unroll
  for (int r = 0; r < 4; ++r) nhv[r] = nh[tband + fg * 4 + r];
#pragma unroll
  for (int j = 0; j < 4; ++j) {
    const bf16x8 b0 = *(const bf16x8*)(ombq + (j * 16 + fr) * 64 + fg * 8);
    const bf16x8 b1 = *(const bf16x8*)(ombq + (j * 16 + fr) * 64 + 32 + fg * 8);
    f32x4 acc = {0.f, 0.f, 0.f, 0.f};
    acc = MFMA16(a0, b0, acc);
    acc = MFMA16(a1, b1, acc);
#pragma unroll
    for (int r = 0; r < 4; ++r) {
      const int t = tband + fg * 4 + r;
      dst[t * dstride + j * 16 + fr] = f2bf(__expf(acc[r] - nhv[r]) * 0.0625f);
    }
  }
}

__global__ __launch_bounds__(256) void outchunk_k(
    const u16* __restrict__ q, const u16* __restrict__ kk,
    const u16* __restrict__ v, const u16* __restrict__ omb,
    const float* __restrict__ state, u16* __restrict__ attn) {
  __shared__ u16 sA[64][264];     // Qp full        33,792 B
  __shared__ u16 sK[64][72];      // Kp quadrant     9,216 B
  __shared__ u16 sB1[64][72];     // state hi / vT   9,216 B
  __shared__ u16 sB2[64][72];     // state lo        9,216 B
  __shared__ u16 sS[64][72];      // S bf16          9,216 B
  __shared__ float ksum_l[256];
  __shared__ float nh_q[64], nh_k[64];
  __shared__ float ssq[64][4];
  __shared__ float dq[64][4];
  __shared__ float sden[64];
  const int tid = threadIdx.x, lane = tid & 63, w = tid >> 6;
  const int fr = lane & 15, fg = lane >> 4;
  // XCD swizzle: 4 chunks of a superchunk -> same XCD (state L2-resident)
  const int lbid = ((blockIdx.x & 7) << 9) | (blockIdx.x >> 3);
  const int bh = lbid >> 6, c = lbid & 63;
  const int sc = c >> 2;
  const size_t tok0 = (size_t)bh * L_ + (size_t)c * 64;
  const u16* qg = q + tok0 * 64;
  const float* stg = state + ((size_t)bh * NSC + sc) * ST_STRIDE;

  ksum_l[tid] = stg[M_ * D_ + tid];
  sumsq_tile(qg, ssq, nh_q, tid);
#pragma unroll 1
  for (int mq = 0; mq < 4; ++mq)
    phi_quad(qg, omb + mq * 4096, &sA[0][mq * 64], 264, nh_q, w, lane);
  __syncthreads();

  // den: ksum part. thread = (t=lane, quadrant=w)
  {
    float s = 0.f;
#pragma unroll
    for (int g8 = 0; g8 < 8; ++g8) {
      bf16x8 qv = *(const bf16x8*)&sA[lane][w * 64 + g8 * 8];
#pragma unroll
      for (int e = 0; e < 8; ++e)
        s += bf2f((u16)qv[e]) * ksum_l[w * 64 + g8 * 8 + e];
    }
    dq[lane][w] = s;
  }

  f32x4 oacc[4] = {};
  // ---- cross term: Qp @ KVex (hi/lo), 4 feature quadrants
#pragma unroll 1
  for (int mq = 0; mq < 4; ++mq) {
    {
      const int d = tid >> 2, seg = tid & 3;
      const float* sp = stg + (size_t)d * M_ + mq * 64 + seg * 16;
      u16* ph = &sB1[d][seg * 16];
      u16* pl = &sB2[d][seg * 16];
#pragma unroll
      for (int e = 0; e < 16; ++e) {
        const float f = sp[e];
        const u16 hi = f2bf(f);
        ph[e] = hi;
        pl[e] = f2bf(f - bf2f(hi));
      }
    }
    __syncthreads();
    const bf16x8 a0 = *(const bf16x8*)&sA[w * 16 + fr][mq * 64 + fg * 8];
    const bf16x8 a1 = *(const bf16x8*)&sA[w * 16 + fr][mq * 64 + 32 + fg * 8];
#pragma unroll
    for (int j = 0; j < 4; ++j) {
      const bf16x8 bh0 = *(const bf16x8*)&sB1[j * 16 + fr][fg * 8];
      const bf16x8 bh1 = *(const bf16x8*)&sB1[j * 16 + fr][32 + fg * 8];
      const bf16x8 bl0 = *(const bf16x8*)&sB2[j * 16 + fr][fg * 8];
      const bf16x8 bl1 = *(const bf16x8*)&sB2[j * 16 + fr][32 + fg * 8];
      oacc[j] = MFMA16(a0, bh0, oacc[j]);
      oacc[j] = MFMA16(a1, bh1, oacc[j]);
      oacc[j] = MFMA16(a0, bl0, oacc[j]);
      oacc[j] = MFMA16(a1, bl1, oacc[j]);
    }
    __syncthreads();
  }

  // ---- source chunks in superchunk
#pragma unroll 1
  for (int s_c = sc * 4; s_c <= c; ++s_c) {
    const size_t ktok = (size_t)bh * L_ + (size_t)s_c * 64;
    const u16* kg = kk + ktok * 64;
    sumsq_tile(kg, ssq, nh_k, tid);
    f32x4 sacc[4] = {};
#pragma unroll 1
    for (int mq = 0; mq < 4; ++mq) {
      phi_quad(kg, omb + mq * 4096, &sK[0][0], 72, nh_k, w, lane);
      __syncthreads();
      const bf16x8 a0 = *(const bf16x8*)&sA[w * 16 + fr][mq * 64 + fg * 8];
      const bf16x8 a1 = *(const bf16x8*)&sA[w * 16 + fr][mq * 64 + 32 + fg * 8];
#pragma unroll
      for (int j = 0; j < 4; ++j) {
        const bf16x8 b0 = *(const bf16x8*)&sK[j * 16 + fr][fg * 8];
        const bf16x8 b1 = *(const bf16x8*)&sK[j * 16 + fr][32 + fg * 8];
        sacc[j] = MFMA16(a0, b0, sacc[j]);
        sacc[j] = MFMA16(a1, b1, sacc[j]);
      }
      __syncthreads();
    }
    const bool diag = (s_c == c);
#pragma unroll
    for (int j = 0; j < 4; ++j)
#pragma unroll
      for (int r = 0; r < 4; ++r) {
        const int s = j * 16 + fr, t = w * 16 + fg * 4 + r;
        float val = sacc[j][r];
        if (diag && s > t) val = 0.f;
        sS[t][s] = f2bf(val);
      }
    __syncthreads();
    // den contribution + vT staging
    {
      float s = 0.f;
      bf16x8 s0 = *(const bf16x8*)&sS[lane][w * 16];
      bf16x8 s1 = *(const bf16x8*)&sS[lane][w * 16 + 8];
#pragma unroll
      for (int e = 0; e < 8; ++e) s += bf2f((u16)s0[e]) + bf2f((u16)s1[e]);
      dq[lane][w] += s;
      const u16* vp = v + (ktok + lane) * 64 + w * 16;
      bf16x8 v0 = *(const bf16x8*)(vp);
      bf16x8 v1 = *(const bf16x8*)(vp + 8);
#pragma unroll
      for (int e = 0; e < 8; ++e) sB1[w * 16 + e][lane] = (u16)v0[e];
#pragma unroll
      for (int e = 0; e < 8; ++e) sB1[w * 16 + 8 + e][lane] = (u16)v1[e];
    }
    __syncthreads();
    // S @ V
    {
      const bf16x8 a0 = *(const bf16x8*)&sS[w * 16 + fr][fg * 8];
      const bf16x8 a1 = *(const bf16x8*)&sS[w * 16 + fr][32 + fg * 8];
#pragma unroll
      for (int j = 0; j < 4; ++j) {
        const bf16x8 b0 = *(const bf16x8*)&sB1[j * 16 + fr][fg * 8];
        const bf16x8 b1 = *(const bf16x8*)&sB1[j * 16 + fr][32 + fg * 8];
        oacc[j] = MFMA16(a0, b0, oacc[j]);
        oacc[j] = MFMA16(a1, b1, oacc[j]);
      }
    }
    __syncthreads();
  }

  if (tid < 64)
    sden[tid] = 1.0f / (dq[tid][0] + dq[tid][1] + dq[tid][2] + dq[tid][3] + 1e-6f);
  __syncthreads();
  const int b = bh >> 4, hh = bh & 15;
#pragma unroll
  for (int j = 0; j < 4; ++j)
#pragma unroll
    for (int r = 0; r < 4; ++r) {
      const int t = w * 16 + fg * 4 + r;
      const int d = j * 16 + fr;
      const int l = c * 64 + t;
      attn[((size_t)b * L_ + l) * DM_ + hh * 64 + d] = f2bf(oacc[j][r] * sden[t]);
    }
}

extern "C" void kernel_launch(void* const* d_in, const int* in_sizes, int n_in,
                              void* d_out, int out_size, void* d_ws, size_t ws_size,
                              hipStream_t stream) {
  const float* x     = (const float*)d_in[0];
  const float* Wq    = (const float*)d_in[1];
  const float* bq    = (const float*)d_in[2];
  const float* Wk    = (const float*)d_in[3];
  const float* bk    = (const float*)d_in[4];
  const float* Wv    = (const float*)d_in[5];
  const float* bv    = (const float*)d_in[6];
  const float* Wo    = (const float*)d_in[7];
  const float* bo    = (const float*)d_in[8];
  const float* omega = (const float*)d_in[9];
  float* out = (float*)d_out;

  char* ws = (char*)d_ws;
  u16*   v     = (u16*)(ws);                            // 32 MB
  u16*   qb    = (u16*)(ws + 33554432ull);              // 32 MB
  u16*   kb    = (u16*)(ws + 67108864ull);              // 32 MB
  u16*   xb    = (u16*)(ws + 100663296ull);             // 32 MB (alias attn)
  u16*   attn  = xb;
  float* state = (float*)(ws + 134217728ull);           // 68.16 MB
  u16*   Wt    = (u16*)(ws + 202375168ull);             // 8 MB
  u16*   omb   = (u16*)(ws + 210763776ull);             // 32 KB

  convx_k<<<16384, 256, 0, stream>>>(x, xb);
  convw_k<<<dim3(16, 16, 4), 256, 0, stream>>>(Wq, Wk, Wv, Wo, Wt);
  convom_k<<<64, 256, 0, stream>>>(omega, omb);

  const dim3 gg(8, 128);
  mm_k<0><<<gg, 256, 0, stream>>>(xb, Wt,                 bq, qb);
  mm_k<0><<<gg, 256, 0, stream>>>(xb, Wt + 1048576ull,    bk, kb);
  mm_k<0><<<gg, 256, 0, stream>>>(xb, Wt + 2097152ull,    bv, v);
  kvstate_k<<<dim3(NSC, BH_), 256, 0, stream>>>(kb, v, omb, state);
  scan_k<<<dim3(8, BH_), 256, 0, stream>>>(state);
  outchunk_k<<<BH_ * 64, 256, 0, stream>>>(qb, kb, v, omb, state, attn);
  mm_k<1><<<gg, 256, 0, stream>>>(attn, Wt + 3145728ull,  bo, out);
}

// Round 7
// 733.451 us; speedup vs baseline: 12.1077x; 1.0108x over previous
//
#include <hip/hip_runtime.h>
#include <hip/hip_bf16.h>

// FAVOR+ attention, MI355X. Round 7: outchunk occupancy attack (3 blocks/CU).
//  - outchunk: sS aliased onto sK, state staged bf16 (no hi/lo), shfl sumsq,
//    setprio around MFMA clusters, 52.5 KB LDS. Den via validated dq map.
//  - mm_k / kvstate / scan / convs: byte-identical to validated R6.
//
// Workspace (bytes):
//   v    bf16 [64bh][4096][64] @ 0        (32 MB)
//   q    bf16                  @ 32 MB    (32 MB)
//   k    bf16                  @ 64 MB    (32 MB)
//   xb   bf16 [16384][1024]    @ 96 MB    (32 MB)  -- ALIASED with attn
//   state f32 [64bh][16][16640]@ 128 MB   (65 MB)
//   Wt   bf16 4x[1024][1024]   @ 202,375,168  (8 MB)
//   omb  bf16 [256][64]        @ 210,763,776  (32 KB)   total ~201 MB

#define B_ 4
#define H_ 16
#define L_ 4096
#define D_ 64
#define M_ 256
#define DM_ 1024
#define BH_ 64
#define NSC 16
#define ST_STRIDE (M_*D_ + M_)   // 16640 floats

typedef unsigned int u32;
typedef unsigned short u16;
typedef __attribute__((ext_vector_type(8))) short bf16x8;
typedef __attribute__((ext_vector_type(4))) float f32x4;

static __device__ __forceinline__ float bf2f(u16 u) {
  return __uint_as_float(((u32)u) << 16);
}
static __device__ __forceinline__ u16 f2bf(float f) {
  u32 x = __float_as_uint(f);
  return (u16)((x + 0x7fffu + ((x >> 16) & 1u)) >> 16);   // RNE
}
#define MFMA16(a, b, c) __builtin_amdgcn_mfma_f32_16x16x32_bf16((a), (b), (c), 0, 0, 0)

// ---------------- converters ----------------------------------------------
__global__ __launch_bounds__(256) void convx_k(const float* __restrict__ x,
                                               u16* __restrict__ xb) {
  const int i = blockIdx.x * 256 + threadIdx.x;
  float4 f = ((const float4*)x)[i];
  ushort4 u;
  u.x = f2bf(f.x); u.y = f2bf(f.y); u.z = f2bf(f.z); u.w = f2bf(f.w);
  ((ushort4*)xb)[i] = u;
}

__global__ __launch_bounds__(256) void convw_k(
    const float* __restrict__ W0, const float* __restrict__ W1,
    const float* __restrict__ W2, const float* __restrict__ W3,
    u16* __restrict__ out) {
  __shared__ u16 tt[64][66];
  const int z = blockIdx.z;
  const float* W = (z == 0) ? W0 : (z == 1) ? W1 : (z == 2) ? W2 : W3;
  u16* o = out + (size_t)z * 1048576ull;
  const int k0 = blockIdx.y * 64, n0 = blockIdx.x * 64;
  const int r = threadIdx.x >> 4, c4 = (threadIdx.x & 15) << 2;
  for (int rr = r; rr < 64; rr += 16) {
    float4 w4 = *(const float4*)(W + (size_t)(k0 + rr) * DM_ + n0 + c4);
    tt[c4 + 0][rr] = f2bf(w4.x);
    tt[c4 + 1][rr] = f2bf(w4.y);
    tt[c4 + 2][rr] = f2bf(w4.z);
    tt[c4 + 3][rr] = f2bf(w4.w);
  }
  __syncthreads();
  for (int rr = r; rr < 64; rr += 16) {
    ushort4 u4;
    u4.x = tt[rr][c4 + 0];
    u4.y = tt[rr][c4 + 1];
    u4.z = tt[rr][c4 + 2];
    u4.w = tt[rr][c4 + 3];
    *(ushort4*)(o + (size_t)(n0 + rr) * DM_ + k0 + c4) = u4;
  }
}

__global__ __launch_bounds__(256) void convom_k(const float* __restrict__ om,
                                                u16* __restrict__ omb) {
  const int i = blockIdx.x * 256 + threadIdx.x;
  omb[i] = f2bf(om[i] * 0.35355339059327373f);       // fold 64^-0.25
}

// ---------------- bf16 MFMA GEMM, LDS-staged (validated R6) ----------------
template<int MODE>
__global__ __launch_bounds__(256) void mm_k(
    const u16* __restrict__ A, const u16* __restrict__ Bt,
    const float* __restrict__ bias, void* __restrict__ outp) {
  __shared__ u16 sA[128][64];   // 16 KB, XOR-swizzled 16B slots
  __shared__ u16 sB[128][64];   // 16 KB
  const int tid = threadIdx.x, lane = tid & 63, w = tid >> 6;
  const int fr = lane & 15, fg = lane >> 4;
  const int wr = w >> 1, wc = w & 1;
  const int m0 = blockIdx.y * 128, n0 = blockIdx.x * 128;
  const int srow = tid >> 3, sslot = tid & 7;   // +p*32 rows per pass
  f32x4 acc[4][4] = {};
  bf16x8 av[4], bv[4];
#pragma unroll
  for (int p = 0; p < 4; ++p) {
    av[p] = *(const bf16x8*)(A  + (size_t)(m0 + srow + p * 32) * DM_ + sslot * 8);
    bv[p] = *(const bf16x8*)(Bt + (size_t)(n0 + srow + p * 32) * DM_ + sslot * 8);
  }
  for (int k0 = 0; k0 < DM_; k0 += 64) {
    __syncthreads();
#pragma unroll
    for (int p = 0; p < 4; ++p) {
      const int r = srow + p * 32;
      *(bf16x8*)&sA[r][(sslot ^ (r & 7)) * 8] = av[p];
      *(bf16x8*)&sB[r][(sslot ^ (r & 7)) * 8] = bv[p];
    }
    if (k0 + 64 < DM_) {
#pragma unroll
      for (int p = 0; p < 4; ++p) {
        av[p] = *(const bf16x8*)(A  + (size_t)(m0 + srow + p * 32) * DM_ + k0 + 64 + sslot * 8);
        bv[p] = *(const bf16x8*)(Bt + (size_t)(n0 + srow + p * 32) * DM_ + k0 + 64 + sslot * 8);
      }
    }
    __syncthreads();
#pragma unroll
    for (int ks = 0; ks < 2; ++ks) {
      bf16x8 af[4], bf[4];
#pragma unroll
      for (int i = 0; i < 4; ++i) {
        const int r = wr * 64 + i * 16 + fr;
        af[i] = *(const bf16x8*)&sA[r][((ks * 4 + fg) ^ (r & 7)) * 8];
      }
#pragma unroll
      for (int j = 0; j < 4; ++j) {
        const int r = wc * 64 + j * 16 + fr;
        bf[j] = *(const bf16x8*)&sB[r][((ks * 4 + fg) ^ (r & 7)) * 8];
      }
#pragma unroll
      for (int i = 0; i < 4; ++i)
#pragma unroll
        for (int j = 0; j < 4; ++j)
          acc[i][j] = MFMA16(af[i], bf[j], acc[i][j]);
    }
  }
  const int m_blk = m0 + wr * 64, n_blk = n0 + wc * 64;
#pragma unroll
  for (int j = 0; j < 4; ++j) {
    const int n = n_blk + j * 16 + fr;
    const float bi = bias[n];
    const int h = n >> 6, d = n & 63;
#pragma unroll
    for (int i = 0; i < 4; ++i) {
#pragma unroll
      for (int r = 0; r < 4; ++r) {
        const int m = m_blk + i * 16 + fg * 4 + r;
        const float val = acc[i][j][r] + bi;
        if (MODE == 0) {
          const int b = m >> 12, l = m & 4095;
          ((u16*)outp)[((size_t)(b * H_ + h) * L_ + l) * D_ + d] = f2bf(val);
        } else {
          ((float*)outp)[(size_t)m * DM_ + n] = val;
        }
      }
    }
  }
}

// ---------------- shared: LDS sumsq (kvstate, validated) -------------------
static __device__ __forceinline__ void sumsq_tile(
    const u16* __restrict__ xg, float (*ssq)[4], float* __restrict__ nh, int tid) {
  const int t = tid >> 2, qt = tid & 3;
  const u16* xp = xg + t * 64 + qt * 16;
  float s = 0.f;
#pragma unroll
  for (int jj = 0; jj < 2; ++jj) {
    bf16x8 xv = *(const bf16x8*)(xp + jj * 8);
#pragma unroll
    for (int e = 0; e < 8; ++e) { const float f = bf2f((u16)xv[e]); s += f * f; }
  }
  ssq[t][qt] = s;
  __syncthreads();
  if (tid < 64)
    nh[tid] = 0.0625f * (ssq[tid][0] + ssq[tid][1] + ssq[tid][2] + ssq[tid][3]);
  __syncthreads();
}

// ---------------- kvstate (MFMA, validated R6) -----------------------------
__global__ __launch_bounds__(256) void kvstate_k(
    const u16* __restrict__ k, const u16* __restrict__ v,
    const u16* __restrict__ omb, float* __restrict__ state) {
  __shared__ u16 sPhi[256][72];
  __shared__ u16 sVt[64][72];
  __shared__ float ssq[64][4];
  __shared__ float nh[64];
  const int tid = threadIdx.x, lane = tid & 63, w = tid >> 6;
  const int fr = lane & 15, fg = lane >> 4;
  const int sc = blockIdx.x, bh = blockIdx.y;
  const size_t base_l = (size_t)bh * L_ + (size_t)sc * 256;

  bf16x8 ones;
#pragma unroll
  for (int e = 0; e < 8; ++e) ones[e] = (short)0x3F80;

  f32x4 kvacc[4][4] = {};
  f32x4 ksacc[4] = {};

  for (int sub = 0; sub < 4; ++sub) {
    const size_t tl = base_l + sub * 64;
    const u16* kg = k + tl * 64;
    __syncthreads();
    {
      const u16* vp = v + (tl + lane) * 64 + w * 16;
      bf16x8 v0 = *(const bf16x8*)(vp);
      bf16x8 v1 = *(const bf16x8*)(vp + 8);
#pragma unroll
      for (int e = 0; e < 8; ++e) sVt[w * 16 + e][lane] = (u16)v0[e];
#pragma unroll
      for (int e = 0; e < 8; ++e) sVt[w * 16 + 8 + e][lane] = (u16)v1[e];
    }
    sumsq_tile(kg, ssq, nh, tid);
#pragma unroll
    for (int mi = 0; mi < 4; ++mi) {
      const int m0 = (w << 6) + mi * 16;
      const bf16x8 a0 = *(const bf16x8*)(omb + (m0 + fr) * 64 + fg * 8);
      const bf16x8 a1 = *(const bf16x8*)(omb + (m0 + fr) * 64 + 32 + fg * 8);
#pragma unroll
      for (int tt = 0; tt < 4; ++tt) {
        const bf16x8 b0 = *(const bf16x8*)(kg + (tt * 16 + fr) * 64 + fg * 8);
        const bf16x8 b1 = *(const bf16x8*)(kg + (tt * 16 + fr) * 64 + 32 + fg * 8);
        f32x4 acc = {0.f, 0.f, 0.f, 0.f};
        acc = MFMA16(a0, b0, acc);
        acc = MFMA16(a1, b1, acc);
        const float nhv = nh[tt * 16 + fr];
#pragma unroll
        for (int r = 0; r < 4; ++r)
          sPhi[m0 + fg * 4 + r][tt * 16 + fr] = f2bf(__expf(acc[r] - nhv) * 0.0625f);
      }
    }
    __syncthreads();
#pragma unroll
    for (int mi = 0; mi < 4; ++mi) {
      const int m0 = (w << 6) + mi * 16;
      const bf16x8 pb0 = *(const bf16x8*)&sPhi[m0 + fr][fg * 8];
      const bf16x8 pb1 = *(const bf16x8*)&sPhi[m0 + fr][32 + fg * 8];
      ksacc[mi] = MFMA16(pb0, ones, ksacc[mi]);
      ksacc[mi] = MFMA16(pb1, ones, ksacc[mi]);
#pragma unroll
      for (int dj = 0; dj < 4; ++dj) {
        const bf16x8 va0 = *(const bf16x8*)&sVt[dj * 16 + fr][fg * 8];
        const bf16x8 va1 = *(const bf16x8*)&sVt[dj * 16 + fr][32 + fg * 8];
        kvacc[mi][dj] = MFMA16(va0, pb0, kvacc[mi][dj]);
        kvacc[mi][dj] = MFMA16(va1, pb1, kvacc[mi][dj]);
      }
    }
  }
  float* st = state + ((size_t)bh * NSC + sc) * ST_STRIDE;
#pragma unroll
  for (int mi = 0; mi < 4; ++mi) {
    const int m = (w << 6) + mi * 16 + fr;
#pragma unroll
    for (int dj = 0; dj < 4; ++dj)
#pragma unroll
      for (int r = 0; r < 4; ++r)
        st[(size_t)(dj * 16 + fg * 4 + r) * M_ + m] = kvacc[mi][dj][r];
    if (fr == 0) {
#pragma unroll
      for (int r = 0; r < 4; ++r)
        st[M_ * D_ + (w << 6) + mi * 16 + fg * 4 + r] = ksacc[mi][r];
    }
  }
}

// ---------------- parallel exclusive prefix over superchunks --------------
__global__ __launch_bounds__(256) void scan_k(float* __restrict__ state) {
  const int bh = blockIdx.y;
  float* sb = state + (size_t)bh * NSC * ST_STRIDE;
  const int base = blockIdx.x * 2048 + threadIdx.x * 8;
  float run[8] = {};
  for (int cc = 0; cc < NSC; ++cc) {
    float* st = sb + (size_t)cc * ST_STRIDE + base;
    float4 t0 = *(float4*)st;
    float4 t1 = *(float4*)(st + 4);
    *(float4*)st       = make_float4(run[0], run[1], run[2], run[3]);
    *(float4*)(st + 4) = make_float4(run[4], run[5], run[6], run[7]);
    run[0] += t0.x; run[1] += t0.y; run[2] += t0.z; run[3] += t0.w;
    run[4] += t1.x; run[5] += t1.y; run[6] += t1.z; run[7] += t1.w;
  }
  if (blockIdx.x == 0) {
    float rk = 0.f;
    for (int cc = 0; cc < NSC; ++cc) {
      float* p = sb + (size_t)cc * ST_STRIDE + M_ * D_ + threadIdx.x;
      const float t = *p;
      *p = rk;
      rk += t;
    }
  }
}

// ---------------- outchunk helpers ----------------------------------------
// per-wave sumsq via shfl: lane(fr,fg) computes ||x_{w*16+fr}||^2/16;
// nhv[r] = value for token w*16+fg*4+r (pulled from lane fg*4+r, which has
// fr=fg*4+r, fg'=0 -> holds token w*16+fg*4+r).  0.0625 = (64^-0.25)^2 / 2.
static __device__ __forceinline__ void sumsq_wave(
    const u16* __restrict__ xg, int w, int lane, float* nhv) {
  const u16* xp = xg + (w * 16 + (lane & 15)) * 64;
  float s = 0.f;
#pragma unroll
  for (int p = 0; p < 8; ++p) {
    bf16x8 xv = *(const bf16x8*)(xp + p * 8);
#pragma unroll
    for (int e = 0; e < 8; ++e) { const float f = bf2f((u16)xv[e]); s += f * f; }
  }
  s *= 0.0625f;
  const int fg = lane >> 4;
#pragma unroll
  for (int r = 0; r < 4; ++r) nhv[r] = __shfl(s, fg * 4 + r, 64);
}

// phi quadrant: dst[t*dstride + j*16+fr] = exp(omb_q . x_t - nh_t)/16
static __device__ __forceinline__ void phi_quad(
    const u16* __restrict__ xg, const u16* __restrict__ ombq,
    u16* __restrict__ dst, int dstride, const float* nhv,
    int w, int lane) {
  const int fr = lane & 15, fg = lane >> 4;
  const int tband = w * 16;
  const bf16x8 a0 = *(const bf16x8*)(xg + (tband + fr) * 64 + fg * 8);
  const bf16x8 a1 = *(const bf16x8*)(xg + (tband + fr) * 64 + 32 + fg * 8);
#pragma unroll
  for (int j = 0; j < 4; ++j) {
    const bf16x8 b0 = *(const bf16x8*)(ombq + (j * 16 + fr) * 64 + fg * 8);
    const bf16x8 b1 = *(const bf16x8*)(ombq + (j * 16 + fr) * 64 + 32 + fg * 8);
    f32x4 acc = {0.f, 0.f, 0.f, 0.f};
    acc = MFMA16(a0, b0, acc);
    acc = MFMA16(a1, b1, acc);
#pragma unroll
    for (int r = 0; r < 4; ++r) {
      const int t = tband + fg * 4 + r;
      dst[t * dstride + j * 16 + fr] = f2bf(__expf(acc[r] - nhv[r]) * 0.0625f);
    }
  }
}

// ---------------- outchunk: 3 blocks/CU, bf16 state, aliased S -------------
__global__ __launch_bounds__(256) void outchunk_k(
    const u16* __restrict__ q, const u16* __restrict__ kk,
    const u16* __restrict__ v, const u16* __restrict__ omb,
    const float* __restrict__ state, u16* __restrict__ attn) {
  __shared__ u16 sA[64][258];     // Qp full         33,024 B
  __shared__ u16 sKS[64][72];     // Kp quadrant / masked S  9,216 B
  __shared__ u16 sB1[64][72];     // state bf16 / vT         9,216 B
  __shared__ float ksum_l[256];   //  1,024 B
  __shared__ float dq[64][4];     //  1,024 B
  __shared__ float sden[64];      //    256 B    total 53,760 B -> 3/CU
  const int tid = threadIdx.x, lane = tid & 63, w = tid >> 6;
  const int fr = lane & 15, fg = lane >> 4;
  // XCD swizzle: 4 chunks of a superchunk -> same XCD (state L2-resident)
  const int lbid = ((blockIdx.x & 7) << 9) | (blockIdx.x >> 3);
  const int bh = lbid >> 6, c = lbid & 63;
  const int sc = c >> 2;
  const size_t tok0 = (size_t)bh * L_ + (size_t)c * 64;
  const u16* qg = q + tok0 * 64;
  const float* stg = state + ((size_t)bh * NSC + sc) * ST_STRIDE;

  ksum_l[tid] = stg[M_ * D_ + tid];

  // phi(q) -> sA, all 4 quadrants; each wave writes only its own rows,
  // no LDS reads inside -> single barrier after.
  float nhq[4];
  sumsq_wave(qg, w, lane, nhq);
#pragma unroll 1
  for (int mq = 0; mq < 4; ++mq)
    phi_quad(qg, omb + mq * 4096, &sA[0][mq * 64], 258, nhq, w, lane);
  __syncthreads();   // sA + ksum_l visible to all

  // den: ksum part. thread (w,lane) owns dq[lane][w]  (t = lane)
  {
    float s = 0.f;
#pragma unroll
    for (int g8 = 0; g8 < 8; ++g8) {
      bf16x8 qv = *(const bf16x8*)&sA[lane][w * 64 + g8 * 8];
#pragma unroll
      for (int e = 0; e < 8; ++e)
        s += bf2f((u16)qv[e]) * ksum_l[w * 64 + g8 * 8 + e];
    }
    dq[lane][w] = s;
  }

  f32x4 oacc[4] = {};
  // ---- cross term: Qp @ KVex (bf16 state), 4 feature quadrants
#pragma unroll 1
  for (int mq = 0; mq < 4; ++mq) {
    __syncthreads();   // prior readers of sB1 done
    {
      const int d = tid >> 2, seg = tid & 3;
      const float* sp = stg + (size_t)d * M_ + mq * 64 + seg * 16;
      u16* ph = &sB1[d][seg * 16];
#pragma unroll
      for (int e = 0; e < 16; ++e) ph[e] = f2bf(sp[e]);
    }
    __syncthreads();
    const bf16x8 a0 = *(const bf16x8*)&sA[w * 16 + fr][mq * 64 + fg * 8];
    const bf16x8 a1 = *(const bf16x8*)&sA[w * 16 + fr][mq * 64 + 32 + fg * 8];
    __builtin_amdgcn_s_setprio(1);
#pragma unroll
    for (int j = 0; j < 4; ++j) {
      const bf16x8 bh0 = *(const bf16x8*)&sB1[j * 16 + fr][fg * 8];
      const bf16x8 bh1 = *(const bf16x8*)&sB1[j * 16 + fr][32 + fg * 8];
      oacc[j] = MFMA16(a0, bh0, oacc[j]);
      oacc[j] = MFMA16(a1, bh1, oacc[j]);
    }
    __builtin_amdgcn_s_setprio(0);
  }

  // ---- source chunks in superchunk
#pragma unroll 1
  for (int s_c = sc * 4; s_c <= c; ++s_c) {
    const size_t ktok = (size_t)bh * L_ + (size_t)s_c * 64;
    const u16* kg = kk + ktok * 64;
    float nhk[4];
    sumsq_wave(kg, w, lane, nhk);
    f32x4 sacc[4] = {};
#pragma unroll 1
    for (int mq = 0; mq < 4; ++mq) {
      __syncthreads();   // prior readers of sKS (S@V or prev S-MFMA) done
      phi_quad(kg, omb + mq * 4096, &sKS[0][0], 72, nhk, w, lane);
      __syncthreads();
      const bf16x8 a0 = *(const bf16x8*)&sA[w * 16 + fr][mq * 64 + fg * 8];
      const bf16x8 a1 = *(const bf16x8*)&sA[w * 16 + fr][mq * 64 + 32 + fg * 8];
      __builtin_amdgcn_s_setprio(1);
#pragma unroll
      for (int j = 0; j < 4; ++j) {
        const bf16x8 b0 = *(const bf16x8*)&sKS[j * 16 + fr][fg * 8];
        const bf16x8 b1 = *(const bf16x8*)&sKS[j * 16 + fr][32 + fg * 8];
        sacc[j] = MFMA16(a0, b0, sacc[j]);
        sacc[j] = MFMA16(a1, b1, sacc[j]);
      }
      __builtin_amdgcn_s_setprio(0);
    }
    __syncthreads();   // all S-MFMA reads of sKS done -> safe to overwrite
    const bool diag = (s_c == c);
#pragma unroll
    for (int j = 0; j < 4; ++j)
#pragma unroll
      for (int r = 0; r < 4; ++r) {
        const int s = j * 16 + fr, t = w * 16 + fg * 4 + r;
        float val = sacc[j][r];
        if (diag && s > t) val = 0.f;
        sKS[t][s] = f2bf(val);      // masked S into aliased buffer (own rows)
      }
    {  // vT staging (own rows of sB1; prior readers separated by mq barriers)
      const u16* vp = v + (ktok + lane) * 64 + w * 16;
      bf16x8 v0 = *(const bf16x8*)(vp);
      bf16x8 v1 = *(const bf16x8*)(vp + 8);
#pragma unroll
      for (int e = 0; e < 8; ++e) sB1[w * 16 + e][lane] = (u16)v0[e];
#pragma unroll
      for (int e = 0; e < 8; ++e) sB1[w * 16 + 8 + e][lane] = (u16)v1[e];
    }
    __syncthreads();   // masked S + vT visible
    // den contribution (reads masked S row `lane`)
    {
      float s = 0.f;
      bf16x8 s0 = *(const bf16x8*)&sKS[lane][w * 16];
      bf16x8 s1 = *(const bf16x8*)&sKS[lane][w * 16 + 8];
#pragma unroll
      for (int e = 0; e < 8; ++e) s += bf2f((u16)s0[e]) + bf2f((u16)s1[e]);
      dq[lane][w] += s;
    }
    // S @ V
    {
      const bf16x8 a0 = *(const bf16x8*)&sKS[w * 16 + fr][fg * 8];
      const bf16x8 a1 = *(const bf16x8*)&sKS[w * 16 + fr][32 + fg * 8];
      __builtin_amdgcn_s_setprio(1);
#pragma unroll
      for (int j = 0; j < 4; ++j) {
        const bf16x8 b0 = *(const bf16x8*)&sB1[j * 16 + fr][fg * 8];
        const bf16x8 b1 = *(const bf16x8*)&sB1[j * 16 + fr][32 + fg * 8];
        oacc[j] = MFMA16(a0, b0, oacc[j]);
        oacc[j] = MFMA16(a1, b1, oacc[j]);
      }
      __builtin_amdgcn_s_setprio(0);
    }
    __syncthreads();   // S@V reads done before next iteration's writes
  }

  if (tid < 64)
    sden[tid] = 1.0f / (dq[tid][0] + dq[tid][1] + dq[tid][2] + dq[tid][3] + 1e-6f);
  __syncthreads();
  const int b = bh >> 4, hh = bh & 15;
#pragma unroll
  for (int j = 0; j < 4; ++j)
#pragma unroll
    for (int r = 0; r < 4; ++r) {
      const int t = w * 16 + fg * 4 + r;
      const int d = j * 16 + fr;
      const int l = c * 64 + t;
      attn[((size_t)b * L_ + l) * DM_ + hh * 64 + d] = f2bf(oacc[j][r] * sden[t]);
    }
}

extern "C" void kernel_launch(void* const* d_in, const int* in_sizes, int n_in,
                              void* d_out, int out_size, void* d_ws, size_t ws_size,
                              hipStream_t stream) {
  const float* x     = (const float*)d_in[0];
  const float* Wq    = (const float*)d_in[1];
  const float* bq    = (const float*)d_in[2];
  const float* Wk    = (const float*)d_in[3];
  const float* bk    = (const float*)d_in[4];
  const float* Wv    = (const float*)d_in[5];
  const float* bv    = (const float*)d_in[6];
  const float* Wo    = (const float*)d_in[7];
  const float* bo    = (const float*)d_in[8];
  const float* omega = (const float*)d_in[9];
  float* out = (float*)d_out;

  char* ws = (char*)d_ws;
  u16*   v     = (u16*)(ws);                            // 32 MB
  u16*   qb    = (u16*)(ws + 33554432ull);              // 32 MB
  u16*   kb    = (u16*)(ws + 67108864ull);              // 32 MB
  u16*   xb    = (u16*)(ws + 100663296ull);             // 32 MB (alias attn)
  u16*   attn  = xb;
  float* state = (float*)(ws + 134217728ull);           // 68.16 MB
  u16*   Wt    = (u16*)(ws + 202375168ull);             // 8 MB
  u16*   omb   = (u16*)(ws + 210763776ull);             // 32 KB

  convx_k<<<16384, 256, 0, stream>>>(x, xb);
  convw_k<<<dim3(16, 16, 4), 256, 0, stream>>>(Wq, Wk, Wv, Wo, Wt);
  convom_k<<<64, 256, 0, stream>>>(omega, omb);

  const dim3 gg(8, 128);
  mm_k<0><<<gg, 256, 0, stream>>>(xb, Wt,                 bq, qb);
  mm_k<0><<<gg, 256, 0, stream>>>(xb, Wt + 1048576ull,    bk, kb);
  mm_k<0><<<gg, 256, 0, stream>>>(xb, Wt + 2097152ull,    bv, v);
  kvstate_k<<<dim3(NSC, BH_), 256, 0, stream>>>(kb, v, omb, state);
  scan_k<<<dim3(8, BH_), 256, 0, stream>>>(state);
  outchunk_k<<<BH_ * 64, 256, 0, stream>>>(qb, kb, v, omb, state, attn);
  mm_k<1><<<gg, 256, 0, stream>>>(attn, Wt + 3145728ull,  bo, out);
}

// Round 9
// 635.685 us; speedup vs baseline: 13.9698x; 1.1538x over previous
//
#include <hip/hip_runtime.h>
#include <hip/hip_bf16.h>

// FAVOR+ attention, MI355X. Round 9: R8's structure at SC=128, no Kp buffer.
//  - stateb bf16 [64bh][32][64d][256m] (64 MB) + f32 ksum (2 MB): cross term
//    reads B-frags DIRECT from global (L2-resident via XCD swizzle).
//  - outchunk: avg 1.5 source chunks (phi(k) recompute) vs R7's 2.5;
//    ~17 barriers vs ~41. Per-chunk code verbatim from R7-validated.
//  - kvstate: SC=128 (2 subtiles), writes bf16 state + f32 ksum.
//  - scan: 32-step f32-register prefix over bf16 state.
//  - mm_k / convs unchanged (validated).
//
// Workspace (bytes), total 211,845,120 (~202 MB; R2 validated 235.9 MB):
//   v      bf16 [64bh][4096][64]   @ 0            (32 MB)
//   q      bf16                    @ 33,554,432   (32 MB)
//   k      bf16                    @ 67,108,864   (32 MB)
//   xb     bf16 [16384][1024]      @ 100,663,296  (32 MB) -- ALIASED attn
//   stateb bf16 [64bh][32][16384]  @ 134,217,728  (64 MB)
//   ksum   f32  [64bh][32][256]    @ 201,326,592  (2 MB)
//   Wt     bf16 4x[1024][1024]     @ 203,423,744  (8 MB)
//   omb    bf16 [256][64]          @ 211,812,352  (32 KB)

#define B_ 4
#define H_ 16
#define L_ 4096
#define D_ 64
#define M_ 256
#define DM_ 1024
#define BH_ 64
#define NSC 32            // superchunks per bh (SC = 128 tokens)

typedef unsigned int u32;
typedef unsigned short u16;
typedef __attribute__((ext_vector_type(8))) short bf16x8;
typedef __attribute__((ext_vector_type(4))) float f32x4;

static __device__ __forceinline__ float bf2f(u16 u) {
  return __uint_as_float(((u32)u) << 16);
}
static __device__ __forceinline__ u16 f2bf(float f) {
  u32 x = __float_as_uint(f);
  return (u16)((x + 0x7fffu + ((x >> 16) & 1u)) >> 16);   // RNE
}
#define MFMA16(a, b, c) __builtin_amdgcn_mfma_f32_16x16x32_bf16((a), (b), (c), 0, 0, 0)

// ---------------- converters ----------------------------------------------
__global__ __launch_bounds__(256) void convx_k(const float* __restrict__ x,
                                               u16* __restrict__ xb) {
  const int i = blockIdx.x * 256 + threadIdx.x;
  float4 f = ((const float4*)x)[i];
  ushort4 u;
  u.x = f2bf(f.x); u.y = f2bf(f.y); u.z = f2bf(f.z); u.w = f2bf(f.w);
  ((ushort4*)xb)[i] = u;
}

__global__ __launch_bounds__(256) void convw_k(
    const float* __restrict__ W0, const float* __restrict__ W1,
    const float* __restrict__ W2, const float* __restrict__ W3,
    u16* __restrict__ out) {
  __shared__ u16 tt[64][66];
  const int z = blockIdx.z;
  const float* W = (z == 0) ? W0 : (z == 1) ? W1 : (z == 2) ? W2 : W3;
  u16* o = out + (size_t)z * 1048576ull;
  const int k0 = blockIdx.y * 64, n0 = blockIdx.x * 64;
  const int r = threadIdx.x >> 4, c4 = (threadIdx.x & 15) << 2;
  for (int rr = r; rr < 64; rr += 16) {
    float4 w4 = *(const float4*)(W + (size_t)(k0 + rr) * DM_ + n0 + c4);
    tt[c4 + 0][rr] = f2bf(w4.x);
    tt[c4 + 1][rr] = f2bf(w4.y);
    tt[c4 + 2][rr] = f2bf(w4.z);
    tt[c4 + 3][rr] = f2bf(w4.w);
  }
  __syncthreads();
  for (int rr = r; rr < 64; rr += 16) {
    ushort4 u4;
    u4.x = tt[rr][c4 + 0];
    u4.y = tt[rr][c4 + 1];
    u4.z = tt[rr][c4 + 2];
    u4.w = tt[rr][c4 + 3];
    *(ushort4*)(o + (size_t)(n0 + rr) * DM_ + k0 + c4) = u4;
  }
}

__global__ __launch_bounds__(256) void convom_k(const float* __restrict__ om,
                                                u16* __restrict__ omb) {
  const int i = blockIdx.x * 256 + threadIdx.x;
  omb[i] = f2bf(om[i] * 0.35355339059327373f);       // fold 64^-0.25
}

// ---------------- bf16 MFMA GEMM, LDS-staged (validated R6/R7) -------------
template<int MODE>
__global__ __launch_bounds__(256) void mm_k(
    const u16* __restrict__ A, const u16* __restrict__ Bt,
    const float* __restrict__ bias, void* __restrict__ outp) {
  __shared__ u16 sA[128][64];   // 16 KB, XOR-swizzled 16B slots
  __shared__ u16 sB[128][64];   // 16 KB
  const int tid = threadIdx.x, lane = tid & 63, w = tid >> 6;
  const int fr = lane & 15, fg = lane >> 4;
  const int wr = w >> 1, wc = w & 1;
  const int m0 = blockIdx.y * 128, n0 = blockIdx.x * 128;
  const int srow = tid >> 3, sslot = tid & 7;   // +p*32 rows per pass
  f32x4 acc[4][4] = {};
  bf16x8 av[4], bv[4];
#pragma unroll
  for (int p = 0; p < 4; ++p) {
    av[p] = *(const bf16x8*)(A  + (size_t)(m0 + srow + p * 32) * DM_ + sslot * 8);
    bv[p] = *(const bf16x8*)(Bt + (size_t)(n0 + srow + p * 32) * DM_ + sslot * 8);
  }
  for (int k0 = 0; k0 < DM_; k0 += 64) {
    __syncthreads();
#pragma unroll
    for (int p = 0; p < 4; ++p) {
      const int r = srow + p * 32;
      *(bf16x8*)&sA[r][(sslot ^ (r & 7)) * 8] = av[p];
      *(bf16x8*)&sB[r][(sslot ^ (r & 7)) * 8] = bv[p];
    }
    if (k0 + 64 < DM_) {
#pragma unroll
      for (int p = 0; p < 4; ++p) {
        av[p] = *(const bf16x8*)(A  + (size_t)(m0 + srow + p * 32) * DM_ + k0 + 64 + sslot * 8);
        bv[p] = *(const bf16x8*)(Bt + (size_t)(n0 + srow + p * 32) * DM_ + k0 + 64 + sslot * 8);
      }
    }
    __syncthreads();
#pragma unroll
    for (int ks = 0; ks < 2; ++ks) {
      bf16x8 af[4], bf[4];
#pragma unroll
      for (int i = 0; i < 4; ++i) {
        const int r = wr * 64 + i * 16 + fr;
        af[i] = *(const bf16x8*)&sA[r][((ks * 4 + fg) ^ (r & 7)) * 8];
      }
#pragma unroll
      for (int j = 0; j < 4; ++j) {
        const int r = wc * 64 + j * 16 + fr;
        bf[j] = *(const bf16x8*)&sB[r][((ks * 4 + fg) ^ (r & 7)) * 8];
      }
#pragma unroll
      for (int i = 0; i < 4; ++i)
#pragma unroll
        for (int j = 0; j < 4; ++j)
          acc[i][j] = MFMA16(af[i], bf[j], acc[i][j]);
    }
  }
  const int m_blk = m0 + wr * 64, n_blk = n0 + wc * 64;
#pragma unroll
  for (int j = 0; j < 4; ++j) {
    const int n = n_blk + j * 16 + fr;
    const float bi = bias[n];
    const int h = n >> 6, d = n & 63;
#pragma unroll
    for (int i = 0; i < 4; ++i) {
#pragma unroll
      for (int r = 0; r < 4; ++r) {
        const int m = m_blk + i * 16 + fg * 4 + r;
        const float val = acc[i][j][r] + bi;
        if (MODE == 0) {
          const int b = m >> 12, l = m & 4095;
          ((u16*)outp)[((size_t)(b * H_ + h) * L_ + l) * D_ + d] = f2bf(val);
        } else {
          ((float*)outp)[(size_t)m * DM_ + n] = val;
        }
      }
    }
  }
}

// ---------------- shared: LDS sumsq (kvstate, validated) -------------------
static __device__ __forceinline__ void sumsq_tile(
    const u16* __restrict__ xg, float (*ssq)[4], float* __restrict__ nh, int tid) {
  const int t = tid >> 2, qt = tid & 3;
  const u16* xp = xg + t * 64 + qt * 16;
  float s = 0.f;
#pragma unroll
  for (int jj = 0; jj < 2; ++jj) {
    bf16x8 xv = *(const bf16x8*)(xp + jj * 8);
#pragma unroll
    for (int e = 0; e < 8; ++e) { const float f = bf2f((u16)xv[e]); s += f * f; }
  }
  ssq[t][qt] = s;
  __syncthreads();
  if (tid < 64)
    nh[tid] = 0.0625f * (ssq[tid][0] + ssq[tid][1] + ssq[tid][2] + ssq[tid][3]);
  __syncthreads();
}

// ---------------- kvstate (MFMA, SC=128): bf16 state + f32 ksum ------------
__global__ __launch_bounds__(256) void kvstate_k(
    const u16* __restrict__ k, const u16* __restrict__ v,
    const u16* __restrict__ omb, u16* __restrict__ stateb,
    float* __restrict__ ksum) {
  __shared__ u16 sPhi[256][72];
  __shared__ u16 sVt[64][72];
  __shared__ float ssq[64][4];
  __shared__ float nh[64];
  const int tid = threadIdx.x, lane = tid & 63, w = tid >> 6;
  const int fr = lane & 15, fg = lane >> 4;
  const int sc = blockIdx.x, bh = blockIdx.y;
  const size_t base_l = (size_t)bh * L_ + (size_t)sc * 128;

  bf16x8 ones;
#pragma unroll
  for (int e = 0; e < 8; ++e) ones[e] = (short)0x3F80;

  f32x4 kvacc[4][4] = {};
  f32x4 ksacc[4] = {};

  for (int sub = 0; sub < 2; ++sub) {
    const size_t tl = base_l + sub * 64;
    const u16* kg = k + tl * 64;
    __syncthreads();
    {
      const u16* vp = v + (tl + lane) * 64 + w * 16;
      bf16x8 v0 = *(const bf16x8*)(vp);
      bf16x8 v1 = *(const bf16x8*)(vp + 8);
#pragma unroll
      for (int e = 0; e < 8; ++e) sVt[w * 16 + e][lane] = (u16)v0[e];
#pragma unroll
      for (int e = 0; e < 8; ++e) sVt[w * 16 + 8 + e][lane] = (u16)v1[e];
    }
    sumsq_tile(kg, ssq, nh, tid);
#pragma unroll
    for (int mi = 0; mi < 4; ++mi) {
      const int m0 = (w << 6) + mi * 16;
      const bf16x8 a0 = *(const bf16x8*)(omb + (m0 + fr) * 64 + fg * 8);
      const bf16x8 a1 = *(const bf16x8*)(omb + (m0 + fr) * 64 + 32 + fg * 8);
#pragma unroll
      for (int tt = 0; tt < 4; ++tt) {
        const bf16x8 b0 = *(const bf16x8*)(kg + (tt * 16 + fr) * 64 + fg * 8);
        const bf16x8 b1 = *(const bf16x8*)(kg + (tt * 16 + fr) * 64 + 32 + fg * 8);
        f32x4 acc = {0.f, 0.f, 0.f, 0.f};
        acc = MFMA16(a0, b0, acc);
        acc = MFMA16(a1, b1, acc);
        const float nhv = nh[tt * 16 + fr];
#pragma unroll
        for (int r = 0; r < 4; ++r)
          sPhi[m0 + fg * 4 + r][tt * 16 + fr] = f2bf(__expf(acc[r] - nhv) * 0.0625f);
      }
    }
    __syncthreads();
#pragma unroll
    for (int mi = 0; mi < 4; ++mi) {
      const int m0 = (w << 6) + mi * 16;
      const bf16x8 pb0 = *(const bf16x8*)&sPhi[m0 + fr][fg * 8];
      const bf16x8 pb1 = *(const bf16x8*)&sPhi[m0 + fr][32 + fg * 8];
      ksacc[mi] = MFMA16(pb0, ones, ksacc[mi]);
      ksacc[mi] = MFMA16(pb1, ones, ksacc[mi]);
#pragma unroll
      for (int dj = 0; dj < 4; ++dj) {
        const bf16x8 va0 = *(const bf16x8*)&sVt[dj * 16 + fr][fg * 8];
        const bf16x8 va1 = *(const bf16x8*)&sVt[dj * 16 + fr][32 + fg * 8];
        kvacc[mi][dj] = MFMA16(va0, pb0, kvacc[mi][dj]);
        kvacc[mi][dj] = MFMA16(va1, pb1, kvacc[mi][dj]);
      }
    }
  }
  // state bf16 [d][m]; ksum f32
  u16* stb = stateb + (size_t)(bh * NSC + sc) * (M_ * D_);
  float* ksp = ksum + (size_t)(bh * NSC + sc) * M_;
#pragma unroll
  for (int mi = 0; mi < 4; ++mi) {
    const int m = (w << 6) + mi * 16 + fr;
#pragma unroll
    for (int dj = 0; dj < 4; ++dj)
#pragma unroll
      for (int r = 0; r < 4; ++r)
        stb[(size_t)(dj * 16 + fg * 4 + r) * M_ + m] = f2bf(kvacc[mi][dj][r]);
    if (fr == 0) {
#pragma unroll
      for (int r = 0; r < 4; ++r)
        ksp[(w << 6) + mi * 16 + fg * 4 + r] = ksacc[mi][r];
    }
  }
}

// ---------------- exclusive prefix over superchunks (bf16 state) -----------
__global__ __launch_bounds__(256) void scan_k(u16* __restrict__ stateb,
                                              float* __restrict__ ksum) {
  const int bh = blockIdx.y;
  u16* sb = stateb + (size_t)bh * NSC * (M_ * D_);
  const int base = blockIdx.x * 2048 + threadIdx.x * 8;
  float run[8] = {};
  for (int cc = 0; cc < NSC; ++cc) {
    u16* st = sb + (size_t)cc * (M_ * D_) + base;
    ushort4 t0 = *(ushort4*)st;
    ushort4 t1 = *(ushort4*)(st + 4);
    ushort4 w0, w1;
    w0.x = f2bf(run[0]); w0.y = f2bf(run[1]); w0.z = f2bf(run[2]); w0.w = f2bf(run[3]);
    w1.x = f2bf(run[4]); w1.y = f2bf(run[5]); w1.z = f2bf(run[6]); w1.w = f2bf(run[7]);
    *(ushort4*)st = w0;
    *(ushort4*)(st + 4) = w1;
    run[0] += bf2f(t0.x); run[1] += bf2f(t0.y); run[2] += bf2f(t0.z); run[3] += bf2f(t0.w);
    run[4] += bf2f(t1.x); run[5] += bf2f(t1.y); run[6] += bf2f(t1.z); run[7] += bf2f(t1.w);
  }
  if (blockIdx.x == 0) {           // ksum f32 in-place exclusive prefix
    float rk = 0.f;
    for (int cc = 0; cc < NSC; ++cc) {
      float* p = ksum + (size_t)(bh * NSC + cc) * M_ + threadIdx.x;
      const float t = *p;
      *p = rk;
      rk += t;
    }
  }
}

// ---------------- outchunk helpers (validated R7) --------------------------
static __device__ __forceinline__ void sumsq_wave(
    const u16* __restrict__ xg, int w, int lane, float* nhv) {
  const u16* xp = xg + (w * 16 + (lane & 15)) * 64;
  float s = 0.f;
#pragma unroll
  for (int p = 0; p < 8; ++p) {
    bf16x8 xv = *(const bf16x8*)(xp + p * 8);
#pragma unroll
    for (int e = 0; e < 8; ++e) { const float f = bf2f((u16)xv[e]); s += f * f; }
  }
  s *= 0.0625f;
  const int fg = lane >> 4;
#pragma unroll
  for (int r = 0; r < 4; ++r) nhv[r] = __shfl(s, fg * 4 + r, 64);
}

static __device__ __forceinline__ void phi_quad(
    const u16* __restrict__ xg, const u16* __restrict__ ombq,
    u16* __restrict__ dst, int dstride, const float* nhv,
    int w, int lane) {
  const int fr = lane & 15, fg = lane >> 4;
  const int tband = w * 16;
  const bf16x8 a0 = *(const bf16x8*)(xg + (tband + fr) * 64 + fg * 8);
  const bf16x8 a1 = *(const bf16x8*)(xg + (tband + fr) * 64 + 32 + fg * 8);
#pragma unroll
  for (int j = 0; j < 4; ++j) {
    const bf16x8 b0 = *(const bf16x8*)(ombq + (j * 16 + fr) * 64 + fg * 8);
    const bf16x8 b1 = *(const bf16x8*)(ombq + (j * 16 + fr) * 64 + 32 + fg * 8);
    f32x4 acc = {0.f, 0.f, 0.f, 0.f};
    acc = MFMA16(a0, b0, acc);
    acc = MFMA16(a1, b1, acc);
#pragma unroll
    for (int r = 0; r < 4; ++r) {
      const int t = tband + fg * 4 + r;
      dst[t * dstride + j * 16 + fr] = f2bf(__expf(acc[r] - nhv[r]) * 0.0625f);
    }
  }
}

// ---------------- outchunk: direct-global cross, <=2 source chunks ---------
__global__ __launch_bounds__(256) void outchunk_k(
    const u16* __restrict__ q, const u16* __restrict__ kk,
    const u16* __restrict__ v, const u16* __restrict__ omb,
    const u16* __restrict__ stateb, const float* __restrict__ ksum,
    u16* __restrict__ attn) {
  __shared__ u16 sA[64][258];     // Qp full         33,024 B
  __shared__ u16 sKS[64][72];     // Kp quadrant / masked S  9,216 B
  __shared__ u16 sB1[64][72];     // vT                      9,216 B
  __shared__ float ksum_l[256];   //  1,024 B
  __shared__ float dq[64][4];     //  1,024 B
  __shared__ float sden[64];      //    256 B    total 53,760 B -> 3/CU
  const int tid = threadIdx.x, lane = tid & 63, w = tid >> 6;
  const int fr = lane & 15, fg = lane >> 4;
  // XCD swizzle: chunks of a superchunk -> same XCD (state L2-resident)
  const int lbid = ((blockIdx.x & 7) << 9) | (blockIdx.x >> 3);
  const int bh = lbid >> 6, c = lbid & 63;
  const int sc = c >> 1;          // SC = 128 tokens = 2 chunks
  const size_t tok0 = (size_t)bh * L_ + (size_t)c * 64;
  const u16* qg = q + tok0 * 64;
  const u16* stgb = stateb + (size_t)(bh * NSC + sc) * (M_ * D_);   // [d][m]
  const float* ksg = ksum + (size_t)(bh * NSC + sc) * M_;

  ksum_l[tid] = ksg[tid];

  // phi(q) -> sA (waves write own rows only; no internal reads)
  float nhq[4];
  sumsq_wave(qg, w, lane, nhq);
#pragma unroll 1
  for (int mq = 0; mq < 4; ++mq)
    phi_quad(qg, omb + mq * 4096, &sA[0][mq * 64], 258, nhq, w, lane);
  __syncthreads();   // sA + ksum_l visible

  // den: ksum part (validated). thread (w,lane) owns dq[lane][w]
  {
    float s = 0.f;
#pragma unroll
    for (int g8 = 0; g8 < 8; ++g8) {
      bf16x8 qv = *(const bf16x8*)&sA[lane][w * 64 + g8 * 8];
#pragma unroll
      for (int e = 0; e < 8; ++e)
        s += bf2f((u16)qv[e]) * ksum_l[w * 64 + g8 * 8 + e];
    }
    dq[lane][w] = s;
  }

  // ---- cross term: Qp @ KVex, B-frags DIRECT from global (bf16 [d][m])
  f32x4 oacc[4] = {};
  __builtin_amdgcn_s_setprio(1);
#pragma unroll
  for (int mq = 0; mq < 4; ++mq) {
    const bf16x8 a0 = *(const bf16x8*)&sA[w * 16 + fr][mq * 64 + fg * 8];
    const bf16x8 a1 = *(const bf16x8*)&sA[w * 16 + fr][mq * 64 + 32 + fg * 8];
#pragma unroll
    for (int j = 0; j < 4; ++j) {
      const bf16x8 b0 = *(const bf16x8*)(stgb + (size_t)(j * 16 + fr) * M_ + mq * 64 + fg * 8);
      const bf16x8 b1 = *(const bf16x8*)(stgb + (size_t)(j * 16 + fr) * M_ + mq * 64 + 32 + fg * 8);
      oacc[j] = MFMA16(a0, b0, oacc[j]);
      oacc[j] = MFMA16(a1, b1, oacc[j]);
    }
  }
  __builtin_amdgcn_s_setprio(0);

  // ---- source chunks within superchunk (1 or 2)
#pragma unroll 1
  for (int s_c = sc * 2; s_c <= c; ++s_c) {
    const size_t ktok = (size_t)bh * L_ + (size_t)s_c * 64;
    const u16* kg = kk + ktok * 64;
    float nhk[4];
    sumsq_wave(kg, w, lane, nhk);
    f32x4 sacc[4] = {};
#pragma unroll 1
    for (int mq = 0; mq < 4; ++mq) {
      __syncthreads();   // prior readers of sKS done
      phi_quad(kg, omb + mq * 4096, &sKS[0][0], 72, nhk, w, lane);
      __syncthreads();
      const bf16x8 a0 = *(const bf16x8*)&sA[w * 16 + fr][mq * 64 + fg * 8];
      const bf16x8 a1 = *(const bf16x8*)&sA[w * 16 + fr][mq * 64 + 32 + fg * 8];
      __builtin_amdgcn_s_setprio(1);
#pragma unroll
      for (int j = 0; j < 4; ++j) {
        const bf16x8 b0 = *(const bf16x8*)&sKS[j * 16 + fr][fg * 8];
        const bf16x8 b1 = *(const bf16x8*)&sKS[j * 16 + fr][32 + fg * 8];
        sacc[j] = MFMA16(a0, b0, sacc[j]);
        sacc[j] = MFMA16(a1, b1, sacc[j]);
      }
      __builtin_amdgcn_s_setprio(0);
    }
    __syncthreads();   // all S-MFMA reads of sKS done -> safe to overwrite
    const bool diag = (s_c == c);
#pragma unroll
    for (int j = 0; j < 4; ++j)
#pragma unroll
      for (int r = 0; r < 4; ++r) {
        const int s = j * 16 + fr, t = w * 16 + fg * 4 + r;
        float val = sacc[j][r];
        if (diag && s > t) val = 0.f;
        sKS[t][s] = f2bf(val);      // own wave rows
      }
    {  // vT staging (own rows)
      const u16* vp = v + (ktok + lane) * 64 + w * 16;
      bf16x8 v0 = *(const bf16x8*)(vp);
      bf16x8 v1 = *(const bf16x8*)(vp + 8);
#pragma unroll
      for (int e = 0; e < 8; ++e) sB1[w * 16 + e][lane] = (u16)v0[e];
#pragma unroll
      for (int e = 0; e < 8; ++e) sB1[w * 16 + 8 + e][lane] = (u16)v1[e];
    }
    __syncthreads();   // masked S + vT visible
    // den contribution (reads masked S row `lane`)
    {
      float s = 0.f;
      bf16x8 s0 = *(const bf16x8*)&sKS[lane][w * 16];
      bf16x8 s1 = *(const bf16x8*)&sKS[lane][w * 16 + 8];
#pragma unroll
      for (int e = 0; e < 8; ++e) s += bf2f((u16)s0[e]) + bf2f((u16)s1[e]);
      dq[lane][w] += s;
    }
    // S @ V
    {
      const bf16x8 a0 = *(const bf16x8*)&sKS[w * 16 + fr][fg * 8];
      const bf16x8 a1 = *(const bf16x8*)&sKS[w * 16 + fr][32 + fg * 8];
      __builtin_amdgcn_s_setprio(1);
#pragma unroll
      for (int j = 0; j < 4; ++j) {
        const bf16x8 b0 = *(const bf16x8*)&sB1[j * 16 + fr][fg * 8];
        const bf16x8 b1 = *(const bf16x8*)&sB1[j * 16 + fr][32 + fg * 8];
        oacc[j] = MFMA16(a0, b0, oacc[j]);
        oacc[j] = MFMA16(a1, b1, oacc[j]);
      }
      __builtin_amdgcn_s_setprio(0);
    }
    __syncthreads();   // S@V reads done before next iteration's writes
  }

  if (tid < 64)
    sden[tid] = 1.0f / (dq[tid][0] + dq[tid][1] + dq[tid][2] + dq[tid][3] + 1e-6f);
  __syncthreads();
  const int b = bh >> 4, hh = bh & 15;
#pragma unroll
  for (int j = 0; j < 4; ++j)
#pragma unroll
    for (int r = 0; r < 4; ++r) {
      const int t = w * 16 + fg * 4 + r;
      const int d = j * 16 + fr;
      const int l = c * 64 + t;
      attn[((size_t)b * L_ + l) * DM_ + hh * 64 + d] = f2bf(oacc[j][r] * sden[t]);
    }
}

extern "C" void kernel_launch(void* const* d_in, const int* in_sizes, int n_in,
                              void* d_out, int out_size, void* d_ws, size_t ws_size,
                              hipStream_t stream) {
  const float* x     = (const float*)d_in[0];
  const float* Wq    = (const float*)d_in[1];
  const float* bq    = (const float*)d_in[2];
  const float* Wk    = (const float*)d_in[3];
  const float* bk    = (const float*)d_in[4];
  const float* Wv    = (const float*)d_in[5];
  const float* bv    = (const float*)d_in[6];
  const float* Wo    = (const float*)d_in[7];
  const float* bo    = (const float*)d_in[8];
  const float* omega = (const float*)d_in[9];
  float* out = (float*)d_out;

  char* ws = (char*)d_ws;
  u16*   v      = (u16*)(ws);                           // 32 MB
  u16*   qb     = (u16*)(ws + 33554432ull);             // 32 MB
  u16*   kb     = (u16*)(ws + 67108864ull);             // 32 MB
  u16*   xb     = (u16*)(ws + 100663296ull);            // 32 MB (alias attn)
  u16*   attn   = xb;
  u16*   stateb = (u16*)(ws + 134217728ull);            // 64 MB
  float* ksum   = (float*)(ws + 201326592ull);          // 2 MB
  u16*   Wt     = (u16*)(ws + 203423744ull);            // 8 MB
  u16*   omb    = (u16*)(ws + 211812352ull);            // 32 KB -> 202 MB

  convx_k<<<16384, 256, 0, stream>>>(x, xb);
  convw_k<<<dim3(16, 16, 4), 256, 0, stream>>>(Wq, Wk, Wv, Wo, Wt);
  convom_k<<<64, 256, 0, stream>>>(omega, omb);

  const dim3 gg(8, 128);
  mm_k<0><<<gg, 256, 0, stream>>>(xb, Wt,                 bq, qb);
  mm_k<0><<<gg, 256, 0, stream>>>(xb, Wt + 1048576ull,    bk, kb);
  mm_k<0><<<gg, 256, 0, stream>>>(xb, Wt + 2097152ull,    bv, v);
  kvstate_k<<<dim3(NSC, BH_), 256, 0, stream>>>(kb, v, omb, stateb, ksum);
  scan_k<<<dim3(8, BH_), 256, 0, stream>>>(stateb, ksum);
  outchunk_k<<<BH_ * 64, 256, 0, stream>>>(qb, kb, v, omb, stateb, ksum, attn);
  mm_k<1><<<gg, 256, 0, stream>>>(attn, Wt + 3145728ull,  bo, out);
}

// Round 10
// 622.813 us; speedup vs baseline: 14.2585x; 1.0207x over previous
//
#include <hip/hip_runtime.h>
#include <hip/hip_bf16.h>

// FAVOR+ attention, MI355X. Round 10: barrier elision + alignment.
//  - outchunk: sA[64][264] (16B-aligned rows); barrier-free phi(q)/den/cross
//    (own-band intra-wave LDS ordering); ping-pong phi(k) buffers (1 bar/quad,
//    phi || S-MFMA overlap); den fully in-register (no dq/sden LDS).
//    Barriers/block ~19 -> 6(even c)/11(odd c).
//  - mm_k: bijective XCD swizzle (1D grid 1024): B panel L2-resident per XCD.
//  - kvstate / scan / convs / layout identical to validated R9.
//
// Workspace (bytes), total 211,845,120 (~202 MB):
//   v      bf16 [64bh][4096][64]   @ 0            (32 MB)
//   q      bf16                    @ 33,554,432   (32 MB)
//   k      bf16                    @ 67,108,864   (32 MB)
//   xb     bf16 [16384][1024]      @ 100,663,296  (32 MB) -- ALIASED attn
//   stateb bf16 [64bh][32][16384]  @ 134,217,728  (64 MB)
//   ksum   f32  [64bh][32][256]    @ 201,326,592  (2 MB)
//   Wt     bf16 4x[1024][1024]     @ 203,423,744  (8 MB)
//   omb    bf16 [256][64]          @ 211,812,352  (32 KB)

#define B_ 4
#define H_ 16
#define L_ 4096
#define D_ 64
#define M_ 256
#define DM_ 1024
#define BH_ 64
#define NSC 32            // superchunks per bh (SC = 128 tokens)

typedef unsigned int u32;
typedef unsigned short u16;
typedef __attribute__((ext_vector_type(8))) short bf16x8;
typedef __attribute__((ext_vector_type(4))) float f32x4;

static __device__ __forceinline__ float bf2f(u16 u) {
  return __uint_as_float(((u32)u) << 16);
}
static __device__ __forceinline__ u16 f2bf(float f) {
  u32 x = __float_as_uint(f);
  return (u16)((x + 0x7fffu + ((x >> 16) & 1u)) >> 16);   // RNE
}
#define MFMA16(a, b, c) __builtin_amdgcn_mfma_f32_16x16x32_bf16((a), (b), (c), 0, 0, 0)

// ---------------- converters ----------------------------------------------
__global__ __launch_bounds__(256) void convx_k(const float* __restrict__ x,
                                               u16* __restrict__ xb) {
  const int i = blockIdx.x * 256 + threadIdx.x;
  float4 f = ((const float4*)x)[i];
  ushort4 u;
  u.x = f2bf(f.x); u.y = f2bf(f.y); u.z = f2bf(f.z); u.w = f2bf(f.w);
  ((ushort4*)xb)[i] = u;
}

__global__ __launch_bounds__(256) void convw_k(
    const float* __restrict__ W0, const float* __restrict__ W1,
    const float* __restrict__ W2, const float* __restrict__ W3,
    u16* __restrict__ out) {
  __shared__ u16 tt[64][66];
  const int z = blockIdx.z;
  const float* W = (z == 0) ? W0 : (z == 1) ? W1 : (z == 2) ? W2 : W3;
  u16* o = out + (size_t)z * 1048576ull;
  const int k0 = blockIdx.y * 64, n0 = blockIdx.x * 64;
  const int r = threadIdx.x >> 4, c4 = (threadIdx.x & 15) << 2;
  for (int rr = r; rr < 64; rr += 16) {
    float4 w4 = *(const float4*)(W + (size_t)(k0 + rr) * DM_ + n0 + c4);
    tt[c4 + 0][rr] = f2bf(w4.x);
    tt[c4 + 1][rr] = f2bf(w4.y);
    tt[c4 + 2][rr] = f2bf(w4.z);
    tt[c4 + 3][rr] = f2bf(w4.w);
  }
  __syncthreads();
  for (int rr = r; rr < 64; rr += 16) {
    ushort4 u4;
    u4.x = tt[rr][c4 + 0];
    u4.y = tt[rr][c4 + 1];
    u4.z = tt[rr][c4 + 2];
    u4.w = tt[rr][c4 + 3];
    *(ushort4*)(o + (size_t)(n0 + rr) * DM_ + k0 + c4) = u4;
  }
}

__global__ __launch_bounds__(256) void convom_k(const float* __restrict__ om,
                                                u16* __restrict__ omb) {
  const int i = blockIdx.x * 256 + threadIdx.x;
  omb[i] = f2bf(om[i] * 0.35355339059327373f);       // fold 64^-0.25
}

// ---------------- bf16 MFMA GEMM, LDS-staged + XCD swizzle -----------------
// 1D grid of 1024 blocks; lb=(bid&7)*128+(bid>>3): each XCD owns 16 m-panels
// x all 8 n-tiles -> B (2MB) L2-resident per XCD.
template<int MODE>
__global__ __launch_bounds__(256) void mm_k(
    const u16* __restrict__ A, const u16* __restrict__ Bt,
    const float* __restrict__ bias, void* __restrict__ outp) {
  __shared__ u16 sA[128][64];   // 16 KB, XOR-swizzled 16B slots
  __shared__ u16 sB[128][64];   // 16 KB
  const int tid = threadIdx.x, lane = tid & 63, w = tid >> 6;
  const int fr = lane & 15, fg = lane >> 4;
  const int wr = w >> 1, wc = w & 1;
  const int lb = ((blockIdx.x & 7) << 7) | (blockIdx.x >> 3);
  const int m0 = (lb >> 3) * 128, n0 = (lb & 7) * 128;
  const int srow = tid >> 3, sslot = tid & 7;   // +p*32 rows per pass
  f32x4 acc[4][4] = {};
  bf16x8 av[4], bv[4];
#pragma unroll
  for (int p = 0; p < 4; ++p) {
    av[p] = *(const bf16x8*)(A  + (size_t)(m0 + srow + p * 32) * DM_ + sslot * 8);
    bv[p] = *(const bf16x8*)(Bt + (size_t)(n0 + srow + p * 32) * DM_ + sslot * 8);
  }
  for (int k0 = 0; k0 < DM_; k0 += 64) {
    __syncthreads();
#pragma unroll
    for (int p = 0; p < 4; ++p) {
      const int r = srow + p * 32;
      *(bf16x8*)&sA[r][(sslot ^ (r & 7)) * 8] = av[p];
      *(bf16x8*)&sB[r][(sslot ^ (r & 7)) * 8] = bv[p];
    }
    if (k0 + 64 < DM_) {
#pragma unroll
      for (int p = 0; p < 4; ++p) {
        av[p] = *(const bf16x8*)(A  + (size_t)(m0 + srow + p * 32) * DM_ + k0 + 64 + sslot * 8);
        bv[p] = *(const bf16x8*)(Bt + (size_t)(n0 + srow + p * 32) * DM_ + k0 + 64 + sslot * 8);
      }
    }
    __syncthreads();
#pragma unroll
    for (int ks = 0; ks < 2; ++ks) {
      bf16x8 af[4], bf[4];
#pragma unroll
      for (int i = 0; i < 4; ++i) {
        const int r = wr * 64 + i * 16 + fr;
        af[i] = *(const bf16x8*)&sA[r][((ks * 4 + fg) ^ (r & 7)) * 8];
      }
#pragma unroll
      for (int j = 0; j < 4; ++j) {
        const int r = wc * 64 + j * 16 + fr;
        bf[j] = *(const bf16x8*)&sB[r][((ks * 4 + fg) ^ (r & 7)) * 8];
      }
#pragma unroll
      for (int i = 0; i < 4; ++i)
#pragma unroll
        for (int j = 0; j < 4; ++j)
          acc[i][j] = MFMA16(af[i], bf[j], acc[i][j]);
    }
  }
  const int m_blk = m0 + wr * 64, n_blk = n0 + wc * 64;
#pragma unroll
  for (int j = 0; j < 4; ++j) {
    const int n = n_blk + j * 16 + fr;
    const float bi = bias[n];
    const int h = n >> 6, d = n & 63;
#pragma unroll
    for (int i = 0; i < 4; ++i) {
#pragma unroll
      for (int r = 0; r < 4; ++r) {
        const int m = m_blk + i * 16 + fg * 4 + r;
        const float val = acc[i][j][r] + bi;
        if (MODE == 0) {
          const int b = m >> 12, l = m & 4095;
          ((u16*)outp)[((size_t)(b * H_ + h) * L_ + l) * D_ + d] = f2bf(val);
        } else {
          ((float*)outp)[(size_t)m * DM_ + n] = val;
        }
      }
    }
  }
}

// ---------------- shared: LDS sumsq (kvstate, validated) -------------------
static __device__ __forceinline__ void sumsq_tile(
    const u16* __restrict__ xg, float (*ssq)[4], float* __restrict__ nh, int tid) {
  const int t = tid >> 2, qt = tid & 3;
  const u16* xp = xg + t * 64 + qt * 16;
  float s = 0.f;
#pragma unroll
  for (int jj = 0; jj < 2; ++jj) {
    bf16x8 xv = *(const bf16x8*)(xp + jj * 8);
#pragma unroll
    for (int e = 0; e < 8; ++e) { const float f = bf2f((u16)xv[e]); s += f * f; }
  }
  ssq[t][qt] = s;
  __syncthreads();
  if (tid < 64)
    nh[tid] = 0.0625f * (ssq[tid][0] + ssq[tid][1] + ssq[tid][2] + ssq[tid][3]);
  __syncthreads();
}

// ---------------- kvstate (MFMA, SC=128): bf16 state + f32 ksum ------------
__global__ __launch_bounds__(256) void kvstate_k(
    const u16* __restrict__ k, const u16* __restrict__ v,
    const u16* __restrict__ omb, u16* __restrict__ stateb,
    float* __restrict__ ksum) {
  __shared__ u16 sPhi[256][72];
  __shared__ u16 sVt[64][72];
  __shared__ float ssq[64][4];
  __shared__ float nh[64];
  const int tid = threadIdx.x, lane = tid & 63, w = tid >> 6;
  const int fr = lane & 15, fg = lane >> 4;
  const int sc = blockIdx.x, bh = blockIdx.y;
  const size_t base_l = (size_t)bh * L_ + (size_t)sc * 128;

  bf16x8 ones;
#pragma unroll
  for (int e = 0; e < 8; ++e) ones[e] = (short)0x3F80;

  f32x4 kvacc[4][4] = {};
  f32x4 ksacc[4] = {};

  for (int sub = 0; sub < 2; ++sub) {
    const size_t tl = base_l + sub * 64;
    const u16* kg = k + tl * 64;
    __syncthreads();
    {
      const u16* vp = v + (tl + lane) * 64 + w * 16;
      bf16x8 v0 = *(const bf16x8*)(vp);
      bf16x8 v1 = *(const bf16x8*)(vp + 8);
#pragma unroll
      for (int e = 0; e < 8; ++e) sVt[w * 16 + e][lane] = (u16)v0[e];
#pragma unroll
      for (int e = 0; e < 8; ++e) sVt[w * 16 + 8 + e][lane] = (u16)v1[e];
    }
    sumsq_tile(kg, ssq, nh, tid);
#pragma unroll
    for (int mi = 0; mi < 4; ++mi) {
      const int m0 = (w << 6) + mi * 16;
      const bf16x8 a0 = *(const bf16x8*)(omb + (m0 + fr) * 64 + fg * 8);
      const bf16x8 a1 = *(const bf16x8*)(omb + (m0 + fr) * 64 + 32 + fg * 8);
#pragma unroll
      for (int tt = 0; tt < 4; ++tt) {
        const bf16x8 b0 = *(const bf16x8*)(kg + (tt * 16 + fr) * 64 + fg * 8);
        const bf16x8 b1 = *(const bf16x8*)(kg + (tt * 16 + fr) * 64 + 32 + fg * 8);
        f32x4 acc = {0.f, 0.f, 0.f, 0.f};
        acc = MFMA16(a0, b0, acc);
        acc = MFMA16(a1, b1, acc);
        const float nhv = nh[tt * 16 + fr];
#pragma unroll
        for (int r = 0; r < 4; ++r)
          sPhi[m0 + fg * 4 + r][tt * 16 + fr] = f2bf(__expf(acc[r] - nhv) * 0.0625f);
      }
    }
    __syncthreads();
#pragma unroll
    for (int mi = 0; mi < 4; ++mi) {
      const int m0 = (w << 6) + mi * 16;
      const bf16x8 pb0 = *(const bf16x8*)&sPhi[m0 + fr][fg * 8];
      const bf16x8 pb1 = *(const bf16x8*)&sPhi[m0 + fr][32 + fg * 8];
      ksacc[mi] = MFMA16(pb0, ones, ksacc[mi]);
      ksacc[mi] = MFMA16(pb1, ones, ksacc[mi]);
#pragma unroll
      for (int dj = 0; dj < 4; ++dj) {
        const bf16x8 va0 = *(const bf16x8*)&sVt[dj * 16 + fr][fg * 8];
        const bf16x8 va1 = *(const bf16x8*)&sVt[dj * 16 + fr][32 + fg * 8];
        kvacc[mi][dj] = MFMA16(va0, pb0, kvacc[mi][dj]);
        kvacc[mi][dj] = MFMA16(va1, pb1, kvacc[mi][dj]);
      }
    }
  }
  // state bf16 [d][m]; ksum f32
  u16* stb = stateb + (size_t)(bh * NSC + sc) * (M_ * D_);
  float* ksp = ksum + (size_t)(bh * NSC + sc) * M_;
#pragma unroll
  for (int mi = 0; mi < 4; ++mi) {
    const int m = (w << 6) + mi * 16 + fr;
#pragma unroll
    for (int dj = 0; dj < 4; ++dj)
#pragma unroll
      for (int r = 0; r < 4; ++r)
        stb[(size_t)(dj * 16 + fg * 4 + r) * M_ + m] = f2bf(kvacc[mi][dj][r]);
    if (fr == 0) {
#pragma unroll
      for (int r = 0; r < 4; ++r)
        ksp[(w << 6) + mi * 16 + fg * 4 + r] = ksacc[mi][r];
    }
  }
}

// ---------------- exclusive prefix over superchunks (bf16 state) -----------
__global__ __launch_bounds__(256) void scan_k(u16* __restrict__ stateb,
                                              float* __restrict__ ksum) {
  const int bh = blockIdx.y;
  u16* sb = stateb + (size_t)bh * NSC * (M_ * D_);
  const int base = blockIdx.x * 2048 + threadIdx.x * 8;
  float run[8] = {};
  for (int cc = 0; cc < NSC; ++cc) {
    u16* st = sb + (size_t)cc * (M_ * D_) + base;
    ushort4 t0 = *(ushort4*)st;
    ushort4 t1 = *(ushort4*)(st + 4);
    ushort4 w0, w1;
    w0.x = f2bf(run[0]); w0.y = f2bf(run[1]); w0.z = f2bf(run[2]); w0.w = f2bf(run[3]);
    w1.x = f2bf(run[4]); w1.y = f2bf(run[5]); w1.z = f2bf(run[6]); w1.w = f2bf(run[7]);
    *(ushort4*)st = w0;
    *(ushort4*)(st + 4) = w1;
    run[0] += bf2f(t0.x); run[1] += bf2f(t0.y); run[2] += bf2f(t0.z); run[3] += bf2f(t0.w);
    run[4] += bf2f(t1.x); run[5] += bf2f(t1.y); run[6] += bf2f(t1.z); run[7] += bf2f(t1.w);
  }
  if (blockIdx.x == 0) {           // ksum f32 in-place exclusive prefix
    float rk = 0.f;
    for (int cc = 0; cc < NSC; ++cc) {
      float* p = ksum + (size_t)(bh * NSC + cc) * M_ + threadIdx.x;
      const float t = *p;
      *p = rk;
      rk += t;
    }
  }
}

// ---------------- outchunk helpers (validated) -----------------------------
static __device__ __forceinline__ void sumsq_wave(
    const u16* __restrict__ xg, int w, int lane, float* nhv) {
  const u16* xp = xg + (w * 16 + (lane & 15)) * 64;
  float s = 0.f;
#pragma unroll
  for (int p = 0; p < 8; ++p) {
    bf16x8 xv = *(const bf16x8*)(xp + p * 8);
#pragma unroll
    for (int e = 0; e < 8; ++e) { const float f = bf2f((u16)xv[e]); s += f * f; }
  }
  s *= 0.0625f;
  const int fg = lane >> 4;
#pragma unroll
  for (int r = 0; r < 4; ++r) nhv[r] = __shfl(s, fg * 4 + r, 64);
}

// phi quadrant: writes ONLY rows of the calling wave's band (w*16..w*16+15)
static __device__ __forceinline__ void phi_quad(
    const u16* __restrict__ xg, const u16* __restrict__ ombq,
    u16* __restrict__ dst, int dstride, const float* nhv,
    int w, int lane) {
  const int fr = lane & 15, fg = lane >> 4;
  const int tband = w * 16;
  const bf16x8 a0 = *(const bf16x8*)(xg + (tband + fr) * 64 + fg * 8);
  const bf16x8 a1 = *(const bf16x8*)(xg + (tband + fr) * 64 + 32 + fg * 8);
#pragma unroll
  for (int j = 0; j < 4; ++j) {
    const bf16x8 b0 = *(const bf16x8*)(ombq + (j * 16 + fr) * 64 + fg * 8);
    const bf16x8 b1 = *(const bf16x8*)(ombq + (j * 16 + fr) * 64 + 32 + fg * 8);
    f32x4 acc = {0.f, 0.f, 0.f, 0.f};
    acc = MFMA16(a0, b0, acc);
    acc = MFMA16(a1, b1, acc);
#pragma unroll
    for (int r = 0; r < 4; ++r) {
      const int t = tband + fg * 4 + r;
      dst[t * dstride + j * 16 + fr] = f2bf(__expf(acc[r] - nhv[r]) * 0.0625f);
    }
  }
}

// ---------------- outchunk: barrier-minimal (6 or 11 bars/block) -----------
__global__ __launch_bounds__(256) void outchunk_k(
    const u16* __restrict__ q, const u16* __restrict__ kk,
    const u16* __restrict__ v, const u16* __restrict__ omb,
    const u16* __restrict__ stateb, const float* __restrict__ ksum,
    u16* __restrict__ attn) {
  __shared__ u16 sA[64][264];     // Qp full (aligned rows)  33,792 B
  __shared__ u16 sK0[64][72];     // phi(k) ping / masked S   9,216 B
  __shared__ u16 sK1[64][72];     // phi(k) pong              9,216 B
  __shared__ u16 sB1[64][72];     // vT                       9,216 B
  __shared__ float ksum_l[256];   //  1,024 B     total 62,464 B -> 2/CU
  const int tid = threadIdx.x, lane = tid & 63, w = tid >> 6;
  const int fr = lane & 15, fg = lane >> 4;
  // XCD swizzle: chunks of a superchunk -> same XCD (state L2-resident)
  const int lbid = ((blockIdx.x & 7) << 9) | (blockIdx.x >> 3);
  const int bh = lbid >> 6, c = lbid & 63;
  const int sc = c >> 1;          // SC = 128 tokens = 2 chunks
  const size_t tok0 = (size_t)bh * L_ + (size_t)c * 64;
  const u16* qg = q + tok0 * 64;
  const u16* stgb = stateb + (size_t)(bh * NSC + sc) * (M_ * D_);   // [d][m]
  const float* ksg = ksum + (size_t)(bh * NSC + sc) * M_;

  ksum_l[tid] = ksg[tid];

  // phi(q) -> sA: own-band writes; all later sA readers are own-band too,
  // so no barrier is needed for sA (intra-wave lgkmcnt ordering).
  float nhq[4];
  sumsq_wave(qg, w, lane, nhq);
#pragma unroll 1
  for (int mq = 0; mq < 4; ++mq)
    phi_quad(qg, omb + mq * 4096, &sA[0][mq * 64], 264, nhq, w, lane);
  __syncthreads();   // BAR P: ksum_l cross-thread visibility only

  // den-ksum: lane (fr,fg): token t=w*16+fr, m-quarter fg; reduce over fg.
  float denk = 0.f;
#pragma unroll
  for (int g8 = 0; g8 < 8; ++g8) {
    bf16x8 qv = *(const bf16x8*)&sA[w * 16 + fr][fg * 64 + g8 * 8];
#pragma unroll
    for (int e = 0; e < 8; ++e)
      denk += bf2f((u16)qv[e]) * ksum_l[fg * 64 + g8 * 8 + e];
  }
  denk += __shfl_xor(denk, 16, 64);
  denk += __shfl_xor(denk, 32, 64);   // all lanes: full den-k for token w*16+fr

  // ---- cross term: Qp @ KVex, B-frags DIRECT from global (bf16 [d][m])
  f32x4 oacc[4] = {};
  __builtin_amdgcn_s_setprio(1);
#pragma unroll
  for (int mq = 0; mq < 4; ++mq) {
    const bf16x8 a0 = *(const bf16x8*)&sA[w * 16 + fr][mq * 64 + fg * 8];
    const bf16x8 a1 = *(const bf16x8*)&sA[w * 16 + fr][mq * 64 + 32 + fg * 8];
#pragma unroll
    for (int j = 0; j < 4; ++j) {
      const bf16x8 b0 = *(const bf16x8*)(stgb + (size_t)(j * 16 + fr) * M_ + mq * 64 + fg * 8);
      const bf16x8 b1 = *(const bf16x8*)(stgb + (size_t)(j * 16 + fr) * M_ + mq * 64 + 32 + fg * 8);
      oacc[j] = MFMA16(a0, b0, oacc[j]);
      oacc[j] = MFMA16(a1, b1, oacc[j]);
    }
  }
  __builtin_amdgcn_s_setprio(0);

  // ---- source chunks (1 or 2): ping-pong phi(k), 5 bars per chunk
  float dS[4] = {0.f, 0.f, 0.f, 0.f};   // S-den for tokens w*16+fg*4+r
#pragma unroll 1
  for (int s_c = sc * 2; s_c <= c; ++s_c) {
    const size_t ktok = (size_t)bh * L_ + (size_t)s_c * 64;
    const u16* kg = kk + ktok * 64;
    float nhk[4];
    sumsq_wave(kg, w, lane, nhk);
    f32x4 sacc[4] = {};
    // phi(k) quadrant 0 -> sK0 (own-band; prior cross-readers of sK0 from the
    // previous chunk finished before its BAR A..E chain — see BAR A note)
    phi_quad(kg, omb, &sK0[0][0], 72, nhk, w, lane);
    __syncthreads();   // BAR A (mq=0 ready; also fences prev chunk's sB1 readers)
#pragma unroll 1
    for (int mq = 0; mq < 4; ++mq) {
      u16* nxt = ((mq & 1) == 0) ? &sK1[0][0] : &sK0[0][0];
      const u16 (*cur)[72] = ((mq & 1) == 0) ? sK0 : sK1;
      if (mq < 3)   // issue next phi first: VALU/MFMA of phi overlaps S-MFMA
        phi_quad(kg, omb + (mq + 1) * 4096, nxt, 72, nhk, w, lane);
      const bf16x8 a0 = *(const bf16x8*)&sA[w * 16 + fr][mq * 64 + fg * 8];
      const bf16x8 a1 = *(const bf16x8*)&sA[w * 16 + fr][mq * 64 + 32 + fg * 8];
      __builtin_amdgcn_s_setprio(1);
#pragma unroll
      for (int j = 0; j < 4; ++j) {
        const bf16x8 b0 = *(const bf16x8*)&cur[j * 16 + fr][fg * 8];
        const bf16x8 b1 = *(const bf16x8*)&cur[j * 16 + fr][32 + fg * 8];
        sacc[j] = MFMA16(a0, b0, sacc[j]);
        sacc[j] = MFMA16(a1, b1, sacc[j]);
      }
      __builtin_amdgcn_s_setprio(0);
      __syncthreads();   // BAR B/C/D/E: next-quadrant buffer ready / WAR fence
    }
    // masked S -> sK0 (own rows; sK0's cross-readers SMFMA0/2 done by BAR D;
    // concurrent SMFMA3 reads sK1 only). dS accumulated from ROUNDED value.
    const bool diag = (s_c == c);
#pragma unroll
    for (int j = 0; j < 4; ++j)
#pragma unroll
      for (int r = 0; r < 4; ++r) {
        const int s = j * 16 + fr, t = w * 16 + fg * 4 + r;
        float val = sacc[j][r];
        if (diag && s > t) val = 0.f;
        const u16 vb = f2bf(val);
        sK0[t][s] = vb;
        dS[r] += bf2f(vb);
      }
    {  // vT staging (own rows; prev readers fenced by this chunk's BAR A)
      const u16* vp = v + (ktok + lane) * 64 + w * 16;
      bf16x8 v0 = *(const bf16x8*)(vp);
      bf16x8 v1 = *(const bf16x8*)(vp + 8);
#pragma unroll
      for (int e = 0; e < 8; ++e) sB1[w * 16 + e][lane] = (u16)v0[e];
#pragma unroll
      for (int e = 0; e < 8; ++e) sB1[w * 16 + 8 + e][lane] = (u16)v1[e];
    }
    __syncthreads();   // BAR F: masked S + vT visible for S@V
    // S @ V (A-frag: sK0 own band; B-frag: sB1 cross band)
    {
      const bf16x8 a0 = *(const bf16x8*)&sK0[w * 16 + fr][fg * 8];
      const bf16x8 a1 = *(const bf16x8*)&sK0[w * 16 + fr][32 + fg * 8];
      __builtin_amdgcn_s_setprio(1);
#pragma unroll
      for (int j = 0; j < 4; ++j) {
        const bf16x8 b0 = *(const bf16x8*)&sB1[j * 16 + fr][fg * 8];
        const bf16x8 b1 = *(const bf16x8*)&sB1[j * 16 + fr][32 + fg * 8];
        oacc[j] = MFMA16(a0, b0, oacc[j]);
        oacc[j] = MFMA16(a1, b1, oacc[j]);
      }
      __builtin_amdgcn_s_setprio(0);
    }
    // no trailing barrier: next chunk's BAR A fences sB1/sK1 reuse; sK0's
    // next writer (phi0) is own-band = intra-wave ordered.
  }

  // den: reduce dS over fr lanes (same fg); combine with denk via shfl.
#pragma unroll
  for (int m2 = 1; m2 <= 8; m2 <<= 1) {
#pragma unroll
    for (int r = 0; r < 4; ++r) dS[r] += __shfl_xor(dS[r], m2, 64);
  }
  const int b = bh >> 4, hh = bh & 15;
#pragma unroll
  for (int r = 0; r < 4; ++r) {
    const float dk = __shfl(denk, fg * 4 + r, 64);   // token w*16+fg*4+r
    const float rinv = 1.0f / (dk + dS[r] + 1e-6f);
    const int t = w * 16 + fg * 4 + r;
    const int l = c * 64 + t;
#pragma unroll
    for (int j = 0; j < 4; ++j) {
      const int d = j * 16 + fr;
      attn[((size_t)b * L_ + l) * DM_ + hh * 64 + d] = f2bf(oacc[j][r] * rinv);
    }
  }
}

extern "C" void kernel_launch(void* const* d_in, const int* in_sizes, int n_in,
                              void* d_out, int out_size, void* d_ws, size_t ws_size,
                              hipStream_t stream) {
  const float* x     = (const float*)d_in[0];
  const float* Wq    = (const float*)d_in[1];
  const float* bq    = (const float*)d_in[2];
  const float* Wk    = (const float*)d_in[3];
  const float* bk    = (const float*)d_in[4];
  const float* Wv    = (const float*)d_in[5];
  const float* bv    = (const float*)d_in[6];
  const float* Wo    = (const float*)d_in[7];
  const float* bo    = (const float*)d_in[8];
  const float* omega = (const float*)d_in[9];
  float* out = (float*)d_out;

  char* ws = (char*)d_ws;
  u16*   v      = (u16*)(ws);                           // 32 MB
  u16*   qb     = (u16*)(ws + 33554432ull);             // 32 MB
  u16*   kb     = (u16*)(ws + 67108864ull);             // 32 MB
  u16*   xb     = (u16*)(ws + 100663296ull);            // 32 MB (alias attn)
  u16*   attn   = xb;
  u16*   stateb = (u16*)(ws + 134217728ull);            // 64 MB
  float* ksum   = (float*)(ws + 201326592ull);          // 2 MB
  u16*   Wt     = (u16*)(ws + 203423744ull);            // 8 MB
  u16*   omb    = (u16*)(ws + 211812352ull);            // 32 KB -> 202 MB

  convx_k<<<16384, 256, 0, stream>>>(x, xb);
  convw_k<<<dim3(16, 16, 4), 256, 0, stream>>>(Wq, Wk, Wv, Wo, Wt);
  convom_k<<<64, 256, 0, stream>>>(omega, omb);

  mm_k<0><<<1024, 256, 0, stream>>>(xb, Wt,                 bq, qb);
  mm_k<0><<<1024, 256, 0, stream>>>(xb, Wt + 1048576ull,    bk, kb);
  mm_k<0><<<1024, 256, 0, stream>>>(xb, Wt + 2097152ull,    bv, v);
  kvstate_k<<<dim3(NSC, BH_), 256, 0, stream>>>(kb, v, omb, stateb, ksum);
  scan_k<<<dim3(8, BH_), 256, 0, stream>>>(stateb, ksum);
  outchunk_k<<<BH_ * 64, 256, 0, stream>>>(qb, kb, v, omb, stateb, ksum, attn);
  mm_k<1><<<1024, 256, 0, stream>>>(attn, Wt + 3145728ull,  bo, out);
}

// Round 11
// 594.694 us; speedup vs baseline: 14.9327x; 1.0473x over previous
//
#include <hip/hip_runtime.h>
#include <hip/hip_bf16.h>

// FAVOR+ attention, MI355X. Round 11: merged superchunk blocks (512 thr).
//  - outchunk: one block per (bh, sc=128 tokens); waves 0-3 = q-half 0,
//    waves 4-7 = q-half 1. phi(k) computed ONCE per source chunk (quadrant
//    production alternates halves, ping-pong sK0/sK1); masked-S aliases the
//    ping-pong buffers (R10-validated); vT by half 0; cross term direct from
//    global bf16 state. 13 barriers/block, 2048 blocks (8 rounds/CU).
//  - mm_k (XCD-swizzled) / kvstate / scan / convs: byte-identical to R10.
//
// Workspace (bytes), total 211,845,120 (~202 MB):
//   v      bf16 [64bh][4096][64]   @ 0            (32 MB)
//   q      bf16                    @ 33,554,432   (32 MB)
//   k      bf16                    @ 67,108,864   (32 MB)
//   xb     bf16 [16384][1024]      @ 100,663,296  (32 MB) -- ALIASED attn
//   stateb bf16 [64bh][32][16384]  @ 134,217,728  (64 MB)
//   ksum   f32  [64bh][32][256]    @ 201,326,592  (2 MB)
//   Wt     bf16 4x[1024][1024]     @ 203,423,744  (8 MB)
//   omb    bf16 [256][64]          @ 211,812,352  (32 KB)

#define B_ 4
#define H_ 16
#define L_ 4096
#define D_ 64
#define M_ 256
#define DM_ 1024
#define BH_ 64
#define NSC 32            // superchunks per bh (SC = 128 tokens)

typedef unsigned int u32;
typedef unsigned short u16;
typedef __attribute__((ext_vector_type(8))) short bf16x8;
typedef __attribute__((ext_vector_type(4))) float f32x4;

static __device__ __forceinline__ float bf2f(u16 u) {
  return __uint_as_float(((u32)u) << 16);
}
static __device__ __forceinline__ u16 f2bf(float f) {
  u32 x = __float_as_uint(f);
  return (u16)((x + 0x7fffu + ((x >> 16) & 1u)) >> 16);   // RNE
}
#define MFMA16(a, b, c) __builtin_amdgcn_mfma_f32_16x16x32_bf16((a), (b), (c), 0, 0, 0)

// ---------------- converters ----------------------------------------------
__global__ __launch_bounds__(256) void convx_k(const float* __restrict__ x,
                                               u16* __restrict__ xb) {
  const int i = blockIdx.x * 256 + threadIdx.x;
  float4 f = ((const float4*)x)[i];
  ushort4 u;
  u.x = f2bf(f.x); u.y = f2bf(f.y); u.z = f2bf(f.z); u.w = f2bf(f.w);
  ((ushort4*)xb)[i] = u;
}

__global__ __launch_bounds__(256) void convw_k(
    const float* __restrict__ W0, const float* __restrict__ W1,
    const float* __restrict__ W2, const float* __restrict__ W3,
    u16* __restrict__ out) {
  __shared__ u16 tt[64][66];
  const int z = blockIdx.z;
  const float* W = (z == 0) ? W0 : (z == 1) ? W1 : (z == 2) ? W2 : W3;
  u16* o = out + (size_t)z * 1048576ull;
  const int k0 = blockIdx.y * 64, n0 = blockIdx.x * 64;
  const int r = threadIdx.x >> 4, c4 = (threadIdx.x & 15) << 2;
  for (int rr = r; rr < 64; rr += 16) {
    float4 w4 = *(const float4*)(W + (size_t)(k0 + rr) * DM_ + n0 + c4);
    tt[c4 + 0][rr] = f2bf(w4.x);
    tt[c4 + 1][rr] = f2bf(w4.y);
    tt[c4 + 2][rr] = f2bf(w4.z);
    tt[c4 + 3][rr] = f2bf(w4.w);
  }
  __syncthreads();
  for (int rr = r; rr < 64; rr += 16) {
    ushort4 u4;
    u4.x = tt[rr][c4 + 0];
    u4.y = tt[rr][c4 + 1];
    u4.z = tt[rr][c4 + 2];
    u4.w = tt[rr][c4 + 3];
    *(ushort4*)(o + (size_t)(n0 + rr) * DM_ + k0 + c4) = u4;
  }
}

__global__ __launch_bounds__(256) void convom_k(const float* __restrict__ om,
                                                u16* __restrict__ omb) {
  const int i = blockIdx.x * 256 + threadIdx.x;
  omb[i] = f2bf(om[i] * 0.35355339059327373f);       // fold 64^-0.25
}

// ---------------- bf16 MFMA GEMM, LDS-staged + XCD swizzle (R10) -----------
template<int MODE>
__global__ __launch_bounds__(256) void mm_k(
    const u16* __restrict__ A, const u16* __restrict__ Bt,
    const float* __restrict__ bias, void* __restrict__ outp) {
  __shared__ u16 sA[128][64];   // 16 KB, XOR-swizzled 16B slots
  __shared__ u16 sB[128][64];   // 16 KB
  const int tid = threadIdx.x, lane = tid & 63, w = tid >> 6;
  const int fr = lane & 15, fg = lane >> 4;
  const int wr = w >> 1, wc = w & 1;
  const int lb = ((blockIdx.x & 7) << 7) | (blockIdx.x >> 3);
  const int m0 = (lb >> 3) * 128, n0 = (lb & 7) * 128;
  const int srow = tid >> 3, sslot = tid & 7;   // +p*32 rows per pass
  f32x4 acc[4][4] = {};
  bf16x8 av[4], bv[4];
#pragma unroll
  for (int p = 0; p < 4; ++p) {
    av[p] = *(const bf16x8*)(A  + (size_t)(m0 + srow + p * 32) * DM_ + sslot * 8);
    bv[p] = *(const bf16x8*)(Bt + (size_t)(n0 + srow + p * 32) * DM_ + sslot * 8);
  }
  for (int k0 = 0; k0 < DM_; k0 += 64) {
    __syncthreads();
#pragma unroll
    for (int p = 0; p < 4; ++p) {
      const int r = srow + p * 32;
      *(bf16x8*)&sA[r][(sslot ^ (r & 7)) * 8] = av[p];
      *(bf16x8*)&sB[r][(sslot ^ (r & 7)) * 8] = bv[p];
    }
    if (k0 + 64 < DM_) {
#pragma unroll
      for (int p = 0; p < 4; ++p) {
        av[p] = *(const bf16x8*)(A  + (size_t)(m0 + srow + p * 32) * DM_ + k0 + 64 + sslot * 8);
        bv[p] = *(const bf16x8*)(Bt + (size_t)(n0 + srow + p * 32) * DM_ + k0 + 64 + sslot * 8);
      }
    }
    __syncthreads();
#pragma unroll
    for (int ks = 0; ks < 2; ++ks) {
      bf16x8 af[4], bf[4];
#pragma unroll
      for (int i = 0; i < 4; ++i) {
        const int r = wr * 64 + i * 16 + fr;
        af[i] = *(const bf16x8*)&sA[r][((ks * 4 + fg) ^ (r & 7)) * 8];
      }
#pragma unroll
      for (int j = 0; j < 4; ++j) {
        const int r = wc * 64 + j * 16 + fr;
        bf[j] = *(const bf16x8*)&sB[r][((ks * 4 + fg) ^ (r & 7)) * 8];
      }
#pragma unroll
      for (int i = 0; i < 4; ++i)
#pragma unroll
        for (int j = 0; j < 4; ++j)
          acc[i][j] = MFMA16(af[i], bf[j], acc[i][j]);
    }
  }
  const int m_blk = m0 + wr * 64, n_blk = n0 + wc * 64;
#pragma unroll
  for (int j = 0; j < 4; ++j) {
    const int n = n_blk + j * 16 + fr;
    const float bi = bias[n];
    const int h = n >> 6, d = n & 63;
#pragma unroll
    for (int i = 0; i < 4; ++i) {
#pragma unroll
      for (int r = 0; r < 4; ++r) {
        const int m = m_blk + i * 16 + fg * 4 + r;
        const float val = acc[i][j][r] + bi;
        if (MODE == 0) {
          const int b = m >> 12, l = m & 4095;
          ((u16*)outp)[((size_t)(b * H_ + h) * L_ + l) * D_ + d] = f2bf(val);
        } else {
          ((float*)outp)[(size_t)m * DM_ + n] = val;
        }
      }
    }
  }
}

// ---------------- shared: LDS sumsq (kvstate, validated) -------------------
static __device__ __forceinline__ void sumsq_tile(
    const u16* __restrict__ xg, float (*ssq)[4], float* __restrict__ nh, int tid) {
  const int t = tid >> 2, qt = tid & 3;
  const u16* xp = xg + t * 64 + qt * 16;
  float s = 0.f;
#pragma unroll
  for (int jj = 0; jj < 2; ++jj) {
    bf16x8 xv = *(const bf16x8*)(xp + jj * 8);
#pragma unroll
    for (int e = 0; e < 8; ++e) { const float f = bf2f((u16)xv[e]); s += f * f; }
  }
  ssq[t][qt] = s;
  __syncthreads();
  if (tid < 64)
    nh[tid] = 0.0625f * (ssq[tid][0] + ssq[tid][1] + ssq[tid][2] + ssq[tid][3]);
  __syncthreads();
}

// ---------------- kvstate (MFMA, SC=128): bf16 state + f32 ksum ------------
__global__ __launch_bounds__(256) void kvstate_k(
    const u16* __restrict__ k, const u16* __restrict__ v,
    const u16* __restrict__ omb, u16* __restrict__ stateb,
    float* __restrict__ ksum) {
  __shared__ u16 sPhi[256][72];
  __shared__ u16 sVt[64][72];
  __shared__ float ssq[64][4];
  __shared__ float nh[64];
  const int tid = threadIdx.x, lane = tid & 63, w = tid >> 6;
  const int fr = lane & 15, fg = lane >> 4;
  const int sc = blockIdx.x, bh = blockIdx.y;
  const size_t base_l = (size_t)bh * L_ + (size_t)sc * 128;

  bf16x8 ones;
#pragma unroll
  for (int e = 0; e < 8; ++e) ones[e] = (short)0x3F80;

  f32x4 kvacc[4][4] = {};
  f32x4 ksacc[4] = {};

  for (int sub = 0; sub < 2; ++sub) {
    const size_t tl = base_l + sub * 64;
    const u16* kg = k + tl * 64;
    __syncthreads();
    {
      const u16* vp = v + (tl + lane) * 64 + w * 16;
      bf16x8 v0 = *(const bf16x8*)(vp);
      bf16x8 v1 = *(const bf16x8*)(vp + 8);
#pragma unroll
      for (int e = 0; e < 8; ++e) sVt[w * 16 + e][lane] = (u16)v0[e];
#pragma unroll
      for (int e = 0; e < 8; ++e) sVt[w * 16 + 8 + e][lane] = (u16)v1[e];
    }
    sumsq_tile(kg, ssq, nh, tid);
#pragma unroll
    for (int mi = 0; mi < 4; ++mi) {
      const int m0 = (w << 6) + mi * 16;
      const bf16x8 a0 = *(const bf16x8*)(omb + (m0 + fr) * 64 + fg * 8);
      const bf16x8 a1 = *(const bf16x8*)(omb + (m0 + fr) * 64 + 32 + fg * 8);
#pragma unroll
      for (int tt = 0; tt < 4; ++tt) {
        const bf16x8 b0 = *(const bf16x8*)(kg + (tt * 16 + fr) * 64 + fg * 8);
        const bf16x8 b1 = *(const bf16x8*)(kg + (tt * 16 + fr) * 64 + 32 + fg * 8);
        f32x4 acc = {0.f, 0.f, 0.f, 0.f};
        acc = MFMA16(a0, b0, acc);
        acc = MFMA16(a1, b1, acc);
        const float nhv = nh[tt * 16 + fr];
#pragma unroll
        for (int r = 0; r < 4; ++r)
          sPhi[m0 + fg * 4 + r][tt * 16 + fr] = f2bf(__expf(acc[r] - nhv) * 0.0625f);
      }
    }
    __syncthreads();
#pragma unroll
    for (int mi = 0; mi < 4; ++mi) {
      const int m0 = (w << 6) + mi * 16;
      const bf16x8 pb0 = *(const bf16x8*)&sPhi[m0 + fr][fg * 8];
      const bf16x8 pb1 = *(const bf16x8*)&sPhi[m0 + fr][32 + fg * 8];
      ksacc[mi] = MFMA16(pb0, ones, ksacc[mi]);
      ksacc[mi] = MFMA16(pb1, ones, ksacc[mi]);
#pragma unroll
      for (int dj = 0; dj < 4; ++dj) {
        const bf16x8 va0 = *(const bf16x8*)&sVt[dj * 16 + fr][fg * 8];
        const bf16x8 va1 = *(const bf16x8*)&sVt[dj * 16 + fr][32 + fg * 8];
        kvacc[mi][dj] = MFMA16(va0, pb0, kvacc[mi][dj]);
        kvacc[mi][dj] = MFMA16(va1, pb1, kvacc[mi][dj]);
      }
    }
  }
  // state bf16 [d][m]; ksum f32
  u16* stb = stateb + (size_t)(bh * NSC + sc) * (M_ * D_);
  float* ksp = ksum + (size_t)(bh * NSC + sc) * M_;
#pragma unroll
  for (int mi = 0; mi < 4; ++mi) {
    const int m = (w << 6) + mi * 16 + fr;
#pragma unroll
    for (int dj = 0; dj < 4; ++dj)
#pragma unroll
      for (int r = 0; r < 4; ++r)
        stb[(size_t)(dj * 16 + fg * 4 + r) * M_ + m] = f2bf(kvacc[mi][dj][r]);
    if (fr == 0) {
#pragma unroll
      for (int r = 0; r < 4; ++r)
        ksp[(w << 6) + mi * 16 + fg * 4 + r] = ksacc[mi][r];
    }
  }
}

// ---------------- exclusive prefix over superchunks (bf16 state) -----------
__global__ __launch_bounds__(256) void scan_k(u16* __restrict__ stateb,
                                              float* __restrict__ ksum) {
  const int bh = blockIdx.y;
  u16* sb = stateb + (size_t)bh * NSC * (M_ * D_);
  const int base = blockIdx.x * 2048 + threadIdx.x * 8;
  float run[8] = {};
  for (int cc = 0; cc < NSC; ++cc) {
    u16* st = sb + (size_t)cc * (M_ * D_) + base;
    ushort4 t0 = *(ushort4*)st;
    ushort4 t1 = *(ushort4*)(st + 4);
    ushort4 w0, w1;
    w0.x = f2bf(run[0]); w0.y = f2bf(run[1]); w0.z = f2bf(run[2]); w0.w = f2bf(run[3]);
    w1.x = f2bf(run[4]); w1.y = f2bf(run[5]); w1.z = f2bf(run[6]); w1.w = f2bf(run[7]);
    *(ushort4*)st = w0;
    *(ushort4*)(st + 4) = w1;
    run[0] += bf2f(t0.x); run[1] += bf2f(t0.y); run[2] += bf2f(t0.z); run[3] += bf2f(t0.w);
    run[4] += bf2f(t1.x); run[5] += bf2f(t1.y); run[6] += bf2f(t1.z); run[7] += bf2f(t1.w);
  }
  if (blockIdx.x == 0) {           // ksum f32 in-place exclusive prefix
    float rk = 0.f;
    for (int cc = 0; cc < NSC; ++cc) {
      float* p = ksum + (size_t)(bh * NSC + cc) * M_ + threadIdx.x;
      const float t = *p;
      *p = rk;
      rk += t;
    }
  }
}

// ---------------- outchunk helpers (validated) -----------------------------
// per-wave sumsq via shfl; band index wb in [0,4)
static __device__ __forceinline__ void sumsq_wave(
    const u16* __restrict__ xg, int wb, int lane, float* nhv) {
  const u16* xp = xg + (wb * 16 + (lane & 15)) * 64;
  float s = 0.f;
#pragma unroll
  for (int p = 0; p < 8; ++p) {
    bf16x8 xv = *(const bf16x8*)(xp + p * 8);
#pragma unroll
    for (int e = 0; e < 8; ++e) { const float f = bf2f((u16)xv[e]); s += f * f; }
  }
  s *= 0.0625f;
  const int fg = lane >> 4;
#pragma unroll
  for (int r = 0; r < 4; ++r) nhv[r] = __shfl(s, fg * 4 + r, 64);
}

// phi quadrant: writes ONLY rows of band wb (wb*16..wb*16+15)
static __device__ __forceinline__ void phi_quad(
    const u16* __restrict__ xg, const u16* __restrict__ ombq,
    u16* __restrict__ dst, int dstride, const float* nhv,
    int wb, int lane) {
  const int fr = lane & 15, fg = lane >> 4;
  const int tband = wb * 16;
  const bf16x8 a0 = *(const bf16x8*)(xg + (tband + fr) * 64 + fg * 8);
  const bf16x8 a1 = *(const bf16x8*)(xg + (tband + fr) * 64 + 32 + fg * 8);
#pragma unroll
  for (int j = 0; j < 4; ++j) {
    const bf16x8 b0 = *(const bf16x8*)(ombq + (j * 16 + fr) * 64 + fg * 8);
    const bf16x8 b1 = *(const bf16x8*)(ombq + (j * 16 + fr) * 64 + 32 + fg * 8);
    f32x4 acc = {0.f, 0.f, 0.f, 0.f};
    acc = MFMA16(a0, b0, acc);
    acc = MFMA16(a1, b1, acc);
#pragma unroll
    for (int r = 0; r < 4; ++r) {
      const int t = tband + fg * 4 + r;
      dst[t * dstride + j * 16 + fr] = f2bf(__expf(acc[r] - nhv[r]) * 0.0625f);
    }
  }
}

// ---------------- outchunk: merged superchunk, 512 threads -----------------
__global__ __launch_bounds__(512) void outchunk_k(
    const u16* __restrict__ q, const u16* __restrict__ kk,
    const u16* __restrict__ v, const u16* __restrict__ omb,
    const u16* __restrict__ stateb, const float* __restrict__ ksum,
    u16* __restrict__ attn) {
  __shared__ u16 sA[2][64][264];  // Qp per half            67,584 B
  __shared__ u16 sK0[64][72];     // phi(k) ping / h0 S      9,216 B
  __shared__ u16 sK1[64][72];     // phi(k) pong / h1 S      9,216 B
  __shared__ u16 sB1[64][72];     // vT                      9,216 B
  __shared__ float ksum_l[256];   //  1,024 B   total 96,256 B -> 1/CU
  const int tid = threadIdx.x, lane = tid & 63, w = tid >> 6;
  const int h = w >> 2, wl = w & 3;
  const int fr = lane & 15, fg = lane >> 4;
  const int bh = blockIdx.x >> 5, sc = blockIdx.x & 31;
  const size_t tokq = (size_t)bh * L_ + (size_t)sc * 128 + (size_t)h * 64;
  const u16* qg = q + tokq * 64;
  const u16* stgb = stateb + (size_t)(bh * NSC + sc) * (M_ * D_);   // [d][m]
  const float* ksg = ksum + (size_t)(bh * NSC + sc) * M_;

  if (tid < 256) ksum_l[tid] = ksg[tid];

  // phi(q) -> sA[h]: own-band writes, later readers same-wave own-band.
  float nhq[4];
  sumsq_wave(qg, wl, lane, nhq);
#pragma unroll 1
  for (int mq = 0; mq < 4; ++mq)
    phi_quad(qg, omb + mq * 4096, &sA[h][0][mq * 64], 264, nhq, wl, lane);
  __syncthreads();   // BAR P: ksum_l visibility

  // den-ksum (R10-validated): lane (fr,fg) -> token wl*16+fr, m-quarter fg
  float denk = 0.f;
#pragma unroll
  for (int g8 = 0; g8 < 8; ++g8) {
    bf16x8 qv = *(const bf16x8*)&sA[h][wl * 16 + fr][fg * 64 + g8 * 8];
#pragma unroll
    for (int e = 0; e < 8; ++e)
      denk += bf2f((u16)qv[e]) * ksum_l[fg * 64 + g8 * 8 + e];
  }
  denk += __shfl_xor(denk, 16, 64);
  denk += __shfl_xor(denk, 32, 64);

  // cross term: Qp @ KVex, B-frags direct from global bf16 [d][m]
  f32x4 oacc[4] = {};
  __builtin_amdgcn_s_setprio(1);
#pragma unroll
  for (int mq = 0; mq < 4; ++mq) {
    const bf16x8 a0 = *(const bf16x8*)&sA[h][wl * 16 + fr][mq * 64 + fg * 8];
    const bf16x8 a1 = *(const bf16x8*)&sA[h][wl * 16 + fr][mq * 64 + 32 + fg * 8];
#pragma unroll
    for (int j = 0; j < 4; ++j) {
      const bf16x8 b0 = *(const bf16x8*)(stgb + (size_t)(j * 16 + fr) * M_ + mq * 64 + fg * 8);
      const bf16x8 b1 = *(const bf16x8*)(stgb + (size_t)(j * 16 + fr) * M_ + mq * 64 + 32 + fg * 8);
      oacc[j] = MFMA16(a0, b0, oacc[j]);
      oacc[j] = MFMA16(a1, b1, oacc[j]);
    }
  }
  __builtin_amdgcn_s_setprio(0);

  // ---- source chunks s=0,1. phi(k) quadrant mq produced by half (mq&1);
  //      half0 participates in S/SV only at s=0; diag mask when s==h.
  float dS[4] = {0.f, 0.f, 0.f, 0.f};
#pragma unroll 1
  for (int s = 0; s < 2; ++s) {
    const size_t ktok = (size_t)bh * L_ + (size_t)sc * 128 + (size_t)s * 64;
    const u16* kg = kk + ktok * 64;
    const bool part = (h == 1) || (s == 0);
    const bool diag = (s == h);
    float nhk[4];
    sumsq_wave(kg, wl, lane, nhk);
    f32x4 sacc[4] = {};
    if (h == 0)   // quadrant 0 producer (sK0 WAR: prior reads were same-wave)
      phi_quad(kg, omb, &sK0[0][0], 72, nhk, wl, lane);
    __syncthreads();   // BAR A: quadrant 0 ready; fences prev-phase sB1/sK1 readers
#pragma unroll 1
    for (int mq = 0; mq < 4; ++mq) {
      u16* nxt = ((mq & 1) == 0) ? &sK1[0][0] : &sK0[0][0];
      const u16 (*cur)[72] = ((mq & 1) == 0) ? sK0 : sK1;
      if (mq < 3 && h == ((mq + 1) & 1))
        phi_quad(kg, omb + (mq + 1) * 4096, nxt, 72, nhk, wl, lane);
      if (part) {
        const bf16x8 a0 = *(const bf16x8*)&sA[h][wl * 16 + fr][mq * 64 + fg * 8];
        const bf16x8 a1 = *(const bf16x8*)&sA[h][wl * 16 + fr][mq * 64 + 32 + fg * 8];
        __builtin_amdgcn_s_setprio(1);
#pragma unroll
        for (int j = 0; j < 4; ++j) {
          const bf16x8 b0 = *(const bf16x8*)&cur[j * 16 + fr][fg * 8];
          const bf16x8 b1 = *(const bf16x8*)&cur[j * 16 + fr][32 + fg * 8];
          sacc[j] = MFMA16(a0, b0, sacc[j]);
          sacc[j] = MFMA16(a1, b1, sacc[j]);
        }
        __builtin_amdgcn_s_setprio(0);
      }
      __syncthreads();   // quadrant BAR: nxt ready / WAR fence on cur
    }
    // S write (half h into its own buffer; own-band rows), dS from rounded val
    u16 (*sS)[72] = (h == 0) ? sK0 : sK1;
    if (part) {
#pragma unroll
      for (int j = 0; j < 4; ++j)
#pragma unroll
        for (int r = 0; r < 4; ++r) {
          const int ss = j * 16 + fr, t = wl * 16 + fg * 4 + r;
          float val = sacc[j][r];
          if (diag && ss > t) val = 0.f;
          const u16 vb = f2bf(val);
          sS[t][ss] = vb;
          dS[r] += bf2f(vb);
        }
    }
    if (h == 0) {  // vT staging (bands wl*16; prior readers fenced by BAR A)
      const u16* vp = v + (ktok + lane) * 64 + wl * 16;
      bf16x8 v0 = *(const bf16x8*)(vp);
      bf16x8 v1 = *(const bf16x8*)(vp + 8);
#pragma unroll
      for (int e = 0; e < 8; ++e) sB1[wl * 16 + e][lane] = (u16)v0[e];
#pragma unroll
      for (int e = 0; e < 8; ++e) sB1[wl * 16 + 8 + e][lane] = (u16)v1[e];
    }
    __syncthreads();   // BAR F: S buffers + vT visible
    if (part) {        // S @ V (A: own buffer own band; B: sB1 cross-band)
      const bf16x8 a0 = *(const bf16x8*)&sS[wl * 16 + fr][fg * 8];
      const bf16x8 a1 = *(const bf16x8*)&sS[wl * 16 + fr][32 + fg * 8];
      __builtin_amdgcn_s_setprio(1);
#pragma unroll
      for (int j = 0; j < 4; ++j) {
        const bf16x8 b0 = *(const bf16x8*)&sB1[j * 16 + fr][fg * 8];
        const bf16x8 b1 = *(const bf16x8*)&sB1[j * 16 + fr][32 + fg * 8];
        oacc[j] = MFMA16(a0, b0, oacc[j]);
        oacc[j] = MFMA16(a1, b1, oacc[j]);
      }
      __builtin_amdgcn_s_setprio(0);
    }
    // no trailing barrier: next phase's BAR A fences sB1/sK1; sK0's next
    // writer (phi0 by half0) follows its own wave's reads (in-order LDS).
  }

  // den: reduce dS over fr lanes; combine with denk via shfl
#pragma unroll
  for (int m2 = 1; m2 <= 8; m2 <<= 1) {
#pragma unroll
    for (int r = 0; r < 4; ++r) dS[r] += __shfl_xor(dS[r], m2, 64);
  }
  const int b = bh >> 4, hh = bh & 15;
#pragma unroll
  for (int r = 0; r < 4; ++r) {
    const float dk = __shfl(denk, fg * 4 + r, 64);   // token wl*16+fg*4+r
    const float rinv = 1.0f / (dk + dS[r] + 1e-6f);
    const int t = wl * 16 + fg * 4 + r;
    const int l = sc * 128 + h * 64 + t;
#pragma unroll
    for (int j = 0; j < 4; ++j) {
      const int d = j * 16 + fr;
      attn[((size_t)b * L_ + l) * DM_ + hh * 64 + d] = f2bf(oacc[j][r] * rinv);
    }
  }
}

extern "C" void kernel_launch(void* const* d_in, const int* in_sizes, int n_in,
                              void* d_out, int out_size, void* d_ws, size_t ws_size,
                              hipStream_t stream) {
  const float* x     = (const float*)d_in[0];
  const float* Wq    = (const float*)d_in[1];
  const float* bq    = (const float*)d_in[2];
  const float* Wk    = (const float*)d_in[3];
  const float* bk    = (const float*)d_in[4];
  const float* Wv    = (const float*)d_in[5];
  const float* bv    = (const float*)d_in[6];
  const float* Wo    = (const float*)d_in[7];
  const float* bo    = (const float*)d_in[8];
  const float* omega = (const float*)d_in[9];
  float* out = (float*)d_out;

  char* ws = (char*)d_ws;
  u16*   v      = (u16*)(ws);                           // 32 MB
  u16*   qb     = (u16*)(ws + 33554432ull);             // 32 MB
  u16*   kb     = (u16*)(ws + 67108864ull);             // 32 MB
  u16*   xb     = (u16*)(ws + 100663296ull);            // 32 MB (alias attn)
  u16*   attn   = xb;
  u16*   stateb = (u16*)(ws + 134217728ull);            // 64 MB
  float* ksum   = (float*)(ws + 201326592ull);          // 2 MB
  u16*   Wt     = (u16*)(ws + 203423744ull);            // 8 MB
  u16*   omb    = (u16*)(ws + 211812352ull);            // 32 KB -> 202 MB

  convx_k<<<16384, 256, 0, stream>>>(x, xb);
  convw_k<<<dim3(16, 16, 4), 256, 0, stream>>>(Wq, Wk, Wv, Wo, Wt);
  convom_k<<<64, 256, 0, stream>>>(omega, omb);

  mm_k<0><<<1024, 256, 0, stream>>>(xb, Wt,                 bq, qb);
  mm_k<0><<<1024, 256, 0, stream>>>(xb, Wt + 1048576ull,    bk, kb);
  mm_k<0><<<1024, 256, 0, stream>>>(xb, Wt + 2097152ull,    bv, v);
  kvstate_k<<<dim3(NSC, BH_), 256, 0, stream>>>(kb, v, omb, stateb, ksum);
  scan_k<<<dim3(8, BH_), 256, 0, stream>>>(stateb, ksum);
  outchunk_k<<<BH_ * NSC, 512, 0, stream>>>(qb, kb, v, omb, stateb, ksum, attn);
  mm_k<1><<<1024, 256, 0, stream>>>(attn, Wt + 3145728ull,  bo, out);
}